// Round 1
// baseline (607.116 us; speedup 1.0000x reference)
//
#include <hip/hip_runtime.h>
#include <cstdint>

#define NODES 50000
#define FIN   128
#define C1    128   // HEADS*HID
#define HEADS 4
#define HID   32
#define CLS   40
#define SLOPE 0.2f

__device__ __forceinline__ float lrelu(float v) { return v > 0.f ? v : SLOPE * v; }

// ---------------- zero int buffer ----------------
__global__ void k_zero(int* __restrict__ p, int n) {
    int i = blockIdx.x * 256 + threadIdx.x;
    if (i < n) p[i] = 0;
}

// ---------------- GEMM1: h1[N,128] = x[N,128] @ W1[128,128] ----------------
__global__ __launch_bounds__(256) void k_gemm1(const float* __restrict__ X,
                                               const float* __restrict__ W,
                                               float* __restrict__ H) {
    __shared__ float As[64][17];   // +1 pad: conflict-free column reads
    __shared__ float Bs[16][128];
    const int tid = threadIdx.x;
    const int tx = tid & 15, ty = tid >> 4;
    const int row0 = blockIdx.x * 64;
    float acc[4][8];
#pragma unroll
    for (int i = 0; i < 4; i++)
#pragma unroll
        for (int j = 0; j < 8; j++) acc[i][j] = 0.f;

    for (int k0 = 0; k0 < FIN; k0 += 16) {
        // stage A tile: 64 rows x 16 k
        {
            int r = tid >> 2, kq = (tid & 3) * 4;
            int gr = row0 + r;
            float4 va = make_float4(0.f, 0.f, 0.f, 0.f);
            if (gr < NODES) va = *(const float4*)(X + (size_t)gr * FIN + k0 + kq);
            As[r][kq + 0] = va.x; As[r][kq + 1] = va.y;
            As[r][kq + 2] = va.z; As[r][kq + 3] = va.w;
        }
        // stage B tile: 16 k x 128 cols
#pragma unroll
        for (int i = 0; i < 2; i++) {
            int qq = tid * 2 + i;
            int rr = qq >> 5, cq = (qq & 31) * 4;
            *(float4*)(&Bs[rr][cq]) = *(const float4*)(W + (size_t)(k0 + rr) * C1 + cq);
        }
        __syncthreads();
#pragma unroll
        for (int kk = 0; kk < 16; kk++) {
            float a[4];
#pragma unroll
            for (int i = 0; i < 4; i++) a[i] = As[ty * 4 + i][kk];
            float4 b0 = *(float4*)(&Bs[kk][tx * 8]);
            float4 b1 = *(float4*)(&Bs[kk][tx * 8 + 4]);
            float b[8] = {b0.x, b0.y, b0.z, b0.w, b1.x, b1.y, b1.z, b1.w};
#pragma unroll
            for (int i = 0; i < 4; i++)
#pragma unroll
                for (int j = 0; j < 8; j++) acc[i][j] = fmaf(a[i], b[j], acc[i][j]);
        }
        __syncthreads();
    }
#pragma unroll
    for (int i = 0; i < 4; i++) {
        int gr = row0 + ty * 4 + i;
        if (gr < NODES) {
            float4 v0 = make_float4(acc[i][0], acc[i][1], acc[i][2], acc[i][3]);
            float4 v1 = make_float4(acc[i][4], acc[i][5], acc[i][6], acc[i][7]);
            *(float4*)(H + (size_t)gr * C1 + tx * 8) = v0;
            *(float4*)(H + (size_t)gr * C1 + tx * 8 + 4) = v1;
        }
    }
}

// ---------------- per-node attention dots, layer 1 ----------------
__global__ void k_att1(const float* __restrict__ H, const float* __restrict__ AS,
                       const float* __restrict__ AD, float* __restrict__ as1,
                       float* __restrict__ ad1) {
    int idx = blockIdx.x * 256 + threadIdx.x;   // n*4 + h
    if (idx >= NODES * HEADS) return;
    int h = idx & 3;
    const float4* hp = (const float4*)(H + (size_t)(idx >> 2) * C1 + h * HID);
    const float4* sp = (const float4*)(AS + h * HID);
    const float4* dp = (const float4*)(AD + h * HID);
    float s = 0.f, d = 0.f;
#pragma unroll
    for (int q = 0; q < 8; q++) {
        float4 hv = hp[q], sv = sp[q], dv = dp[q];
        s += hv.x * sv.x + hv.y * sv.y + hv.z * sv.z + hv.w * sv.w;
        d += hv.x * dv.x + hv.y * dv.y + hv.z * dv.z + hv.w * dv.w;
    }
    as1[idx] = s;
    ad1[idx] = d;
}

// ---------------- degree histogram ----------------
__global__ void k_hist(const int* __restrict__ dst, int E, int* __restrict__ deg) {
    int e = blockIdx.x * 256 + threadIdx.x;
    if (e < E) atomicAdd(&deg[dst[e]], 1);
}

// ---------------- single-block exclusive scan over degrees ----------------
__global__ __launch_bounds__(1024) void k_scan(const int* __restrict__ deg, int n,
                                               int* __restrict__ rowptr,
                                               int* __restrict__ wp) {
    __shared__ int part[1024];
    int t = threadIdx.x;
    int chunk = (n + 1023) >> 10;
    int s = t * chunk;
    int e = s + chunk; if (e > n) e = n; if (s > n) s = n;
    int sum = 0;
    for (int i = s; i < e; i++) sum += deg[i];
    part[t] = sum;
    __syncthreads();
    for (int d = 1; d < 1024; d <<= 1) {
        int v = (t >= d) ? part[t - d] : 0;
        __syncthreads();
        part[t] += v;
        __syncthreads();
    }
    int run = part[t] - sum;   // exclusive prefix
    for (int i = s; i < e; i++) {
        rowptr[i] = run;
        wp[i] = run;
        run += deg[i];
    }
    if (t == 1023) rowptr[n] = part[1023];
}

// ---------------- scatter edges into CSR ----------------
__global__ void k_scatter(const int* __restrict__ src, const int* __restrict__ dst,
                          int E, int* __restrict__ wp, int* __restrict__ col) {
    int e = blockIdx.x * 256 + threadIdx.x;
    if (e < E) {
        int p = atomicAdd(&wp[dst[e]], 1);
        col[p] = src[e];
    }
}

// ---------------- layer-1 aggregation: one wave per dst node ----------------
__global__ __launch_bounds__(256) void k_agg1(const float* __restrict__ H,
                                              const float* __restrict__ as1,
                                              const float* __restrict__ ad1,
                                              const int* __restrict__ rowptr,
                                              const int* __restrict__ col,
                                              const float* __restrict__ b1,
                                              float* __restrict__ out1) {
    int wid = (blockIdx.x * 256 + threadIdx.x) >> 6;
    if (wid >= NODES) return;
    const int lane = threadIdx.x & 63;
    const int head = lane >> 4;     // 16 lanes per head
    const int c0 = lane * 2;        // 2 channels per lane
    const int n = wid;
    const float adn = ad1[n * HEADS + head];
    const int rs = rowptr[n], re = rowptr[n + 1];
    const float e_self = lrelu(as1[n * HEADS + head] + adn);
    // pass 1: segment max (self-loop included implicitly)
    float m = e_self;
    for (int i = rs; i < re; i++) {
        int s = col[i];
        m = fmaxf(m, lrelu(as1[s * HEADS + head] + adn));
    }
    // pass 2: exp / denom / weighted feature sum
    float w = __expf(e_self - m);
    float den = w;
    float2 hv = *(const float2*)(H + (size_t)n * C1 + c0);
    float a0 = w * hv.x, a1 = w * hv.y;
    for (int i = rs; i < re; i++) {
        int s = col[i];
        float wi = __expf(lrelu(as1[s * HEADS + head] + adn) - m);
        den += wi;
        float2 hs = *(const float2*)(H + (size_t)s * C1 + c0);
        a0 = fmaf(wi, hs.x, a0);
        a1 = fmaf(wi, hs.y, a1);
    }
    float o0 = a0 / den + b1[c0];
    float o1 = a1 / den + b1[c0 + 1];
    out1[(size_t)n * C1 + c0]     = fmaxf(o0, 0.f);   // relu after layer 1
    out1[(size_t)n * C1 + c0 + 1] = fmaxf(o1, 0.f);
}

// ---------------- GEMM2: h2[N,40] = out1[N,128] @ W2[128,40] ----------------
__global__ __launch_bounds__(320) void k_gemm2(const float* __restrict__ A,
                                               const float* __restrict__ W,
                                               float* __restrict__ H) {
    __shared__ float xs[64][132];       // pad 128->132 (16B-aligned rows, conflict-lite)
    __shared__ float ws2[128 * 40];
    const int tid = threadIdx.x;
    const int row0 = blockIdx.x * 64;
    for (int q = tid; q < 1280; q += 320)  // W2: 5120 floats
        *(float4*)(ws2 + q * 4) = *(const float4*)(W + q * 4);
    for (int q = tid; q < 2048; q += 320) {  // A tile: 64x128
        int r = q >> 5, kq = (q & 31) * 4;
        int gr = row0 + r;
        float4 v = make_float4(0.f, 0.f, 0.f, 0.f);
        if (gr < NODES) v = *(const float4*)(A + (size_t)gr * FIN + kq);
        *(float4*)(&xs[r][kq]) = v;
    }
    __syncthreads();
    const int r = tid / 5;
    const int c0 = (tid % 5) * 8;
    float acc[8];
#pragma unroll
    for (int j = 0; j < 8; j++) acc[j] = 0.f;
    for (int k = 0; k < 128; k++) {
        float a = xs[r][k];
        float4 b0 = *(float4*)(ws2 + k * CLS + c0);
        float4 b1 = *(float4*)(ws2 + k * CLS + c0 + 4);
        acc[0] = fmaf(a, b0.x, acc[0]); acc[1] = fmaf(a, b0.y, acc[1]);
        acc[2] = fmaf(a, b0.z, acc[2]); acc[3] = fmaf(a, b0.w, acc[3]);
        acc[4] = fmaf(a, b1.x, acc[4]); acc[5] = fmaf(a, b1.y, acc[5]);
        acc[6] = fmaf(a, b1.z, acc[6]); acc[7] = fmaf(a, b1.w, acc[7]);
    }
    int gr = row0 + r;
    if (gr < NODES) {
        *(float4*)(H + (size_t)gr * CLS + c0) =
            make_float4(acc[0], acc[1], acc[2], acc[3]);
        *(float4*)(H + (size_t)gr * CLS + c0 + 4) =
            make_float4(acc[4], acc[5], acc[6], acc[7]);
    }
}

// ---------------- per-node attention dots, layer 2 ----------------
__global__ void k_att2(const float* __restrict__ H2, const float* __restrict__ AS,
                       const float* __restrict__ AD, float* __restrict__ as2,
                       float* __restrict__ ad2) {
    int n = blockIdx.x * 256 + threadIdx.x;
    if (n >= NODES) return;
    const float* hp = H2 + (size_t)n * CLS;
    float s = 0.f, d = 0.f;
#pragma unroll
    for (int c = 0; c < CLS; c++) {
        float v = hp[c];
        s = fmaf(v, AS[c], s);
        d = fmaf(v, AD[c], d);
    }
    as2[n] = s;
    ad2[n] = d;
}

// ---------------- layer-2 aggregation: one wave per dst node ----------------
__global__ __launch_bounds__(256) void k_agg2(const float* __restrict__ H2,
                                              const float* __restrict__ as2,
                                              const float* __restrict__ ad2,
                                              const int* __restrict__ rowptr,
                                              const int* __restrict__ col,
                                              const float* __restrict__ b2,
                                              float* __restrict__ out) {
    int wid = (blockIdx.x * 256 + threadIdx.x) >> 6;
    if (wid >= NODES) return;
    const int lane = threadIdx.x & 63;
    const int n = wid;
    const float adn = ad2[n];
    const int rs = rowptr[n], re = rowptr[n + 1];
    const float e_self = lrelu(as2[n] + adn);
    float m = e_self;
    for (int i = rs; i < re; i++) m = fmaxf(m, lrelu(as2[col[i]] + adn));
    float w = __expf(e_self - m);
    float den = w;
    float acc = (lane < CLS) ? w * H2[(size_t)n * CLS + lane] : 0.f;
    for (int i = rs; i < re; i++) {
        int s = col[i];
        float wi = __expf(lrelu(as2[s] + adn) - m);
        den += wi;
        if (lane < CLS) acc = fmaf(wi, H2[(size_t)s * CLS + lane], acc);
    }
    if (lane < CLS) out[(size_t)n * CLS + lane] = acc / den + b2[lane];
}

extern "C" void kernel_launch(void* const* d_in, const int* in_sizes, int n_in,
                              void* d_out, int out_size, void* d_ws, size_t ws_size,
                              hipStream_t stream) {
    const float* x     = (const float*)d_in[0];
    const int*   ei    = (const int*)d_in[1];
    const float* W1    = (const float*)d_in[2];
    const float* aS1   = (const float*)d_in[3];
    const float* aD1   = (const float*)d_in[4];
    const float* b1    = (const float*)d_in[5];
    const float* W2    = (const float*)d_in[6];
    const float* aS2   = (const float*)d_in[7];
    const float* aD2   = (const float*)d_in[8];
    const float* b2    = (const float*)d_in[9];
    float* out = (float*)d_out;
    const int E = in_sizes[1] / 2;
    const int* src = ei;
    const int* dst = ei + E;

    char* ws = (char*)d_ws;
    size_t off = 0;
    auto alloc = [&](size_t bytes) -> char* {
        char* p = ws + off;
        off += (bytes + 255) & ~(size_t)255;
        return p;
    };
    float* h1   = (float*)alloc((size_t)NODES * C1 * 4);
    float* out1 = (float*)alloc((size_t)NODES * C1 * 4);
    float* h2   = (float*)alloc((size_t)NODES * CLS * 4);
    float* as1  = (float*)alloc((size_t)NODES * HEADS * 4);
    float* ad1  = (float*)alloc((size_t)NODES * HEADS * 4);
    float* as2  = (float*)alloc((size_t)NODES * 4);
    float* ad2  = (float*)alloc((size_t)NODES * 4);
    int* deg    = (int*)alloc((size_t)NODES * 4);
    int* rowptr = (int*)alloc((size_t)(NODES + 1) * 4);
    int* wp     = (int*)alloc((size_t)NODES * 4);
    int* col    = (int*)alloc((size_t)E * 4);

    k_zero<<<(NODES + 255) / 256, 256, 0, stream>>>(deg, NODES);
    k_gemm1<<<(NODES + 63) / 64, 256, 0, stream>>>(x, W1, h1);
    k_att1<<<(NODES * HEADS + 255) / 256, 256, 0, stream>>>(h1, aS1, aD1, as1, ad1);
    k_hist<<<(E + 255) / 256, 256, 0, stream>>>(dst, E, deg);
    k_scan<<<1, 1024, 0, stream>>>(deg, NODES, rowptr, wp);
    k_scatter<<<(E + 255) / 256, 256, 0, stream>>>(src, dst, E, wp, col);
    k_agg1<<<(NODES * 64) / 256, 256, 0, stream>>>(h1, as1, ad1, rowptr, col, b1, out1);
    k_gemm2<<<(NODES + 63) / 64, 320, 0, stream>>>(out1, W2, h2);
    k_att2<<<(NODES + 255) / 256, 256, 0, stream>>>(h2, aS2, aD2, as2, ad2);
    k_agg2<<<(NODES * 64) / 256, 256, 0, stream>>>(h2, as2, ad2, rowptr, col, b2, out);
}

// Round 2
// 482.010 us; speedup vs baseline: 1.2596x; 1.2596x over previous
//
#include <hip/hip_runtime.h>
#include <cstdint>

#define NODES 50000
#define FIN   128
#define C1    128   // HEADS*HID
#define HEADS 4
#define HID   32
#define CLS   40
#define SLOPE 0.2f

__device__ __forceinline__ float lrelu(float v) { return v > 0.f ? v : SLOPE * v; }

// ---------------- zero int buffer ----------------
__global__ void k_zero(int* __restrict__ p, int n) {
    int i = blockIdx.x * 256 + threadIdx.x;
    if (i < n) p[i] = 0;
}

// ---------------- GEMM1: h1[N,128] = x[N,128] @ W1[128,128] ----------------
__global__ __launch_bounds__(256) void k_gemm1(const float* __restrict__ X,
                                               const float* __restrict__ W,
                                               float* __restrict__ H) {
    __shared__ float As[64][17];
    __shared__ float Bs[16][128];
    const int tid = threadIdx.x;
    const int tx = tid & 15, ty = tid >> 4;
    const int row0 = blockIdx.x * 64;
    float acc[4][8];
#pragma unroll
    for (int i = 0; i < 4; i++)
#pragma unroll
        for (int j = 0; j < 8; j++) acc[i][j] = 0.f;

    for (int k0 = 0; k0 < FIN; k0 += 16) {
        {
            int r = tid >> 2, kq = (tid & 3) * 4;
            int gr = row0 + r;
            float4 va = make_float4(0.f, 0.f, 0.f, 0.f);
            if (gr < NODES) va = *(const float4*)(X + (size_t)gr * FIN + k0 + kq);
            As[r][kq + 0] = va.x; As[r][kq + 1] = va.y;
            As[r][kq + 2] = va.z; As[r][kq + 3] = va.w;
        }
#pragma unroll
        for (int i = 0; i < 2; i++) {
            int qq = tid * 2 + i;
            int rr = qq >> 5, cq = (qq & 31) * 4;
            *(float4*)(&Bs[rr][cq]) = *(const float4*)(W + (size_t)(k0 + rr) * C1 + cq);
        }
        __syncthreads();
#pragma unroll
        for (int kk = 0; kk < 16; kk++) {
            float a[4];
#pragma unroll
            for (int i = 0; i < 4; i++) a[i] = As[ty * 4 + i][kk];
            float4 b0 = *(float4*)(&Bs[kk][tx * 8]);
            float4 b1 = *(float4*)(&Bs[kk][tx * 8 + 4]);
            float b[8] = {b0.x, b0.y, b0.z, b0.w, b1.x, b1.y, b1.z, b1.w};
#pragma unroll
            for (int i = 0; i < 4; i++)
#pragma unroll
                for (int j = 0; j < 8; j++) acc[i][j] = fmaf(a[i], b[j], acc[i][j]);
        }
        __syncthreads();
    }
#pragma unroll
    for (int i = 0; i < 4; i++) {
        int gr = row0 + ty * 4 + i;
        if (gr < NODES) {
            *(float4*)(H + (size_t)gr * C1 + tx * 8) =
                make_float4(acc[i][0], acc[i][1], acc[i][2], acc[i][3]);
            *(float4*)(H + (size_t)gr * C1 + tx * 8 + 4) =
                make_float4(acc[i][4], acc[i][5], acc[i][6], acc[i][7]);
        }
    }
}

// ---------------- per-node attention dots, layer 1 ----------------
__global__ void k_att1(const float* __restrict__ H, const float* __restrict__ AS,
                       const float* __restrict__ AD, float* __restrict__ as1,
                       float* __restrict__ ad1) {
    int idx = blockIdx.x * 256 + threadIdx.x;   // n*4 + h
    if (idx >= NODES * HEADS) return;
    int h = idx & 3;
    const float4* hp = (const float4*)(H + (size_t)(idx >> 2) * C1 + h * HID);
    const float4* sp = (const float4*)(AS + h * HID);
    const float4* dp = (const float4*)(AD + h * HID);
    float s = 0.f, d = 0.f;
#pragma unroll
    for (int q = 0; q < 8; q++) {
        float4 hv = hp[q], sv = sp[q], dv = dp[q];
        s += hv.x * sv.x + hv.y * sv.y + hv.z * sv.z + hv.w * sv.w;
        d += hv.x * dv.x + hv.y * dv.y + hv.z * dv.z + hv.w * dv.w;
    }
    as1[idx] = s;
    ad1[idx] = d;
}

// ---------------- degree histogram ----------------
__global__ void k_hist(const int* __restrict__ dst, int E, int* __restrict__ deg) {
    int e = blockIdx.x * 256 + threadIdx.x;
    if (e < E) atomicAdd(&deg[dst[e]], 1);
}

// ---------------- single-block exclusive scan over degrees ----------------
__global__ __launch_bounds__(1024) void k_scan(const int* __restrict__ deg, int n,
                                               int* __restrict__ rowptr,
                                               int* __restrict__ wp) {
    __shared__ int part[1024];
    int t = threadIdx.x;
    int chunk = (n + 1023) >> 10;
    int s = t * chunk;
    int e = s + chunk; if (e > n) e = n; if (s > n) s = n;
    int sum = 0;
    for (int i = s; i < e; i++) sum += deg[i];
    part[t] = sum;
    __syncthreads();
    for (int d = 1; d < 1024; d <<= 1) {
        int v = (t >= d) ? part[t - d] : 0;
        __syncthreads();
        part[t] += v;
        __syncthreads();
    }
    int run = part[t] - sum;
    for (int i = s; i < e; i++) {
        rowptr[i] = run;
        wp[i] = run;
        run += deg[i];
    }
    if (t == 1023) rowptr[n] = part[1023];
}

// ---------------- scatter edges into CSR ----------------
__global__ void k_scatter(const int* __restrict__ src, const int* __restrict__ dst,
                          int E, int* __restrict__ wp, int* __restrict__ col) {
    int e = blockIdx.x * 256 + threadIdx.x;
    if (e < E) {
        int p = atomicAdd(&wp[dst[e]], 1);
        col[p] = src[e];
    }
}

// ---------------- layer-1 aggregation: one wave per dst node ----------------
// wave layout: lane = 16*head + sub; sub indexes edges within a 16-edge chunk.
// attention scores computed lane-parallel; feature pass broadcasts (col,w) via shfl.
__global__ __launch_bounds__(256) void k_agg1(const float* __restrict__ H,
                                              const float* __restrict__ as1,
                                              const float* __restrict__ ad1,
                                              const int* __restrict__ rowptr,
                                              const int* __restrict__ col,
                                              const float* __restrict__ b1,
                                              float* __restrict__ out1) {
    int wid = (blockIdx.x * 256 + threadIdx.x) >> 6;
    if (wid >= NODES) return;
    const int lane = threadIdx.x & 63;
    const int sub = lane & 15;
    const int head = lane >> 4;
    const int n = wid;
    const float adn = ad1[n * HEADS + head];
    const int rs = rowptr[n], re = rowptr[n + 1];
    const float e_self = lrelu(as1[n * HEADS + head] + adn);

    // pass 1: lane-parallel max over edges (chunks of 16), buffer first 2 chunks
    float m = e_self;
    float e0 = -INFINITY, e1 = -INFINITY;
    int   c0v = 0, c1v = 0;
    int ch = 0;
    for (int base = rs; base < re; base += 16, ch++) {
        int i = base + sub;
        float e = -INFINITY;
        int c = 0;
        if (i < re) {
            c = col[i];
            e = lrelu(as1[c * HEADS + head] + adn);
        }
        if (ch == 0)      { e0 = e; c0v = c; }
        else if (ch == 1) { e1 = e; c1v = c; }
        m = fmaxf(m, e);
    }
#pragma unroll
    for (int d = 1; d < 16; d <<= 1) m = fmaxf(m, __shfl_xor(m, d));

    // pass 2: weights + denom + feature aggregation
    const float wself = __expf(e_self - m);
    float den = (sub == 0) ? wself : 0.f;
    const int cc = lane * 2;
    float2 hv = *(const float2*)(H + (size_t)n * C1 + cc);
    float a0 = wself * hv.x, a1 = wself * hv.y;
    ch = 0;
    for (int base = rs; base < re; base += 16, ch++) {
        int i = base + sub;
        float e; int c;
        if (ch == 0)      { e = e0; c = c0v; }
        else if (ch == 1) { e = e1; c = c1v; }
        else {
            e = -INFINITY; c = 0;
            if (i < re) { c = col[i]; e = lrelu(as1[c * HEADS + head] + adn); }
        }
        float w = (i < re) ? __expf(e - m) : 0.f;
        den += w;
        int cnt = re - base; if (cnt > 16) cnt = 16;
        for (int j = 0; j < cnt; j++) {
            int lj = (lane & 48) | j;
            int   sj = __shfl(c, lj);
            float wj = __shfl(w, lj);
            float2 hs = *(const float2*)(H + (size_t)sj * C1 + cc);
            a0 = fmaf(wj, hs.x, a0);
            a1 = fmaf(wj, hs.y, a1);
        }
    }
#pragma unroll
    for (int d = 1; d < 16; d <<= 1) den += __shfl_xor(den, d);
    float o0 = a0 / den + b1[cc];
    float o1 = a1 / den + b1[cc + 1];
    out1[(size_t)n * C1 + cc]     = fmaxf(o0, 0.f);
    out1[(size_t)n * C1 + cc + 1] = fmaxf(o1, 0.f);
}

// ---------------- GEMM2: h2[N,40] = out1[N,128] @ W2[128,40] ----------------
__global__ __launch_bounds__(320) void k_gemm2(const float* __restrict__ A,
                                               const float* __restrict__ W,
                                               float* __restrict__ H) {
    __shared__ float xs[64][132];
    __shared__ float ws2[128 * 40];
    const int tid = threadIdx.x;
    const int row0 = blockIdx.x * 64;
    for (int q = tid; q < 1280; q += 320)
        *(float4*)(ws2 + q * 4) = *(const float4*)(W + q * 4);
    for (int q = tid; q < 2048; q += 320) {
        int r = q >> 5, kq = (q & 31) * 4;
        int gr = row0 + r;
        float4 v = make_float4(0.f, 0.f, 0.f, 0.f);
        if (gr < NODES) v = *(const float4*)(A + (size_t)gr * FIN + kq);
        *(float4*)(&xs[r][kq]) = v;
    }
    __syncthreads();
    const int r = tid / 5;
    const int c0 = (tid % 5) * 8;
    float acc[8];
#pragma unroll
    for (int j = 0; j < 8; j++) acc[j] = 0.f;
    for (int k = 0; k < 128; k++) {
        float a = xs[r][k];
        float4 b0 = *(float4*)(ws2 + k * CLS + c0);
        float4 b1 = *(float4*)(ws2 + k * CLS + c0 + 4);
        acc[0] = fmaf(a, b0.x, acc[0]); acc[1] = fmaf(a, b0.y, acc[1]);
        acc[2] = fmaf(a, b0.z, acc[2]); acc[3] = fmaf(a, b0.w, acc[3]);
        acc[4] = fmaf(a, b1.x, acc[4]); acc[5] = fmaf(a, b1.y, acc[5]);
        acc[6] = fmaf(a, b1.z, acc[6]); acc[7] = fmaf(a, b1.w, acc[7]);
    }
    int gr = row0 + r;
    if (gr < NODES) {
        *(float4*)(H + (size_t)gr * CLS + c0) =
            make_float4(acc[0], acc[1], acc[2], acc[3]);
        *(float4*)(H + (size_t)gr * CLS + c0 + 4) =
            make_float4(acc[4], acc[5], acc[6], acc[7]);
    }
}

// ---------------- per-node attention dots, layer 2 ----------------
__global__ void k_att2(const float* __restrict__ H2, const float* __restrict__ AS,
                       const float* __restrict__ AD, float* __restrict__ as2,
                       float* __restrict__ ad2) {
    int n = blockIdx.x * 256 + threadIdx.x;
    if (n >= NODES) return;
    const float* hp = H2 + (size_t)n * CLS;
    float s = 0.f, d = 0.f;
#pragma unroll
    for (int c = 0; c < CLS; c++) {
        float v = hp[c];
        s = fmaf(v, AS[c], s);
        d = fmaf(v, AD[c], d);
    }
    as2[n] = s;
    ad2[n] = d;
}

// ---------------- layer-2 aggregation: one wave per dst node ----------------
// attention lane-parallel over 64-edge chunks; feature pass: lanes 0..39 own classes.
__global__ __launch_bounds__(256) void k_agg2(const float* __restrict__ H2,
                                              const float* __restrict__ as2,
                                              const float* __restrict__ ad2,
                                              const int* __restrict__ rowptr,
                                              const int* __restrict__ col,
                                              const float* __restrict__ b2,
                                              float* __restrict__ out) {
    int wid = (blockIdx.x * 256 + threadIdx.x) >> 6;
    if (wid >= NODES) return;
    const int lane = threadIdx.x & 63;
    const int n = wid;
    const float adn = ad2[n];
    const int rs = rowptr[n], re = rowptr[n + 1];
    const float e_self = lrelu(as2[n] + adn);

    float m = e_self;
    float e0 = -INFINITY, e1 = -INFINITY;
    int   c0v = 0, c1v = 0;
    int ch = 0;
    for (int base = rs; base < re; base += 64, ch++) {
        int i = base + lane;
        float e = -INFINITY;
        int c = 0;
        if (i < re) {
            c = col[i];
            e = lrelu(as2[c] + adn);
        }
        if (ch == 0)      { e0 = e; c0v = c; }
        else if (ch == 1) { e1 = e; c1v = c; }
        m = fmaxf(m, e);
    }
#pragma unroll
    for (int d = 1; d < 64; d <<= 1) m = fmaxf(m, __shfl_xor(m, d));

    const float wself = __expf(e_self - m);
    float den = (lane == 0) ? wself : 0.f;
    float acc = (lane < CLS) ? wself * H2[(size_t)n * CLS + lane] : 0.f;
    ch = 0;
    for (int base = rs; base < re; base += 64, ch++) {
        int i = base + lane;
        float e; int c;
        if (ch == 0)      { e = e0; c = c0v; }
        else if (ch == 1) { e = e1; c = c1v; }
        else {
            e = -INFINITY; c = 0;
            if (i < re) { c = col[i]; e = lrelu(as2[c] + adn); }
        }
        float w = (i < re) ? __expf(e - m) : 0.f;
        den += w;
        int cnt = re - base; if (cnt > 64) cnt = 64;
        for (int j = 0; j < cnt; j++) {
            int   sj = __shfl(c, j);
            float wj = __shfl(w, j);
            if (lane < CLS) acc = fmaf(wj, H2[(size_t)sj * CLS + lane], acc);
        }
    }
#pragma unroll
    for (int d = 1; d < 64; d <<= 1) den += __shfl_xor(den, d);
    if (lane < CLS) out[(size_t)n * CLS + lane] = acc / den + b2[lane];
}

extern "C" void kernel_launch(void* const* d_in, const int* in_sizes, int n_in,
                              void* d_out, int out_size, void* d_ws, size_t ws_size,
                              hipStream_t stream) {
    const float* x     = (const float*)d_in[0];
    const int*   ei    = (const int*)d_in[1];
    const float* W1    = (const float*)d_in[2];
    const float* aS1   = (const float*)d_in[3];
    const float* aD1   = (const float*)d_in[4];
    const float* b1    = (const float*)d_in[5];
    const float* W2    = (const float*)d_in[6];
    const float* aS2   = (const float*)d_in[7];
    const float* aD2   = (const float*)d_in[8];
    const float* b2    = (const float*)d_in[9];
    float* out = (float*)d_out;
    const int E = in_sizes[1] / 2;
    const int* src = ei;
    const int* dst = ei + E;

    char* ws = (char*)d_ws;
    size_t off = 0;
    auto alloc = [&](size_t bytes) -> char* {
        char* p = ws + off;
        off += (bytes + 255) & ~(size_t)255;
        return p;
    };
    float* h1   = (float*)alloc((size_t)NODES * C1 * 4);
    float* out1 = (float*)alloc((size_t)NODES * C1 * 4);
    float* h2   = (float*)alloc((size_t)NODES * CLS * 4);
    float* as1  = (float*)alloc((size_t)NODES * HEADS * 4);
    float* ad1  = (float*)alloc((size_t)NODES * HEADS * 4);
    float* as2  = (float*)alloc((size_t)NODES * 4);
    float* ad2  = (float*)alloc((size_t)NODES * 4);
    int* deg    = (int*)alloc((size_t)NODES * 4);
    int* rowptr = (int*)alloc((size_t)(NODES + 1) * 4);
    int* wp     = (int*)alloc((size_t)NODES * 4);
    int* col    = (int*)alloc((size_t)E * 4);

    k_zero<<<(NODES + 255) / 256, 256, 0, stream>>>(deg, NODES);
    k_gemm1<<<(NODES + 63) / 64, 256, 0, stream>>>(x, W1, h1);
    k_att1<<<(NODES * HEADS + 255) / 256, 256, 0, stream>>>(h1, aS1, aD1, as1, ad1);
    k_hist<<<(E + 255) / 256, 256, 0, stream>>>(dst, E, deg);
    k_scan<<<1, 1024, 0, stream>>>(deg, NODES, rowptr, wp);
    k_scatter<<<(E + 255) / 256, 256, 0, stream>>>(src, dst, E, wp, col);
    k_agg1<<<(NODES * 64) / 256, 256, 0, stream>>>(h1, as1, ad1, rowptr, col, b1, out1);
    k_gemm2<<<(NODES + 63) / 64, 320, 0, stream>>>(out1, W2, h2);
    k_att2<<<(NODES + 255) / 256, 256, 0, stream>>>(h2, aS2, aD2, as2, ad2);
    k_agg2<<<(NODES * 64) / 256, 256, 0, stream>>>(h2, as2, ad2, rowptr, col, b2, out);
}

// Round 3
// 376.841 us; speedup vs baseline: 1.6111x; 1.2791x over previous
//
#include <hip/hip_runtime.h>
#include <cstdint>

#define NODES 50000
#define FIN   128
#define C1    128   // HEADS*HID
#define HEADS 4
#define HID   32
#define CLS   40
#define SLOPE 0.2f

#define SCAN_TILE 1024
#define SCAN_BLOCKS ((NODES + SCAN_TILE - 1) / SCAN_TILE)   // 49

__device__ __forceinline__ float lrelu(float v) { return v > 0.f ? v : SLOPE * v; }

// ---------------- zero int buffer ----------------
__global__ void k_zero(int* __restrict__ p, int n) {
    int i = blockIdx.x * 256 + threadIdx.x;
    if (i < n) p[i] = 0;
}

// ---------------- GEMM1: h1[N,128] = x[N,128] @ W1[128,128] ----------------
__global__ __launch_bounds__(256) void k_gemm1(const float* __restrict__ X,
                                               const float* __restrict__ W,
                                               float* __restrict__ H) {
    __shared__ float As[64][17];
    __shared__ float Bs[16][128];
    const int tid = threadIdx.x;
    const int tx = tid & 15, ty = tid >> 4;
    const int row0 = blockIdx.x * 64;
    float acc[4][8];
#pragma unroll
    for (int i = 0; i < 4; i++)
#pragma unroll
        for (int j = 0; j < 8; j++) acc[i][j] = 0.f;

    for (int k0 = 0; k0 < FIN; k0 += 16) {
        {
            int r = tid >> 2, kq = (tid & 3) * 4;
            int gr = row0 + r;
            float4 va = make_float4(0.f, 0.f, 0.f, 0.f);
            if (gr < NODES) va = *(const float4*)(X + (size_t)gr * FIN + k0 + kq);
            As[r][kq + 0] = va.x; As[r][kq + 1] = va.y;
            As[r][kq + 2] = va.z; As[r][kq + 3] = va.w;
        }
#pragma unroll
        for (int i = 0; i < 2; i++) {
            int qq = tid * 2 + i;
            int rr = qq >> 5, cq = (qq & 31) * 4;
            *(float4*)(&Bs[rr][cq]) = *(const float4*)(W + (size_t)(k0 + rr) * C1 + cq);
        }
        __syncthreads();
#pragma unroll
        for (int kk = 0; kk < 16; kk++) {
            float a[4];
#pragma unroll
            for (int i = 0; i < 4; i++) a[i] = As[ty * 4 + i][kk];
            float4 b0 = *(float4*)(&Bs[kk][tx * 8]);
            float4 b1 = *(float4*)(&Bs[kk][tx * 8 + 4]);
            float b[8] = {b0.x, b0.y, b0.z, b0.w, b1.x, b1.y, b1.z, b1.w};
#pragma unroll
            for (int i = 0; i < 4; i++)
#pragma unroll
                for (int j = 0; j < 8; j++) acc[i][j] = fmaf(a[i], b[j], acc[i][j]);
        }
        __syncthreads();
    }
#pragma unroll
    for (int i = 0; i < 4; i++) {
        int gr = row0 + ty * 4 + i;
        if (gr < NODES) {
            *(float4*)(H + (size_t)gr * C1 + tx * 8) =
                make_float4(acc[i][0], acc[i][1], acc[i][2], acc[i][3]);
            *(float4*)(H + (size_t)gr * C1 + tx * 8 + 4) =
                make_float4(acc[i][4], acc[i][5], acc[i][6], acc[i][7]);
        }
    }
}

// ---------------- per-node attention dots, layer 1 ----------------
__global__ void k_att1(const float* __restrict__ H, const float* __restrict__ AS,
                       const float* __restrict__ AD, float* __restrict__ as1,
                       float* __restrict__ ad1) {
    int idx = blockIdx.x * 256 + threadIdx.x;   // n*4 + h
    if (idx >= NODES * HEADS) return;
    int h = idx & 3;
    const float4* hp = (const float4*)(H + (size_t)(idx >> 2) * C1 + h * HID);
    const float4* sp = (const float4*)(AS + h * HID);
    const float4* dp = (const float4*)(AD + h * HID);
    float s = 0.f, d = 0.f;
#pragma unroll
    for (int q = 0; q < 8; q++) {
        float4 hv = hp[q], sv = sp[q], dv = dp[q];
        s += hv.x * sv.x + hv.y * sv.y + hv.z * sv.z + hv.w * sv.w;
        d += hv.x * dv.x + hv.y * dv.y + hv.z * dv.z + hv.w * dv.w;
    }
    as1[idx] = s;
    ad1[idx] = d;
}

// ---------------- degree histogram ----------------
__global__ void k_hist(const int* __restrict__ dst, int E, int* __restrict__ deg) {
    int e = blockIdx.x * 256 + threadIdx.x;
    if (e < E) atomicAdd(&deg[dst[e]], 1);
}

// ---------------- device-wide scan, stage 1: per-block reduce ----------------
__global__ __launch_bounds__(256) void k_part(const int* __restrict__ deg,
                                              int* __restrict__ part) {
    __shared__ int sm[4];
    const int t = threadIdx.x;
    const int base = blockIdx.x * SCAN_TILE + t * 4;
    int s = 0;
    if (base + 3 < NODES) {
        int4 v = *(const int4*)(deg + base);
        s = v.x + v.y + v.z + v.w;
    } else {
#pragma unroll
        for (int i = 0; i < 4; i++) if (base + i < NODES) s += deg[base + i];
    }
    // wave reduce
#pragma unroll
    for (int d = 1; d < 64; d <<= 1) s += __shfl_xor(s, d);
    if ((t & 63) == 0) sm[t >> 6] = s;
    __syncthreads();
    if (t == 0) part[blockIdx.x] = sm[0] + sm[1] + sm[2] + sm[3];
}

// ---------------- stage 2: single-wave scan of partials ----------------
__global__ __launch_bounds__(64) void k_scan_part(const int* __restrict__ part,
                                                  int* __restrict__ partpfx,
                                                  int* __restrict__ rowptr) {
    const int t = threadIdx.x;
    int v = (t < SCAN_BLOCKS) ? part[t] : 0;
    int incl = v;
#pragma unroll
    for (int d = 1; d < 64; d <<= 1) {
        int u = __shfl_up(incl, d);
        if (t >= d) incl += u;
    }
    if (t < SCAN_BLOCKS) partpfx[t] = incl - v;   // exclusive
    if (t == 63) rowptr[NODES] = incl;            // grand total
}

// ---------------- stage 3: per-block scan + write rowptr/wp ----------------
__global__ __launch_bounds__(256) void k_scan_write(const int* __restrict__ deg,
                                                    const int* __restrict__ partpfx,
                                                    int* __restrict__ rowptr,
                                                    int* __restrict__ wp) {
    __shared__ int sm[4];
    const int t = threadIdx.x;
    const int lane = t & 63, w = t >> 6;
    const int base = blockIdx.x * SCAN_TILE + t * 4;
    int v0 = 0, v1 = 0, v2 = 0, v3 = 0;
    if (base + 3 < NODES) {
        int4 v = *(const int4*)(deg + base);
        v0 = v.x; v1 = v.y; v2 = v.z; v3 = v.w;
    } else {
        if (base + 0 < NODES) v0 = deg[base + 0];
        if (base + 1 < NODES) v1 = deg[base + 1];
        if (base + 2 < NODES) v2 = deg[base + 2];
        if (base + 3 < NODES) v3 = deg[base + 3];
    }
    const int s = v0 + v1 + v2 + v3;
    int incl = s;
#pragma unroll
    for (int d = 1; d < 64; d <<= 1) {
        int u = __shfl_up(incl, d);
        if (lane >= d) incl += u;
    }
    if (lane == 63) sm[w] = incl;
    __syncthreads();
    if (t == 0) {
        int r = 0;
#pragma unroll
        for (int i = 0; i < 4; i++) { int x = sm[i]; sm[i] = r; r += x; }
    }
    __syncthreads();
    int run = (incl - s) + sm[w] + partpfx[blockIdx.x];
    if (base + 3 < NODES) {
        int4 rp = make_int4(run, run + v0, run + v0 + v1, run + v0 + v1 + v2);
        *(int4*)(rowptr + base) = rp;
        *(int4*)(wp + base) = rp;
    } else {
        int r = run;
        if (base + 0 < NODES) { rowptr[base + 0] = r; wp[base + 0] = r; r += v0; }
        if (base + 1 < NODES) { rowptr[base + 1] = r; wp[base + 1] = r; r += v1; }
        if (base + 2 < NODES) { rowptr[base + 2] = r; wp[base + 2] = r; r += v2; }
        if (base + 3 < NODES) { rowptr[base + 3] = r; wp[base + 3] = r; r += v3; }
    }
}

// ---------------- scatter edges into CSR ----------------
__global__ void k_scatter(const int* __restrict__ src, const int* __restrict__ dst,
                          int E, int* __restrict__ wp, int* __restrict__ col) {
    int e = blockIdx.x * 256 + threadIdx.x;
    if (e < E) {
        int p = atomicAdd(&wp[dst[e]], 1);
        col[p] = src[e];
    }
}

// ---------------- layer-1 aggregation: one wave per dst node ----------------
__global__ __launch_bounds__(256) void k_agg1(const float* __restrict__ H,
                                              const float* __restrict__ as1,
                                              const float* __restrict__ ad1,
                                              const int* __restrict__ rowptr,
                                              const int* __restrict__ col,
                                              const float* __restrict__ b1,
                                              float* __restrict__ out1) {
    int wid = (blockIdx.x * 256 + threadIdx.x) >> 6;
    if (wid >= NODES) return;
    const int lane = threadIdx.x & 63;
    const int sub = lane & 15;
    const int head = lane >> 4;
    const int n = wid;
    const float adn = ad1[n * HEADS + head];
    const int rs = rowptr[n], re = rowptr[n + 1];
    const float e_self = lrelu(as1[n * HEADS + head] + adn);

    float m = e_self;
    float e0 = -INFINITY, e1 = -INFINITY;
    int   c0v = 0, c1v = 0;
    int ch = 0;
    for (int base = rs; base < re; base += 16, ch++) {
        int i = base + sub;
        float e = -INFINITY;
        int c = 0;
        if (i < re) {
            c = col[i];
            e = lrelu(as1[c * HEADS + head] + adn);
        }
        if (ch == 0)      { e0 = e; c0v = c; }
        else if (ch == 1) { e1 = e; c1v = c; }
        m = fmaxf(m, e);
    }
#pragma unroll
    for (int d = 1; d < 16; d <<= 1) m = fmaxf(m, __shfl_xor(m, d));

    const float wself = __expf(e_self - m);
    float den = (sub == 0) ? wself : 0.f;
    const int cc = lane * 2;
    float2 hv = *(const float2*)(H + (size_t)n * C1 + cc);
    float a0 = wself * hv.x, a1 = wself * hv.y;
    ch = 0;
    for (int base = rs; base < re; base += 16, ch++) {
        int i = base + sub;
        float e; int c;
        if (ch == 0)      { e = e0; c = c0v; }
        else if (ch == 1) { e = e1; c = c1v; }
        else {
            e = -INFINITY; c = 0;
            if (i < re) { c = col[i]; e = lrelu(as1[c * HEADS + head] + adn); }
        }
        float w = (i < re) ? __expf(e - m) : 0.f;
        den += w;
        int cnt = re - base; if (cnt > 16) cnt = 16;
        for (int j = 0; j < cnt; j++) {
            int lj = (lane & 48) | j;
            int   sj = __shfl(c, lj);
            float wj = __shfl(w, lj);
            float2 hs = *(const float2*)(H + (size_t)sj * C1 + cc);
            a0 = fmaf(wj, hs.x, a0);
            a1 = fmaf(wj, hs.y, a1);
        }
    }
#pragma unroll
    for (int d = 1; d < 16; d <<= 1) den += __shfl_xor(den, d);
    float o0 = a0 / den + b1[cc];
    float o1 = a1 / den + b1[cc + 1];
    out1[(size_t)n * C1 + cc]     = fmaxf(o0, 0.f);
    out1[(size_t)n * C1 + cc + 1] = fmaxf(o1, 0.f);
}

// ---------------- GEMM2: h2[N,40] = out1[N,128] @ W2[128,40] ----------------
__global__ __launch_bounds__(320) void k_gemm2(const float* __restrict__ A,
                                               const float* __restrict__ W,
                                               float* __restrict__ H) {
    __shared__ float xs[64][132];
    __shared__ float ws2[128 * 40];
    const int tid = threadIdx.x;
    const int row0 = blockIdx.x * 64;
    for (int q = tid; q < 1280; q += 320)
        *(float4*)(ws2 + q * 4) = *(const float4*)(W + q * 4);
    for (int q = tid; q < 2048; q += 320) {
        int r = q >> 5, kq = (q & 31) * 4;
        int gr = row0 + r;
        float4 v = make_float4(0.f, 0.f, 0.f, 0.f);
        if (gr < NODES) v = *(const float4*)(A + (size_t)gr * FIN + kq);
        *(float4*)(&xs[r][kq]) = v;
    }
    __syncthreads();
    const int r = tid / 5;
    const int c0 = (tid % 5) * 8;
    float acc[8];
#pragma unroll
    for (int j = 0; j < 8; j++) acc[j] = 0.f;
    for (int k = 0; k < 128; k++) {
        float a = xs[r][k];
        float4 b0 = *(float4*)(ws2 + k * CLS + c0);
        float4 b1 = *(float4*)(ws2 + k * CLS + c0 + 4);
        acc[0] = fmaf(a, b0.x, acc[0]); acc[1] = fmaf(a, b0.y, acc[1]);
        acc[2] = fmaf(a, b0.z, acc[2]); acc[3] = fmaf(a, b0.w, acc[3]);
        acc[4] = fmaf(a, b1.x, acc[4]); acc[5] = fmaf(a, b1.y, acc[5]);
        acc[6] = fmaf(a, b1.z, acc[6]); acc[7] = fmaf(a, b1.w, acc[7]);
    }
    int gr = row0 + r;
    if (gr < NODES) {
        *(float4*)(H + (size_t)gr * CLS + c0) =
            make_float4(acc[0], acc[1], acc[2], acc[3]);
        *(float4*)(H + (size_t)gr * CLS + c0 + 4) =
            make_float4(acc[4], acc[5], acc[6], acc[7]);
    }
}

// ---------------- per-node attention dots, layer 2 ----------------
__global__ void k_att2(const float* __restrict__ H2, const float* __restrict__ AS,
                       const float* __restrict__ AD, float* __restrict__ as2,
                       float* __restrict__ ad2) {
    int n = blockIdx.x * 256 + threadIdx.x;
    if (n >= NODES) return;
    const float* hp = H2 + (size_t)n * CLS;
    float s = 0.f, d = 0.f;
#pragma unroll
    for (int c = 0; c < CLS; c++) {
        float v = hp[c];
        s = fmaf(v, AS[c], s);
        d = fmaf(v, AD[c], d);
    }
    as2[n] = s;
    ad2[n] = d;
}

// ---------------- layer-2 aggregation: one wave per dst node ----------------
__global__ __launch_bounds__(256) void k_agg2(const float* __restrict__ H2,
                                              const float* __restrict__ as2,
                                              const float* __restrict__ ad2,
                                              const int* __restrict__ rowptr,
                                              const int* __restrict__ col,
                                              const float* __restrict__ b2,
                                              float* __restrict__ out) {
    int wid = (blockIdx.x * 256 + threadIdx.x) >> 6;
    if (wid >= NODES) return;
    const int lane = threadIdx.x & 63;
    const int n = wid;
    const float adn = ad2[n];
    const int rs = rowptr[n], re = rowptr[n + 1];
    const float e_self = lrelu(as2[n] + adn);

    float m = e_self;
    float e0 = -INFINITY, e1 = -INFINITY;
    int   c0v = 0, c1v = 0;
    int ch = 0;
    for (int base = rs; base < re; base += 64, ch++) {
        int i = base + lane;
        float e = -INFINITY;
        int c = 0;
        if (i < re) {
            c = col[i];
            e = lrelu(as2[c] + adn);
        }
        if (ch == 0)      { e0 = e; c0v = c; }
        else if (ch == 1) { e1 = e; c1v = c; }
        m = fmaxf(m, e);
    }
#pragma unroll
    for (int d = 1; d < 64; d <<= 1) m = fmaxf(m, __shfl_xor(m, d));

    const float wself = __expf(e_self - m);
    float den = (lane == 0) ? wself : 0.f;
    float acc = (lane < CLS) ? wself * H2[(size_t)n * CLS + lane] : 0.f;
    ch = 0;
    for (int base = rs; base < re; base += 64, ch++) {
        int i = base + lane;
        float e; int c;
        if (ch == 0)      { e = e0; c = c0v; }
        else if (ch == 1) { e = e1; c = c1v; }
        else {
            e = -INFINITY; c = 0;
            if (i < re) { c = col[i]; e = lrelu(as2[c] + adn); }
        }
        float w = (i < re) ? __expf(e - m) : 0.f;
        den += w;
        int cnt = re - base; if (cnt > 64) cnt = 64;
        for (int j = 0; j < cnt; j++) {
            int   sj = __shfl(c, j);
            float wj = __shfl(w, j);
            if (lane < CLS) acc = fmaf(wj, H2[(size_t)sj * CLS + lane], acc);
        }
    }
#pragma unroll
    for (int d = 1; d < 64; d <<= 1) den += __shfl_xor(den, d);
    if (lane < CLS) out[(size_t)n * CLS + lane] = acc / den + b2[lane];
}

extern "C" void kernel_launch(void* const* d_in, const int* in_sizes, int n_in,
                              void* d_out, int out_size, void* d_ws, size_t ws_size,
                              hipStream_t stream) {
    const float* x     = (const float*)d_in[0];
    const int*   ei    = (const int*)d_in[1];
    const float* W1    = (const float*)d_in[2];
    const float* aS1   = (const float*)d_in[3];
    const float* aD1   = (const float*)d_in[4];
    const float* b1    = (const float*)d_in[5];
    const float* W2    = (const float*)d_in[6];
    const float* aS2   = (const float*)d_in[7];
    const float* aD2   = (const float*)d_in[8];
    const float* b2    = (const float*)d_in[9];
    float* out = (float*)d_out;
    const int E = in_sizes[1] / 2;
    const int* src = ei;
    const int* dst = ei + E;

    char* ws = (char*)d_ws;
    size_t off = 0;
    auto alloc = [&](size_t bytes) -> char* {
        char* p = ws + off;
        off += (bytes + 255) & ~(size_t)255;
        return p;
    };
    float* h1     = (float*)alloc((size_t)NODES * C1 * 4);
    float* out1   = (float*)alloc((size_t)NODES * C1 * 4);
    float* h2     = (float*)alloc((size_t)NODES * CLS * 4);
    float* as1    = (float*)alloc((size_t)NODES * HEADS * 4);
    float* ad1    = (float*)alloc((size_t)NODES * HEADS * 4);
    float* as2    = (float*)alloc((size_t)NODES * 4);
    float* ad2    = (float*)alloc((size_t)NODES * 4);
    int* deg      = (int*)alloc((size_t)NODES * 4);
    int* rowptr   = (int*)alloc((size_t)(NODES + 1) * 4);
    int* wp       = (int*)alloc((size_t)NODES * 4);
    int* col      = (int*)alloc((size_t)E * 4);
    int* part     = (int*)alloc((size_t)SCAN_BLOCKS * 4);
    int* partpfx  = (int*)alloc((size_t)SCAN_BLOCKS * 4);

    k_zero<<<(NODES + 255) / 256, 256, 0, stream>>>(deg, NODES);
    k_gemm1<<<(NODES + 63) / 64, 256, 0, stream>>>(x, W1, h1);
    k_att1<<<(NODES * HEADS + 255) / 256, 256, 0, stream>>>(h1, aS1, aD1, as1, ad1);
    k_hist<<<(E + 255) / 256, 256, 0, stream>>>(dst, E, deg);
    k_part<<<SCAN_BLOCKS, 256, 0, stream>>>(deg, part);
    k_scan_part<<<1, 64, 0, stream>>>(part, partpfx, rowptr);
    k_scan_write<<<SCAN_BLOCKS, 256, 0, stream>>>(deg, partpfx, rowptr, wp);
    k_scatter<<<(E + 255) / 256, 256, 0, stream>>>(src, dst, E, wp, col);
    k_agg1<<<(NODES * 64) / 256, 256, 0, stream>>>(h1, as1, ad1, rowptr, col, b1, out1);
    k_gemm2<<<(NODES + 63) / 64, 320, 0, stream>>>(out1, W2, h2);
    k_att2<<<(NODES + 255) / 256, 256, 0, stream>>>(h2, aS2, aD2, as2, ad2);
    k_agg2<<<(NODES * 64) / 256, 256, 0, stream>>>(h2, as2, ad2, rowptr, col, b2, out);
}

// Round 4
// 334.739 us; speedup vs baseline: 1.8137x; 1.1258x over previous
//
#include <hip/hip_runtime.h>
#include <cstdint>

#define NODES 50000
#define FIN   128
#define C1    128   // HEADS*HID
#define HEADS 4
#define HID   32
#define CLS   40
#define SLOPE 0.2f

#define SCAN_TILE 1024
#define SCAN_BLOCKS ((NODES + SCAN_TILE - 1) / SCAN_TILE)   // 49

__device__ __forceinline__ float lrelu(float v) { return v > 0.f ? v : SLOPE * v; }

// bf16 helpers (RNE pack, exact unpack)
__device__ __forceinline__ unsigned short f2bf(float f) {
    union { float f; unsigned u; } v; v.f = f;
    unsigned u = v.u;
    return (unsigned short)((u + 0x7FFFu + ((u >> 16) & 1u)) >> 16);
}
__device__ __forceinline__ float bf2f(unsigned short b) {
    union { unsigned u; float f; } v; v.u = ((unsigned)b) << 16;
    return v.f;
}

// ---------------- zero int buffer ----------------
__global__ void k_zero(int* __restrict__ p, int n) {
    int i = blockIdx.x * 256 + threadIdx.x;
    if (i < n) p[i] = 0;
}

// ---- GEMM1: h1b[N,128](bf16) = x @ W1 ; also as1/ad1 from fp32 acc ----
__global__ __launch_bounds__(256) void k_gemm1(const float* __restrict__ X,
                                               const float* __restrict__ W,
                                               const float* __restrict__ AS,
                                               const float* __restrict__ AD,
                                               unsigned short* __restrict__ h1b,
                                               float* __restrict__ as1,
                                               float* __restrict__ ad1) {
    __shared__ float As[64][17];
    __shared__ float Bs[16][128];
    const int tid = threadIdx.x;
    const int tx = tid & 15, ty = tid >> 4;
    const int row0 = blockIdx.x * 64;
    float acc[4][8];
#pragma unroll
    for (int i = 0; i < 4; i++)
#pragma unroll
        for (int j = 0; j < 8; j++) acc[i][j] = 0.f;

    for (int k0 = 0; k0 < FIN; k0 += 16) {
        {
            int r = tid >> 2, kq = (tid & 3) * 4;
            int gr = row0 + r;
            float4 va = make_float4(0.f, 0.f, 0.f, 0.f);
            if (gr < NODES) va = *(const float4*)(X + (size_t)gr * FIN + k0 + kq);
            As[r][kq + 0] = va.x; As[r][kq + 1] = va.y;
            As[r][kq + 2] = va.z; As[r][kq + 3] = va.w;
        }
#pragma unroll
        for (int i = 0; i < 2; i++) {
            int qq = tid * 2 + i;
            int rr = qq >> 5, cq = (qq & 31) * 4;
            *(float4*)(&Bs[rr][cq]) = *(const float4*)(W + (size_t)(k0 + rr) * C1 + cq);
        }
        __syncthreads();
#pragma unroll
        for (int kk = 0; kk < 16; kk++) {
            float a[4];
#pragma unroll
            for (int i = 0; i < 4; i++) a[i] = As[ty * 4 + i][kk];
            float4 b0 = *(float4*)(&Bs[kk][tx * 8]);
            float4 b1 = *(float4*)(&Bs[kk][tx * 8 + 4]);
            float b[8] = {b0.x, b0.y, b0.z, b0.w, b1.x, b1.y, b1.z, b1.w};
#pragma unroll
            for (int i = 0; i < 4; i++)
#pragma unroll
                for (int j = 0; j < 8; j++) acc[i][j] = fmaf(a[i], b[j], acc[i][j]);
        }
        __syncthreads();
    }
    // write bf16 features
#pragma unroll
    for (int i = 0; i < 4; i++) {
        int gr = row0 + ty * 4 + i;
        if (gr < NODES) {
            unsigned short tb[8];
#pragma unroll
            for (int j = 0; j < 8; j++) tb[j] = f2bf(acc[i][j]);
            uint4 pk;
            pk.x = (unsigned)tb[0] | ((unsigned)tb[1] << 16);
            pk.y = (unsigned)tb[2] | ((unsigned)tb[3] << 16);
            pk.z = (unsigned)tb[4] | ((unsigned)tb[5] << 16);
            pk.w = (unsigned)tb[6] | ((unsigned)tb[7] << 16);
            *(uint4*)(h1b + (size_t)gr * C1 + tx * 8) = pk;
        }
    }
    // fused attention dots (fp32-exact): head h = tx>>2, sub-offset co = (tx&3)*8
    const int h = tx >> 2;
    const int co = (tx & 3) * 8;
    float ps[4], pd[4];
#pragma unroll
    for (int i = 0; i < 4; i++) {
        float s = 0.f, d = 0.f;
#pragma unroll
        for (int j = 0; j < 8; j++) {
            s = fmaf(acc[i][j], AS[h * HID + co + j], s);
            d = fmaf(acc[i][j], AD[h * HID + co + j], d);
        }
        ps[i] = s; pd[i] = d;
    }
#pragma unroll
    for (int i = 0; i < 4; i++) {
        ps[i] += __shfl_xor(ps[i], 1); ps[i] += __shfl_xor(ps[i], 2);
        pd[i] += __shfl_xor(pd[i], 1); pd[i] += __shfl_xor(pd[i], 2);
    }
    if ((tx & 3) == 0) {
#pragma unroll
        for (int i = 0; i < 4; i++) {
            int gr = row0 + ty * 4 + i;
            if (gr < NODES) {
                as1[gr * HEADS + h] = ps[i];
                ad1[gr * HEADS + h] = pd[i];
            }
        }
    }
}

// ---------------- degree histogram ----------------
__global__ void k_hist(const int* __restrict__ dst, int E, int* __restrict__ deg) {
    int e = blockIdx.x * 256 + threadIdx.x;
    if (e < E) atomicAdd(&deg[dst[e]], 1);
}

// ---------------- device-wide scan, stage 1: per-block reduce ----------------
__global__ __launch_bounds__(256) void k_part(const int* __restrict__ deg,
                                              int* __restrict__ part) {
    __shared__ int sm[4];
    const int t = threadIdx.x;
    const int base = blockIdx.x * SCAN_TILE + t * 4;
    int s = 0;
    if (base + 3 < NODES) {
        int4 v = *(const int4*)(deg + base);
        s = v.x + v.y + v.z + v.w;
    } else {
#pragma unroll
        for (int i = 0; i < 4; i++) if (base + i < NODES) s += deg[base + i];
    }
#pragma unroll
    for (int d = 1; d < 64; d <<= 1) s += __shfl_xor(s, d);
    if ((t & 63) == 0) sm[t >> 6] = s;
    __syncthreads();
    if (t == 0) part[blockIdx.x] = sm[0] + sm[1] + sm[2] + sm[3];
}

// ---------------- stage 2: single-wave scan of partials ----------------
__global__ __launch_bounds__(64) void k_scan_part(const int* __restrict__ part,
                                                  int* __restrict__ partpfx,
                                                  int* __restrict__ rowptr) {
    const int t = threadIdx.x;
    int v = (t < SCAN_BLOCKS) ? part[t] : 0;
    int incl = v;
#pragma unroll
    for (int d = 1; d < 64; d <<= 1) {
        int u = __shfl_up(incl, d);
        if (t >= d) incl += u;
    }
    if (t < SCAN_BLOCKS) partpfx[t] = incl - v;
    if (t == 63) rowptr[NODES] = incl;
}

// ---------------- stage 3: per-block scan + write rowptr/wp ----------------
__global__ __launch_bounds__(256) void k_scan_write(const int* __restrict__ deg,
                                                    const int* __restrict__ partpfx,
                                                    int* __restrict__ rowptr,
                                                    int* __restrict__ wp) {
    __shared__ int sm[4];
    const int t = threadIdx.x;
    const int lane = t & 63, w = t >> 6;
    const int base = blockIdx.x * SCAN_TILE + t * 4;
    int v0 = 0, v1 = 0, v2 = 0, v3 = 0;
    if (base + 3 < NODES) {
        int4 v = *(const int4*)(deg + base);
        v0 = v.x; v1 = v.y; v2 = v.z; v3 = v.w;
    } else {
        if (base + 0 < NODES) v0 = deg[base + 0];
        if (base + 1 < NODES) v1 = deg[base + 1];
        if (base + 2 < NODES) v2 = deg[base + 2];
        if (base + 3 < NODES) v3 = deg[base + 3];
    }
    const int s = v0 + v1 + v2 + v3;
    int incl = s;
#pragma unroll
    for (int d = 1; d < 64; d <<= 1) {
        int u = __shfl_up(incl, d);
        if (lane >= d) incl += u;
    }
    if (lane == 63) sm[w] = incl;
    __syncthreads();
    if (t == 0) {
        int r = 0;
#pragma unroll
        for (int i = 0; i < 4; i++) { int x = sm[i]; sm[i] = r; r += x; }
    }
    __syncthreads();
    int run = (incl - s) + sm[w] + partpfx[blockIdx.x];
    if (base + 3 < NODES) {
        int4 rp = make_int4(run, run + v0, run + v0 + v1, run + v0 + v1 + v2);
        *(int4*)(rowptr + base) = rp;
        *(int4*)(wp + base) = rp;
    } else {
        int r = run;
        if (base + 0 < NODES) { rowptr[base + 0] = r; wp[base + 0] = r; r += v0; }
        if (base + 1 < NODES) { rowptr[base + 1] = r; wp[base + 1] = r; r += v1; }
        if (base + 2 < NODES) { rowptr[base + 2] = r; wp[base + 2] = r; r += v2; }
        if (base + 3 < NODES) { rowptr[base + 3] = r; wp[base + 3] = r; r += v3; }
    }
}

// ---------------- scatter edges into CSR ----------------
__global__ void k_scatter(const int* __restrict__ src, const int* __restrict__ dst,
                          int E, int* __restrict__ wp, int* __restrict__ col) {
    int e = blockIdx.x * 256 + threadIdx.x;
    if (e < E) {
        int p = atomicAdd(&wp[dst[e]], 1);
        col[p] = src[e];
    }
}

// ---------------- layer-1 aggregation: one wave per dst node ----------------
__global__ __launch_bounds__(256) void k_agg1(const unsigned short* __restrict__ h1b,
                                              const float* __restrict__ as1,
                                              const float* __restrict__ ad1,
                                              const int* __restrict__ rowptr,
                                              const int* __restrict__ col,
                                              const float* __restrict__ b1,
                                              float* __restrict__ out1) {
    int wid = (blockIdx.x * 256 + threadIdx.x) >> 6;
    if (wid >= NODES) return;
    const int lane = threadIdx.x & 63;
    const int sub = lane & 15;
    const int head = lane >> 4;
    const int n = wid;
    const float adn = ad1[n * HEADS + head];
    const int rs = rowptr[n], re = rowptr[n + 1];
    const float e_self = lrelu(as1[n * HEADS + head] + adn);

    float m = e_self;
    float e0 = -INFINITY, e1 = -INFINITY;
    int   c0v = 0, c1v = 0;
    int ch = 0;
    for (int base = rs; base < re; base += 16, ch++) {
        int i = base + sub;
        float e = -INFINITY;
        int c = 0;
        if (i < re) {
            c = col[i];
            e = lrelu(as1[c * HEADS + head] + adn);
        }
        if (ch == 0)      { e0 = e; c0v = c; }
        else if (ch == 1) { e1 = e; c1v = c; }
        m = fmaxf(m, e);
    }
#pragma unroll
    for (int d = 1; d < 16; d <<= 1) m = fmaxf(m, __shfl_xor(m, d));

    const float wself = __expf(e_self - m);
    float den = (sub == 0) ? wself : 0.f;
    const int cc = lane * 2;
    ushort2 uself = *(const ushort2*)(h1b + (size_t)n * C1 + cc);
    float a0 = wself * bf2f(uself.x), a1 = wself * bf2f(uself.y);
    ch = 0;
    for (int base = rs; base < re; base += 16, ch++) {
        int i = base + sub;
        float e; int c;
        if (ch == 0)      { e = e0; c = c0v; }
        else if (ch == 1) { e = e1; c = c1v; }
        else {
            e = -INFINITY; c = 0;
            if (i < re) { c = col[i]; e = lrelu(as1[c * HEADS + head] + adn); }
        }
        float w = (i < re) ? __expf(e - m) : 0.f;
        den += w;
        int cnt = re - base; if (cnt > 16) cnt = 16;
        for (int j = 0; j < cnt; j++) {
            int lj = (lane & 48) | j;
            int   sj = __shfl(c, lj);
            float wj = __shfl(w, lj);
            ushort2 us = *(const ushort2*)(h1b + (size_t)sj * C1 + cc);
            a0 = fmaf(wj, bf2f(us.x), a0);
            a1 = fmaf(wj, bf2f(us.y), a1);
        }
    }
#pragma unroll
    for (int d = 1; d < 16; d <<= 1) den += __shfl_xor(den, d);
    float2 bv = *(const float2*)(b1 + cc);
    float o0 = a0 / den + bv.x;
    float o1 = a1 / den + bv.y;
    out1[(size_t)n * C1 + cc]     = fmaxf(o0, 0.f);
    out1[(size_t)n * C1 + cc + 1] = fmaxf(o1, 0.f);
}

// ---- GEMM2: h2[N,40](fp32) + h2b[N,64-stride](bf16) = out1 @ W2 ----
__global__ __launch_bounds__(320) void k_gemm2(const float* __restrict__ A,
                                               const float* __restrict__ W,
                                               float* __restrict__ H,
                                               unsigned short* __restrict__ h2b) {
    __shared__ float xs[64][132];
    __shared__ float ws2[128 * 40];
    const int tid = threadIdx.x;
    const int row0 = blockIdx.x * 64;
    for (int q = tid; q < 1280; q += 320)
        *(float4*)(ws2 + q * 4) = *(const float4*)(W + q * 4);
    for (int q = tid; q < 2048; q += 320) {
        int r = q >> 5, kq = (q & 31) * 4;
        int gr = row0 + r;
        float4 v = make_float4(0.f, 0.f, 0.f, 0.f);
        if (gr < NODES) v = *(const float4*)(A + (size_t)gr * FIN + kq);
        *(float4*)(&xs[r][kq]) = v;
    }
    __syncthreads();
    const int r = tid / 5;
    const int c0 = (tid % 5) * 8;
    float acc[8];
#pragma unroll
    for (int j = 0; j < 8; j++) acc[j] = 0.f;
    for (int k = 0; k < 128; k++) {
        float a = xs[r][k];
        float4 b0 = *(float4*)(ws2 + k * CLS + c0);
        float4 b1 = *(float4*)(ws2 + k * CLS + c0 + 4);
        acc[0] = fmaf(a, b0.x, acc[0]); acc[1] = fmaf(a, b0.y, acc[1]);
        acc[2] = fmaf(a, b0.z, acc[2]); acc[3] = fmaf(a, b0.w, acc[3]);
        acc[4] = fmaf(a, b1.x, acc[4]); acc[5] = fmaf(a, b1.y, acc[5]);
        acc[6] = fmaf(a, b1.z, acc[6]); acc[7] = fmaf(a, b1.w, acc[7]);
    }
    int gr = row0 + r;
    if (gr < NODES) {
        *(float4*)(H + (size_t)gr * CLS + c0) =
            make_float4(acc[0], acc[1], acc[2], acc[3]);
        *(float4*)(H + (size_t)gr * CLS + c0 + 4) =
            make_float4(acc[4], acc[5], acc[6], acc[7]);
        unsigned short tb[8];
#pragma unroll
        for (int j = 0; j < 8; j++) tb[j] = f2bf(acc[j]);
        uint4 pk;
        pk.x = (unsigned)tb[0] | ((unsigned)tb[1] << 16);
        pk.y = (unsigned)tb[2] | ((unsigned)tb[3] << 16);
        pk.z = (unsigned)tb[4] | ((unsigned)tb[5] << 16);
        pk.w = (unsigned)tb[6] | ((unsigned)tb[7] << 16);
        *(uint4*)(h2b + (size_t)gr * 64 + c0) = pk;
    }
}

// ---------------- per-node attention dots, layer 2 (fp32-exact) ----------------
__global__ void k_att2(const float* __restrict__ H2, const float* __restrict__ AS,
                       const float* __restrict__ AD, float* __restrict__ as2,
                       float* __restrict__ ad2) {
    int n = blockIdx.x * 256 + threadIdx.x;
    if (n >= NODES) return;
    const float* hp = H2 + (size_t)n * CLS;
    float s = 0.f, d = 0.f;
#pragma unroll
    for (int c = 0; c < CLS; c++) {
        float v = hp[c];
        s = fmaf(v, AS[c], s);
        d = fmaf(v, AD[c], d);
    }
    as2[n] = s;
    ad2[n] = d;
}

// ---------------- layer-2 aggregation: one wave per dst node ----------------
// features bf16 (stride 64); lanes ll<20 of each 32-half own 2 classes; 2 edges/iter.
__global__ __launch_bounds__(256) void k_agg2(const unsigned short* __restrict__ h2b,
                                              const float* __restrict__ as2,
                                              const float* __restrict__ ad2,
                                              const int* __restrict__ rowptr,
                                              const int* __restrict__ col,
                                              const float* __restrict__ b2,
                                              float* __restrict__ out) {
    int wid = (blockIdx.x * 256 + threadIdx.x) >> 6;
    if (wid >= NODES) return;
    const int lane = threadIdx.x & 63;
    const int half = lane >> 5, ll = lane & 31;
    const int n = wid;
    const float adn = ad2[n];
    const int rs = rowptr[n], re = rowptr[n + 1];
    const float e_self = lrelu(as2[n] + adn);

    float m = e_self;
    float e0 = -INFINITY, e1 = -INFINITY;
    int   c0v = 0, c1v = 0;
    int ch = 0;
    for (int base = rs; base < re; base += 64, ch++) {
        int i = base + lane;
        float e = -INFINITY;
        int c = 0;
        if (i < re) {
            c = col[i];
            e = lrelu(as2[c] + adn);
        }
        if (ch == 0)      { e0 = e; c0v = c; }
        else if (ch == 1) { e1 = e; c1v = c; }
        m = fmaxf(m, e);
    }
#pragma unroll
    for (int d = 1; d < 64; d <<= 1) m = fmaxf(m, __shfl_xor(m, d));

    const float wself = __expf(e_self - m);
    float den = (lane == 0) ? wself : 0.f;
    float ac0 = 0.f, ac1 = 0.f;
    if (half == 0 && ll < 20) {
        ushort2 uv = *(const ushort2*)(h2b + (size_t)n * 64 + ll * 2);
        ac0 = wself * bf2f(uv.x);
        ac1 = wself * bf2f(uv.y);
    }
    ch = 0;
    for (int base = rs; base < re; base += 64, ch++) {
        int i = base + lane;
        float e; int c;
        if (ch == 0)      { e = e0; c = c0v; }
        else if (ch == 1) { e = e1; c = c1v; }
        else {
            e = -INFINITY; c = 0;
            if (i < re) { c = col[i]; e = lrelu(as2[c] + adn); }
        }
        float w = (i < re) ? __expf(e - m) : 0.f;
        den += w;
        int cnt = re - base; if (cnt > 64) cnt = 64;
        for (int j = 0; j < cnt; j += 2) {
            int jj = j + half;              // edges beyond cnt carry w=0 -> harmless
            int   sj = __shfl(c, jj);
            float wj = __shfl(w, jj);
            if (ll < 20) {
                ushort2 uv = *(const ushort2*)(h2b + (size_t)sj * 64 + ll * 2);
                ac0 = fmaf(wj, bf2f(uv.x), ac0);
                ac1 = fmaf(wj, bf2f(uv.y), ac1);
            }
        }
    }
    ac0 += __shfl_xor(ac0, 32);
    ac1 += __shfl_xor(ac1, 32);
#pragma unroll
    for (int d = 1; d < 64; d <<= 1) den += __shfl_xor(den, d);
    if (half == 0 && ll < 20) {
        float2 bv = *(const float2*)(b2 + ll * 2);
        *(float2*)(out + (size_t)n * CLS + ll * 2) =
            make_float2(ac0 / den + bv.x, ac1 / den + bv.y);
    }
}

extern "C" void kernel_launch(void* const* d_in, const int* in_sizes, int n_in,
                              void* d_out, int out_size, void* d_ws, size_t ws_size,
                              hipStream_t stream) {
    const float* x     = (const float*)d_in[0];
    const int*   ei    = (const int*)d_in[1];
    const float* W1    = (const float*)d_in[2];
    const float* aS1   = (const float*)d_in[3];
    const float* aD1   = (const float*)d_in[4];
    const float* b1    = (const float*)d_in[5];
    const float* W2    = (const float*)d_in[6];
    const float* aS2   = (const float*)d_in[7];
    const float* aD2   = (const float*)d_in[8];
    const float* b2    = (const float*)d_in[9];
    float* out = (float*)d_out;
    const int E = in_sizes[1] / 2;
    const int* src = ei;
    const int* dst = ei + E;

    char* ws = (char*)d_ws;
    size_t off = 0;
    auto alloc = [&](size_t bytes) -> char* {
        char* p = ws + off;
        off += (bytes + 255) & ~(size_t)255;
        return p;
    };
    unsigned short* h1b = (unsigned short*)alloc((size_t)NODES * C1 * 2);
    float* out1   = (float*)alloc((size_t)NODES * C1 * 4);
    float* h2     = (float*)alloc((size_t)NODES * CLS * 4);
    unsigned short* h2b = (unsigned short*)alloc((size_t)NODES * 64 * 2);
    float* as1    = (float*)alloc((size_t)NODES * HEADS * 4);
    float* ad1    = (float*)alloc((size_t)NODES * HEADS * 4);
    float* as2    = (float*)alloc((size_t)NODES * 4);
    float* ad2    = (float*)alloc((size_t)NODES * 4);
    int* deg      = (int*)alloc((size_t)NODES * 4);
    int* rowptr   = (int*)alloc((size_t)(NODES + 1) * 4);
    int* wp       = (int*)alloc((size_t)NODES * 4);
    int* col      = (int*)alloc((size_t)E * 4);
    int* part     = (int*)alloc((size_t)SCAN_BLOCKS * 4);
    int* partpfx  = (int*)alloc((size_t)SCAN_BLOCKS * 4);

    k_zero<<<(NODES + 255) / 256, 256, 0, stream>>>(deg, NODES);
    k_gemm1<<<(NODES + 63) / 64, 256, 0, stream>>>(x, W1, aS1, aD1, h1b, as1, ad1);
    k_hist<<<(E + 255) / 256, 256, 0, stream>>>(dst, E, deg);
    k_part<<<SCAN_BLOCKS, 256, 0, stream>>>(deg, part);
    k_scan_part<<<1, 64, 0, stream>>>(part, partpfx, rowptr);
    k_scan_write<<<SCAN_BLOCKS, 256, 0, stream>>>(deg, partpfx, rowptr, wp);
    k_scatter<<<(E + 255) / 256, 256, 0, stream>>>(src, dst, E, wp, col);
    k_agg1<<<(NODES * 64) / 256, 256, 0, stream>>>(h1b, as1, ad1, rowptr, col, b1, out1);
    k_gemm2<<<(NODES + 63) / 64, 320, 0, stream>>>(out1, W2, h2, h2b);
    k_att2<<<(NODES + 255) / 256, 256, 0, stream>>>(h2, aS2, aD2, as2, ad2);
    k_agg2<<<(NODES * 64) / 256, 256, 0, stream>>>(h2b, as2, ad2, rowptr, col, b2, out);
}

// Round 5
// 307.305 us; speedup vs baseline: 1.9756x; 1.0893x over previous
//
#include <hip/hip_runtime.h>
#include <cstdint>

#define NODES 50000
#define FIN   128
#define C1    128   // HEADS*HID
#define HEADS 4
#define HID   32
#define CLS   40
#define SLOPE 0.2f

#define SCAN_TILE 1024
#define SCAN_BLOCKS ((NODES + SCAN_TILE - 1) / SCAN_TILE)   // 49

__device__ __forceinline__ float lrelu(float v) { return v > 0.f ? v : SLOPE * v; }

// bf16 helpers (RNE pack, exact unpack)
__device__ __forceinline__ unsigned short f2bf(float f) {
    union { float f; unsigned u; } v; v.f = f;
    unsigned u = v.u;
    return (unsigned short)((u + 0x7FFFu + ((u >> 16) & 1u)) >> 16);
}
__device__ __forceinline__ float bflo(unsigned u) {
    union { unsigned x; float f; } v; v.x = u << 16; return v.f;
}
__device__ __forceinline__ float bfhi(unsigned u) {
    union { unsigned x; float f; } v; v.x = u & 0xffff0000u; return v.f;
}

// ---------------- zero int buffer ----------------
__global__ void k_zero(int* __restrict__ p, int n) {
    int i = blockIdx.x * 256 + threadIdx.x;
    if (i < n) p[i] = 0;
}

// ---- GEMM1: h1b[N,128](bf16) = x @ W1 ; also as1/ad1 from fp32 acc ----
__global__ __launch_bounds__(256) void k_gemm1(const float* __restrict__ X,
                                               const float* __restrict__ W,
                                               const float* __restrict__ AS,
                                               const float* __restrict__ AD,
                                               unsigned short* __restrict__ h1b,
                                               float* __restrict__ as1,
                                               float* __restrict__ ad1) {
    __shared__ float As[64][17];
    __shared__ float Bs[16][128];
    const int tid = threadIdx.x;
    const int tx = tid & 15, ty = tid >> 4;
    const int row0 = blockIdx.x * 64;
    float acc[4][8];
#pragma unroll
    for (int i = 0; i < 4; i++)
#pragma unroll
        for (int j = 0; j < 8; j++) acc[i][j] = 0.f;

    for (int k0 = 0; k0 < FIN; k0 += 16) {
        {
            int r = tid >> 2, kq = (tid & 3) * 4;
            int gr = row0 + r;
            float4 va = make_float4(0.f, 0.f, 0.f, 0.f);
            if (gr < NODES) va = *(const float4*)(X + (size_t)gr * FIN + k0 + kq);
            As[r][kq + 0] = va.x; As[r][kq + 1] = va.y;
            As[r][kq + 2] = va.z; As[r][kq + 3] = va.w;
        }
#pragma unroll
        for (int i = 0; i < 2; i++) {
            int qq = tid * 2 + i;
            int rr = qq >> 5, cq = (qq & 31) * 4;
            *(float4*)(&Bs[rr][cq]) = *(const float4*)(W + (size_t)(k0 + rr) * C1 + cq);
        }
        __syncthreads();
#pragma unroll
        for (int kk = 0; kk < 16; kk++) {
            float a[4];
#pragma unroll
            for (int i = 0; i < 4; i++) a[i] = As[ty * 4 + i][kk];
            float4 b0 = *(float4*)(&Bs[kk][tx * 8]);
            float4 b1 = *(float4*)(&Bs[kk][tx * 8 + 4]);
            float b[8] = {b0.x, b0.y, b0.z, b0.w, b1.x, b1.y, b1.z, b1.w};
#pragma unroll
            for (int i = 0; i < 4; i++)
#pragma unroll
                for (int j = 0; j < 8; j++) acc[i][j] = fmaf(a[i], b[j], acc[i][j]);
        }
        __syncthreads();
    }
#pragma unroll
    for (int i = 0; i < 4; i++) {
        int gr = row0 + ty * 4 + i;
        if (gr < NODES) {
            unsigned short tb[8];
#pragma unroll
            for (int j = 0; j < 8; j++) tb[j] = f2bf(acc[i][j]);
            uint4 pk;
            pk.x = (unsigned)tb[0] | ((unsigned)tb[1] << 16);
            pk.y = (unsigned)tb[2] | ((unsigned)tb[3] << 16);
            pk.z = (unsigned)tb[4] | ((unsigned)tb[5] << 16);
            pk.w = (unsigned)tb[6] | ((unsigned)tb[7] << 16);
            *(uint4*)(h1b + (size_t)gr * C1 + tx * 8) = pk;
        }
    }
    const int h = tx >> 2;
    const int co = (tx & 3) * 8;
    float ps[4], pd[4];
#pragma unroll
    for (int i = 0; i < 4; i++) {
        float s = 0.f, d = 0.f;
#pragma unroll
        for (int j = 0; j < 8; j++) {
            s = fmaf(acc[i][j], AS[h * HID + co + j], s);
            d = fmaf(acc[i][j], AD[h * HID + co + j], d);
        }
        ps[i] = s; pd[i] = d;
    }
#pragma unroll
    for (int i = 0; i < 4; i++) {
        ps[i] += __shfl_xor(ps[i], 1); ps[i] += __shfl_xor(ps[i], 2);
        pd[i] += __shfl_xor(pd[i], 1); pd[i] += __shfl_xor(pd[i], 2);
    }
    if ((tx & 3) == 0) {
#pragma unroll
        for (int i = 0; i < 4; i++) {
            int gr = row0 + ty * 4 + i;
            if (gr < NODES) {
                as1[gr * HEADS + h] = ps[i];
                ad1[gr * HEADS + h] = pd[i];
            }
        }
    }
}

// ---------------- degree histogram ----------------
__global__ void k_hist(const int* __restrict__ dst, int E, int* __restrict__ deg) {
    int e = blockIdx.x * 256 + threadIdx.x;
    if (e < E) atomicAdd(&deg[dst[e]], 1);
}

// ---------------- device-wide scan, stage 1: per-block reduce ----------------
__global__ __launch_bounds__(256) void k_part(const int* __restrict__ deg,
                                              int* __restrict__ part) {
    __shared__ int sm[4];
    const int t = threadIdx.x;
    const int base = blockIdx.x * SCAN_TILE + t * 4;
    int s = 0;
    if (base + 3 < NODES) {
        int4 v = *(const int4*)(deg + base);
        s = v.x + v.y + v.z + v.w;
    } else {
#pragma unroll
        for (int i = 0; i < 4; i++) if (base + i < NODES) s += deg[base + i];
    }
#pragma unroll
    for (int d = 1; d < 64; d <<= 1) s += __shfl_xor(s, d);
    if ((t & 63) == 0) sm[t >> 6] = s;
    __syncthreads();
    if (t == 0) part[blockIdx.x] = sm[0] + sm[1] + sm[2] + sm[3];
}

// ---------------- stage 2: single-wave scan of partials ----------------
__global__ __launch_bounds__(64) void k_scan_part(const int* __restrict__ part,
                                                  int* __restrict__ partpfx,
                                                  int* __restrict__ rowptr) {
    const int t = threadIdx.x;
    int v = (t < SCAN_BLOCKS) ? part[t] : 0;
    int incl = v;
#pragma unroll
    for (int d = 1; d < 64; d <<= 1) {
        int u = __shfl_up(incl, d);
        if (t >= d) incl += u;
    }
    if (t < SCAN_BLOCKS) partpfx[t] = incl - v;
    if (t == 63) rowptr[NODES] = incl;
}

// ---------------- stage 3: per-block scan + write rowptr/wp ----------------
__global__ __launch_bounds__(256) void k_scan_write(const int* __restrict__ deg,
                                                    const int* __restrict__ partpfx,
                                                    int* __restrict__ rowptr,
                                                    int* __restrict__ wp) {
    __shared__ int sm[4];
    const int t = threadIdx.x;
    const int lane = t & 63, w = t >> 6;
    const int base = blockIdx.x * SCAN_TILE + t * 4;
    int v0 = 0, v1 = 0, v2 = 0, v3 = 0;
    if (base + 3 < NODES) {
        int4 v = *(const int4*)(deg + base);
        v0 = v.x; v1 = v.y; v2 = v.z; v3 = v.w;
    } else {
        if (base + 0 < NODES) v0 = deg[base + 0];
        if (base + 1 < NODES) v1 = deg[base + 1];
        if (base + 2 < NODES) v2 = deg[base + 2];
        if (base + 3 < NODES) v3 = deg[base + 3];
    }
    const int s = v0 + v1 + v2 + v3;
    int incl = s;
#pragma unroll
    for (int d = 1; d < 64; d <<= 1) {
        int u = __shfl_up(incl, d);
        if (lane >= d) incl += u;
    }
    if (lane == 63) sm[w] = incl;
    __syncthreads();
    if (t == 0) {
        int r = 0;
#pragma unroll
        for (int i = 0; i < 4; i++) { int x = sm[i]; sm[i] = r; r += x; }
    }
    __syncthreads();
    int run = (incl - s) + sm[w] + partpfx[blockIdx.x];
    if (base + 3 < NODES) {
        int4 rp = make_int4(run, run + v0, run + v0 + v1, run + v0 + v1 + v2);
        *(int4*)(rowptr + base) = rp;
        *(int4*)(wp + base) = rp;
    } else {
        int r = run;
        if (base + 0 < NODES) { rowptr[base + 0] = r; wp[base + 0] = r; r += v0; }
        if (base + 1 < NODES) { rowptr[base + 1] = r; wp[base + 1] = r; r += v1; }
        if (base + 2 < NODES) { rowptr[base + 2] = r; wp[base + 2] = r; r += v2; }
        if (base + 3 < NODES) { rowptr[base + 3] = r; wp[base + 3] = r; r += v3; }
    }
}

// ---------------- scatter edges into CSR ----------------
__global__ void k_scatter(const int* __restrict__ src, const int* __restrict__ dst,
                          int E, int* __restrict__ wp, int* __restrict__ col) {
    int e = blockIdx.x * 256 + threadIdx.x;
    if (e < E) {
        int p = atomicAdd(&wp[dst[e]], 1);
        col[p] = src[e];
    }
}

// ---------------- layer-1 aggregation: one wave per dst node ----------------
// attention pass: lane = head*16 + sub (per-edge-per-head scores, 16-edge chunks).
// feature pass: lane = q*16 + ll; edge slot q (4 edges/iter), channels ll*8..+7,
// uint4 (8 bf16) gathers; cross-slot reduce via shfl_xor(16|32).
__global__ __launch_bounds__(256) void k_agg1(const unsigned short* __restrict__ h1b,
                                              const float* __restrict__ as1,
                                              const float* __restrict__ ad1,
                                              const int* __restrict__ rowptr,
                                              const int* __restrict__ col,
                                              const float* __restrict__ b1,
                                              float* __restrict__ out1) {
    int wid = (blockIdx.x * 256 + threadIdx.x) >> 6;
    if (wid >= NODES) return;
    const int lane = threadIdx.x & 63;
    const int sub = lane & 15;
    const int head = lane >> 4;
    const int q  = lane >> 4;       // feature edge slot
    const int ll = lane & 15;       // feature channel group (8 ch)
    const int fh = ll >> 2;         // head owning channels ll*8
    const int n = wid;
    const float adn = ad1[n * HEADS + head];
    const int rs = rowptr[n], re = rowptr[n + 1];
    const float e_self = lrelu(as1[n * HEADS + head] + adn);

    // pass 1: lane-parallel max (16-edge chunks), buffer first 2 chunks
    float m = e_self;
    float e0 = -INFINITY, e1 = -INFINITY;
    int   c0v = 0, c1v = 0;
    int ch = 0;
    for (int base = rs; base < re; base += 16, ch++) {
        int i = base + sub;
        float e = -INFINITY;
        int c = 0;
        if (i < re) {
            c = col[i];
            e = lrelu(as1[c * HEADS + head] + adn);
        }
        if (ch == 0)      { e0 = e; c0v = c; }
        else if (ch == 1) { e1 = e; c1v = c; }
        m = fmaxf(m, e);
    }
#pragma unroll
    for (int d = 1; d < 16; d <<= 1) m = fmaxf(m, __shfl_xor(m, d));

    const float wself = __expf(e_self - m);
    float den = (sub == 0) ? wself : 0.f;
    float ac[8];
#pragma unroll
    for (int k = 0; k < 8; k++) ac[k] = 0.f;

    ch = 0;
    for (int base = rs; base < re; base += 16, ch++) {
        int i = base + sub;
        float e; int c;
        if (ch == 0)      { e = e0; c = c0v; }
        else if (ch == 1) { e = e1; c = c1v; }
        else {
            e = -INFINITY; c = 0;
            if (i < re) { c = col[i]; e = lrelu(as1[c * HEADS + head] + adn); }
        }
        float w = (i < re) ? __expf(e - m) : 0.f;
        den += w;
        int cnt = re - base; if (cnt > 16) cnt = 16;
        for (int j = 0; j < cnt; j += 4) {
            int jj = j + q;                    // <= 15 always
            int sl = fh * 16 + jj;
            int   sj = __shfl(c, sl);
            float wj = __shfl(w, sl);          // 0 for jj >= cnt
            uint4 pk = *(const uint4*)(h1b + (size_t)sj * C1 + ll * 8);
            ac[0] = fmaf(wj, bflo(pk.x), ac[0]); ac[1] = fmaf(wj, bfhi(pk.x), ac[1]);
            ac[2] = fmaf(wj, bflo(pk.y), ac[2]); ac[3] = fmaf(wj, bfhi(pk.y), ac[3]);
            ac[4] = fmaf(wj, bflo(pk.z), ac[4]); ac[5] = fmaf(wj, bfhi(pk.z), ac[5]);
            ac[6] = fmaf(wj, bflo(pk.w), ac[6]); ac[7] = fmaf(wj, bfhi(pk.w), ac[7]);
        }
    }
#pragma unroll
    for (int d = 1; d < 16; d <<= 1) den += __shfl_xor(den, d);
    const float den_f = __shfl(den, fh * 16);
    const float ws_f  = __shfl(wself, fh * 16);
#pragma unroll
    for (int k = 0; k < 8; k++) {
        ac[k] += __shfl_xor(ac[k], 16);
        ac[k] += __shfl_xor(ac[k], 32);
    }
    if (q == 0) {
        uint4 sp = *(const uint4*)(h1b + (size_t)n * C1 + ll * 8);
        float sv[8] = {bflo(sp.x), bfhi(sp.x), bflo(sp.y), bfhi(sp.y),
                       bflo(sp.z), bfhi(sp.z), bflo(sp.w), bfhi(sp.w)};
        float4 bv0 = *(const float4*)(b1 + ll * 8);
        float4 bv1 = *(const float4*)(b1 + ll * 8 + 4);
        float bb[8] = {bv0.x, bv0.y, bv0.z, bv0.w, bv1.x, bv1.y, bv1.z, bv1.w};
        float o[8];
#pragma unroll
        for (int k = 0; k < 8; k++)
            o[k] = fmaxf((ac[k] + ws_f * sv[k]) / den_f + bb[k], 0.f);
        *(float4*)(out1 + (size_t)n * C1 + ll * 8) =
            make_float4(o[0], o[1], o[2], o[3]);
        *(float4*)(out1 + (size_t)n * C1 + ll * 8 + 4) =
            make_float4(o[4], o[5], o[6], o[7]);
    }
}

// ---- GEMM2: h2[N,40](fp32) + h2b[N,64-stride](bf16) = out1 @ W2 ----
__global__ __launch_bounds__(320) void k_gemm2(const float* __restrict__ A,
                                               const float* __restrict__ W,
                                               float* __restrict__ H,
                                               unsigned short* __restrict__ h2b) {
    __shared__ float xs[64][132];
    __shared__ float ws2[128 * 40];
    const int tid = threadIdx.x;
    const int row0 = blockIdx.x * 64;
    for (int q = tid; q < 1280; q += 320)
        *(float4*)(ws2 + q * 4) = *(const float4*)(W + q * 4);
    for (int q = tid; q < 2048; q += 320) {
        int r = q >> 5, kq = (q & 31) * 4;
        int gr = row0 + r;
        float4 v = make_float4(0.f, 0.f, 0.f, 0.f);
        if (gr < NODES) v = *(const float4*)(A + (size_t)gr * FIN + kq);
        *(float4*)(&xs[r][kq]) = v;
    }
    __syncthreads();
    const int r = tid / 5;
    const int c0 = (tid % 5) * 8;
    float acc[8];
#pragma unroll
    for (int j = 0; j < 8; j++) acc[j] = 0.f;
    for (int k = 0; k < 128; k++) {
        float a = xs[r][k];
        float4 b0 = *(float4*)(ws2 + k * CLS + c0);
        float4 b1 = *(float4*)(ws2 + k * CLS + c0 + 4);
        acc[0] = fmaf(a, b0.x, acc[0]); acc[1] = fmaf(a, b0.y, acc[1]);
        acc[2] = fmaf(a, b0.z, acc[2]); acc[3] = fmaf(a, b0.w, acc[3]);
        acc[4] = fmaf(a, b1.x, acc[4]); acc[5] = fmaf(a, b1.y, acc[5]);
        acc[6] = fmaf(a, b1.z, acc[6]); acc[7] = fmaf(a, b1.w, acc[7]);
    }
    int gr = row0 + r;
    if (gr < NODES) {
        *(float4*)(H + (size_t)gr * CLS + c0) =
            make_float4(acc[0], acc[1], acc[2], acc[3]);
        *(float4*)(H + (size_t)gr * CLS + c0 + 4) =
            make_float4(acc[4], acc[5], acc[6], acc[7]);
        unsigned short tb[8];
#pragma unroll
        for (int j = 0; j < 8; j++) tb[j] = f2bf(acc[j]);
        uint4 pk;
        pk.x = (unsigned)tb[0] | ((unsigned)tb[1] << 16);
        pk.y = (unsigned)tb[2] | ((unsigned)tb[3] << 16);
        pk.z = (unsigned)tb[4] | ((unsigned)tb[5] << 16);
        pk.w = (unsigned)tb[6] | ((unsigned)tb[7] << 16);
        *(uint4*)(h2b + (size_t)gr * 64 + c0) = pk;
    }
}

// ---------------- per-node attention dots, layer 2 (fp32-exact) ----------------
__global__ void k_att2(const float* __restrict__ H2, const float* __restrict__ AS,
                       const float* __restrict__ AD, float* __restrict__ as2,
                       float* __restrict__ ad2) {
    int n = blockIdx.x * 256 + threadIdx.x;
    if (n >= NODES) return;
    const float* hp = H2 + (size_t)n * CLS;
    float s = 0.f, d = 0.f;
#pragma unroll
    for (int c = 0; c < CLS; c++) {
        float v = hp[c];
        s = fmaf(v, AS[c], s);
        d = fmaf(v, AD[c], d);
    }
    as2[n] = s;
    ad2[n] = d;
}

// ---------------- layer-2 aggregation: one wave per dst node ----------------
// feature pass: lane = q8*8 + l8; 8 edge slots, l8<5 own channels l8*8..+7 (bf16).
__global__ __launch_bounds__(256) void k_agg2(const unsigned short* __restrict__ h2b,
                                              const float* __restrict__ as2,
                                              const float* __restrict__ ad2,
                                              const int* __restrict__ rowptr,
                                              const int* __restrict__ col,
                                              const float* __restrict__ b2,
                                              float* __restrict__ out) {
    int wid = (blockIdx.x * 256 + threadIdx.x) >> 6;
    if (wid >= NODES) return;
    const int lane = threadIdx.x & 63;
    const int q8 = lane >> 3, l8 = lane & 7;
    const int n = wid;
    const float adn = ad2[n];
    const int rs = rowptr[n], re = rowptr[n + 1];
    const float e_self = lrelu(as2[n] + adn);

    float m = e_self;
    float e0 = -INFINITY, e1 = -INFINITY;
    int   c0v = 0, c1v = 0;
    int ch = 0;
    for (int base = rs; base < re; base += 64, ch++) {
        int i = base + lane;
        float e = -INFINITY;
        int c = 0;
        if (i < re) {
            c = col[i];
            e = lrelu(as2[c] + adn);
        }
        if (ch == 0)      { e0 = e; c0v = c; }
        else if (ch == 1) { e1 = e; c1v = c; }
        m = fmaxf(m, e);
    }
#pragma unroll
    for (int d = 1; d < 64; d <<= 1) m = fmaxf(m, __shfl_xor(m, d));

    const float wself = __expf(e_self - m);
    float den = (lane == 0) ? wself : 0.f;
    float ac[8];
#pragma unroll
    for (int k = 0; k < 8; k++) ac[k] = 0.f;
    ch = 0;
    for (int base = rs; base < re; base += 64, ch++) {
        int i = base + lane;
        float e; int c;
        if (ch == 0)      { e = e0; c = c0v; }
        else if (ch == 1) { e = e1; c = c1v; }
        else {
            e = -INFINITY; c = 0;
            if (i < re) { c = col[i]; e = lrelu(as2[c] + adn); }
        }
        float w = (i < re) ? __expf(e - m) : 0.f;
        den += w;
        int cnt = re - base; if (cnt > 64) cnt = 64;
        for (int j = 0; j < cnt; j += 8) {
            int jj = j + q8;                   // <= 63 always
            int   sj = __shfl(c, jj);
            float wj = __shfl(w, jj);          // 0 for jj >= cnt
            if (l8 < 5) {
                uint4 pk = *(const uint4*)(h2b + (size_t)sj * 64 + l8 * 8);
                ac[0] = fmaf(wj, bflo(pk.x), ac[0]); ac[1] = fmaf(wj, bfhi(pk.x), ac[1]);
                ac[2] = fmaf(wj, bflo(pk.y), ac[2]); ac[3] = fmaf(wj, bfhi(pk.y), ac[3]);
                ac[4] = fmaf(wj, bflo(pk.z), ac[4]); ac[5] = fmaf(wj, bfhi(pk.z), ac[5]);
                ac[6] = fmaf(wj, bflo(pk.w), ac[6]); ac[7] = fmaf(wj, bfhi(pk.w), ac[7]);
            }
        }
    }
#pragma unroll
    for (int d = 1; d < 64; d <<= 1) den += __shfl_xor(den, d);
#pragma unroll
    for (int k = 0; k < 8; k++) {
        ac[k] += __shfl_xor(ac[k], 8);
        ac[k] += __shfl_xor(ac[k], 16);
        ac[k] += __shfl_xor(ac[k], 32);
    }
    if (q8 == 0 && l8 < 5) {
        uint4 sp = *(const uint4*)(h2b + (size_t)n * 64 + l8 * 8);
        float sv[8] = {bflo(sp.x), bfhi(sp.x), bflo(sp.y), bfhi(sp.y),
                       bflo(sp.z), bfhi(sp.z), bflo(sp.w), bfhi(sp.w)};
        float4 bv0 = *(const float4*)(b2 + l8 * 8);
        float4 bv1 = *(const float4*)(b2 + l8 * 8 + 4);
        float bb[8] = {bv0.x, bv0.y, bv0.z, bv0.w, bv1.x, bv1.y, bv1.z, bv1.w};
        float o[8];
#pragma unroll
        for (int k = 0; k < 8; k++)
            o[k] = (ac[k] + wself * sv[k]) / den + bb[k];
        *(float4*)(out + (size_t)n * CLS + l8 * 8) =
            make_float4(o[0], o[1], o[2], o[3]);
        *(float4*)(out + (size_t)n * CLS + l8 * 8 + 4) =
            make_float4(o[4], o[5], o[6], o[7]);
    }
}

extern "C" void kernel_launch(void* const* d_in, const int* in_sizes, int n_in,
                              void* d_out, int out_size, void* d_ws, size_t ws_size,
                              hipStream_t stream) {
    const float* x     = (const float*)d_in[0];
    const int*   ei    = (const int*)d_in[1];
    const float* W1    = (const float*)d_in[2];
    const float* aS1   = (const float*)d_in[3];
    const float* aD1   = (const float*)d_in[4];
    const float* b1    = (const float*)d_in[5];
    const float* W2    = (const float*)d_in[6];
    const float* aS2   = (const float*)d_in[7];
    const float* aD2   = (const float*)d_in[8];
    const float* b2    = (const float*)d_in[9];
    float* out = (float*)d_out;
    const int E = in_sizes[1] / 2;
    const int* src = ei;
    const int* dst = ei + E;

    char* ws = (char*)d_ws;
    size_t off = 0;
    auto alloc = [&](size_t bytes) -> char* {
        char* p = ws + off;
        off += (bytes + 255) & ~(size_t)255;
        return p;
    };
    unsigned short* h1b = (unsigned short*)alloc((size_t)NODES * C1 * 2);
    float* out1   = (float*)alloc((size_t)NODES * C1 * 4);
    float* h2     = (float*)alloc((size_t)NODES * CLS * 4);
    unsigned short* h2b = (unsigned short*)alloc((size_t)NODES * 64 * 2);
    float* as1    = (float*)alloc((size_t)NODES * HEADS * 4);
    float* ad1    = (float*)alloc((size_t)NODES * HEADS * 4);
    float* as2    = (float*)alloc((size_t)NODES * 4);
    float* ad2    = (float*)alloc((size_t)NODES * 4);
    int* deg      = (int*)alloc((size_t)NODES * 4);
    int* rowptr   = (int*)alloc((size_t)(NODES + 1) * 4);
    int* wp       = (int*)alloc((size_t)NODES * 4);
    int* col      = (int*)alloc((size_t)E * 4);
    int* part     = (int*)alloc((size_t)SCAN_BLOCKS * 4);
    int* partpfx  = (int*)alloc((size_t)SCAN_BLOCKS * 4);

    k_zero<<<(NODES + 255) / 256, 256, 0, stream>>>(deg, NODES);
    k_gemm1<<<(NODES + 63) / 64, 256, 0, stream>>>(x, W1, aS1, aD1, h1b, as1, ad1);
    k_hist<<<(E + 255) / 256, 256, 0, stream>>>(dst, E, deg);
    k_part<<<SCAN_BLOCKS, 256, 0, stream>>>(deg, part);
    k_scan_part<<<1, 64, 0, stream>>>(part, partpfx, rowptr);
    k_scan_write<<<SCAN_BLOCKS, 256, 0, stream>>>(deg, partpfx, rowptr, wp);
    k_scatter<<<(E + 255) / 256, 256, 0, stream>>>(src, dst, E, wp, col);
    k_agg1<<<(NODES * 64) / 256, 256, 0, stream>>>(h1b, as1, ad1, rowptr, col, b1, out1);
    k_gemm2<<<(NODES + 63) / 64, 320, 0, stream>>>(out1, W2, h2, h2b);
    k_att2<<<(NODES + 255) / 256, 256, 0, stream>>>(h2, aS2, aD2, as2, ad2);
    k_agg2<<<(NODES * 64) / 256, 256, 0, stream>>>(h2b, as2, ad2, rowptr, col, b2, out);
}

// Round 6
// 285.526 us; speedup vs baseline: 2.1263x; 1.0763x over previous
//
#include <hip/hip_runtime.h>
#include <cstdint>

#define NODES 50000
#define FIN   128
#define C1    128   // HEADS*HID
#define HEADS 4
#define HID   32
#define CLS   40
#define SLOPE 0.2f

#define SCAN_TILE 1024
#define SCAN_BLOCKS ((NODES + SCAN_TILE - 1) / SCAN_TILE)   // 49
#define NBUCK ((NODES + 255) >> 8)                          // 196
#define EPB 2048                                            // edges per bucketA block

__device__ __forceinline__ float lrelu(float v) { return v > 0.f ? v : SLOPE * v; }

// bf16 helpers (RNE pack, exact unpack)
__device__ __forceinline__ unsigned short f2bf(float f) {
    union { float f; unsigned u; } v; v.f = f;
    unsigned u = v.u;
    return (unsigned short)((u + 0x7FFFu + ((u >> 16) & 1u)) >> 16);
}
__device__ __forceinline__ float bflo(unsigned u) {
    union { unsigned x; float f; } v; v.x = u << 16; return v.f;
}
__device__ __forceinline__ float bfhi(unsigned u) {
    union { unsigned x; float f; } v; v.x = u & 0xffff0000u; return v.f;
}

// ---------------- zero int buffer ----------------
__global__ void k_zero(int* __restrict__ p, int n) {
    int i = blockIdx.x * 256 + threadIdx.x;
    if (i < n) p[i] = 0;
}

// ---- GEMM1: h1b[N,128](bf16) = x @ W1 ; also as1/ad1 from fp32 acc ----
__global__ __launch_bounds__(256) void k_gemm1(const float* __restrict__ X,
                                               const float* __restrict__ W,
                                               const float* __restrict__ AS,
                                               const float* __restrict__ AD,
                                               unsigned short* __restrict__ h1b,
                                               float* __restrict__ as1,
                                               float* __restrict__ ad1) {
    __shared__ float As[64][17];
    __shared__ float Bs[16][128];
    const int tid = threadIdx.x;
    const int tx = tid & 15, ty = tid >> 4;
    const int row0 = blockIdx.x * 64;
    float acc[4][8];
#pragma unroll
    for (int i = 0; i < 4; i++)
#pragma unroll
        for (int j = 0; j < 8; j++) acc[i][j] = 0.f;

    for (int k0 = 0; k0 < FIN; k0 += 16) {
        {
            int r = tid >> 2, kq = (tid & 3) * 4;
            int gr = row0 + r;
            float4 va = make_float4(0.f, 0.f, 0.f, 0.f);
            if (gr < NODES) va = *(const float4*)(X + (size_t)gr * FIN + k0 + kq);
            As[r][kq + 0] = va.x; As[r][kq + 1] = va.y;
            As[r][kq + 2] = va.z; As[r][kq + 3] = va.w;
        }
#pragma unroll
        for (int i = 0; i < 2; i++) {
            int qq = tid * 2 + i;
            int rr = qq >> 5, cq = (qq & 31) * 4;
            *(float4*)(&Bs[rr][cq]) = *(const float4*)(W + (size_t)(k0 + rr) * C1 + cq);
        }
        __syncthreads();
#pragma unroll
        for (int kk = 0; kk < 16; kk++) {
            float a[4];
#pragma unroll
            for (int i = 0; i < 4; i++) a[i] = As[ty * 4 + i][kk];
            float4 b0 = *(float4*)(&Bs[kk][tx * 8]);
            float4 b1 = *(float4*)(&Bs[kk][tx * 8 + 4]);
            float b[8] = {b0.x, b0.y, b0.z, b0.w, b1.x, b1.y, b1.z, b1.w};
#pragma unroll
            for (int i = 0; i < 4; i++)
#pragma unroll
                for (int j = 0; j < 8; j++) acc[i][j] = fmaf(a[i], b[j], acc[i][j]);
        }
        __syncthreads();
    }
#pragma unroll
    for (int i = 0; i < 4; i++) {
        int gr = row0 + ty * 4 + i;
        if (gr < NODES) {
            unsigned short tb[8];
#pragma unroll
            for (int j = 0; j < 8; j++) tb[j] = f2bf(acc[i][j]);
            uint4 pk;
            pk.x = (unsigned)tb[0] | ((unsigned)tb[1] << 16);
            pk.y = (unsigned)tb[2] | ((unsigned)tb[3] << 16);
            pk.z = (unsigned)tb[4] | ((unsigned)tb[5] << 16);
            pk.w = (unsigned)tb[6] | ((unsigned)tb[7] << 16);
            *(uint4*)(h1b + (size_t)gr * C1 + tx * 8) = pk;
        }
    }
    const int h = tx >> 2;
    const int co = (tx & 3) * 8;
    float ps[4], pd[4];
#pragma unroll
    for (int i = 0; i < 4; i++) {
        float s = 0.f, d = 0.f;
#pragma unroll
        for (int j = 0; j < 8; j++) {
            s = fmaf(acc[i][j], AS[h * HID + co + j], s);
            d = fmaf(acc[i][j], AD[h * HID + co + j], d);
        }
        ps[i] = s; pd[i] = d;
    }
#pragma unroll
    for (int i = 0; i < 4; i++) {
        ps[i] += __shfl_xor(ps[i], 1); ps[i] += __shfl_xor(ps[i], 2);
        pd[i] += __shfl_xor(pd[i], 1); pd[i] += __shfl_xor(pd[i], 2);
    }
    if ((tx & 3) == 0) {
#pragma unroll
        for (int i = 0; i < 4; i++) {
            int gr = row0 + ty * 4 + i;
            if (gr < NODES) {
                as1[gr * HEADS + h] = ps[i];
                ad1[gr * HEADS + h] = pd[i];
            }
        }
    }
}

// ---------------- degree histogram ----------------
__global__ void k_hist(const int* __restrict__ dst, int E, int* __restrict__ deg) {
    int e = blockIdx.x * 256 + threadIdx.x;
    if (e < E) atomicAdd(&deg[dst[e]], 1);
}

// ---------------- device-wide scan, stage 1: per-block reduce ----------------
__global__ __launch_bounds__(256) void k_part(const int* __restrict__ deg,
                                              int* __restrict__ part) {
    __shared__ int sm[4];
    const int t = threadIdx.x;
    const int base = blockIdx.x * SCAN_TILE + t * 4;
    int s = 0;
    if (base + 3 < NODES) {
        int4 v = *(const int4*)(deg + base);
        s = v.x + v.y + v.z + v.w;
    } else {
#pragma unroll
        for (int i = 0; i < 4; i++) if (base + i < NODES) s += deg[base + i];
    }
#pragma unroll
    for (int d = 1; d < 64; d <<= 1) s += __shfl_xor(s, d);
    if ((t & 63) == 0) sm[t >> 6] = s;
    __syncthreads();
    if (t == 0) part[blockIdx.x] = sm[0] + sm[1] + sm[2] + sm[3];
}

// ---------------- stage 2: single-wave scan of partials ----------------
__global__ __launch_bounds__(64) void k_scan_part(const int* __restrict__ part,
                                                  int* __restrict__ partpfx,
                                                  int* __restrict__ rowptr) {
    const int t = threadIdx.x;
    int v = (t < SCAN_BLOCKS) ? part[t] : 0;
    int incl = v;
#pragma unroll
    for (int d = 1; d < 64; d <<= 1) {
        int u = __shfl_up(incl, d);
        if (t >= d) incl += u;
    }
    if (t < SCAN_BLOCKS) partpfx[t] = incl - v;
    if (t == 63) rowptr[NODES] = incl;
}

// ---------------- stage 3: per-block scan + write rowptr ----------------
__global__ __launch_bounds__(256) void k_scan_write(const int* __restrict__ deg,
                                                    const int* __restrict__ partpfx,
                                                    int* __restrict__ rowptr) {
    __shared__ int sm[4];
    const int t = threadIdx.x;
    const int lane = t & 63, w = t >> 6;
    const int base = blockIdx.x * SCAN_TILE + t * 4;
    int v0 = 0, v1 = 0, v2 = 0, v3 = 0;
    if (base + 3 < NODES) {
        int4 v = *(const int4*)(deg + base);
        v0 = v.x; v1 = v.y; v2 = v.z; v3 = v.w;
    } else {
        if (base + 0 < NODES) v0 = deg[base + 0];
        if (base + 1 < NODES) v1 = deg[base + 1];
        if (base + 2 < NODES) v2 = deg[base + 2];
        if (base + 3 < NODES) v3 = deg[base + 3];
    }
    const int s = v0 + v1 + v2 + v3;
    int incl = s;
#pragma unroll
    for (int d = 1; d < 64; d <<= 1) {
        int u = __shfl_up(incl, d);
        if (lane >= d) incl += u;
    }
    if (lane == 63) sm[w] = incl;
    __syncthreads();
    if (t == 0) {
        int r = 0;
#pragma unroll
        for (int i = 0; i < 4; i++) { int x = sm[i]; sm[i] = r; r += x; }
    }
    __syncthreads();
    int run = (incl - s) + sm[w] + partpfx[blockIdx.x];
    if (base + 3 < NODES) {
        *(int4*)(rowptr + base) =
            make_int4(run, run + v0, run + v0 + v1, run + v0 + v1 + v2);
    } else {
        int r = run;
        if (base + 0 < NODES) { rowptr[base + 0] = r; r += v0; }
        if (base + 1 < NODES) { rowptr[base + 1] = r; r += v1; }
        if (base + 2 < NODES) { rowptr[base + 2] = r; r += v2; }
        if (base + 3 < NODES) { rowptr[base + 3] = r; r += v3; }
    }
}

// ---------------- bucket write-pointer init: bwp[b] = rowptr[256b] ----------------
__global__ void k_binit(const int* __restrict__ rowptr, int* __restrict__ bwp) {
    int t = blockIdx.x * 64 + threadIdx.x;
    if (t < NBUCK) bwp[t] = rowptr[t << 8];
}

// ---------------- pass A: bucket edges by dst>>8 into staging ----------------
// packed v = (src<<8) | (dst&255); block-local LDS histogram for rank,
// one global atomicAdd per (block,bucket).
__global__ __launch_bounds__(256) void k_bucketA(const int* __restrict__ src,
                                                 const int* __restrict__ dst, int E,
                                                 int* __restrict__ bwp,
                                                 int* __restrict__ tmp) {
    __shared__ int cnt[NBUCK];
    __shared__ int bbase[NBUCK];
    const int t = threadIdx.x;
    for (int i = t; i < NBUCK; i += 256) cnt[i] = 0;
    __syncthreads();
    const int e0 = blockIdx.x * EPB;
    int v[8], rb[8];
#pragma unroll
    for (int k = 0; k < 8; k++) {
        int e = e0 + k * 256 + t;
        rb[k] = -1;
        if (e < E) {
            int d = dst[e], s = src[e];
            int b = d >> 8;
            int r = atomicAdd(&cnt[b], 1);
            v[k] = (s << 8) | (d & 255);
            rb[k] = (r << 8) | b;
        }
    }
    __syncthreads();
    for (int i = t; i < NBUCK; i += 256) {
        int c = cnt[i];
        bbase[i] = c ? atomicAdd(&bwp[i], c) : 0;
    }
    __syncthreads();
#pragma unroll
    for (int k = 0; k < 8; k++) {
        if (rb[k] >= 0) {
            int b = rb[k] & 255;
            int r = rb[k] >> 8;
            tmp[bbase[b] + r] = v[k];
        }
    }
}

// ---------------- pass B: per-bucket scatter to final CSR col ----------------
__global__ __launch_bounds__(256) void k_bucketB(const int* __restrict__ rowptr,
                                                 const int* __restrict__ tmp,
                                                 int* __restrict__ col) {
    __shared__ int wp[256];
    const int b = blockIdx.x;
    const int n0 = b << 8;
    int nend = n0 + 256; if (nend > NODES) nend = NODES;
    const int nn = nend - n0;
    const int t = threadIdx.x;
    const int beg = rowptr[n0];
    const int end = rowptr[nend];
    if (t < nn) wp[t] = rowptr[n0 + t];
    __syncthreads();
    for (int e = beg + t; e < end; e += 256) {
        int v = tmp[e];
        int p = atomicAdd(&wp[v & 255], 1);
        col[p] = v >> 8;
    }
}

// ---------------- layer-1 aggregation: one wave per dst node ----------------
__global__ __launch_bounds__(256) void k_agg1(const unsigned short* __restrict__ h1b,
                                              const float* __restrict__ as1,
                                              const float* __restrict__ ad1,
                                              const int* __restrict__ rowptr,
                                              const int* __restrict__ col,
                                              const float* __restrict__ b1,
                                              float* __restrict__ out1) {
    int wid = (blockIdx.x * 256 + threadIdx.x) >> 6;
    if (wid >= NODES) return;
    const int lane = threadIdx.x & 63;
    const int sub = lane & 15;
    const int head = lane >> 4;
    const int q  = lane >> 4;
    const int ll = lane & 15;
    const int fh = ll >> 2;
    const int n = wid;
    const float adn = ad1[n * HEADS + head];
    const int rs = rowptr[n], re = rowptr[n + 1];
    const float e_self = lrelu(as1[n * HEADS + head] + adn);

    float m = e_self;
    float e0 = -INFINITY, e1 = -INFINITY;
    int   c0v = 0, c1v = 0;
    int ch = 0;
    for (int base = rs; base < re; base += 16, ch++) {
        int i = base + sub;
        float e = -INFINITY;
        int c = 0;
        if (i < re) {
            c = col[i];
            e = lrelu(as1[c * HEADS + head] + adn);
        }
        if (ch == 0)      { e0 = e; c0v = c; }
        else if (ch == 1) { e1 = e; c1v = c; }
        m = fmaxf(m, e);
    }
#pragma unroll
    for (int d = 1; d < 16; d <<= 1) m = fmaxf(m, __shfl_xor(m, d));

    const float wself = __expf(e_self - m);
    float den = (sub == 0) ? wself : 0.f;
    float ac[8];
#pragma unroll
    for (int k = 0; k < 8; k++) ac[k] = 0.f;

    ch = 0;
    for (int base = rs; base < re; base += 16, ch++) {
        int i = base + sub;
        float e; int c;
        if (ch == 0)      { e = e0; c = c0v; }
        else if (ch == 1) { e = e1; c = c1v; }
        else {
            e = -INFINITY; c = 0;
            if (i < re) { c = col[i]; e = lrelu(as1[c * HEADS + head] + adn); }
        }
        float w = (i < re) ? __expf(e - m) : 0.f;
        den += w;
        int cnt = re - base; if (cnt > 16) cnt = 16;
        for (int j = 0; j < cnt; j += 4) {
            int jj = j + q;
            int sl = fh * 16 + jj;
            int   sj = __shfl(c, sl);
            float wj = __shfl(w, sl);
            uint4 pk = *(const uint4*)(h1b + (size_t)sj * C1 + ll * 8);
            ac[0] = fmaf(wj, bflo(pk.x), ac[0]); ac[1] = fmaf(wj, bfhi(pk.x), ac[1]);
            ac[2] = fmaf(wj, bflo(pk.y), ac[2]); ac[3] = fmaf(wj, bfhi(pk.y), ac[3]);
            ac[4] = fmaf(wj, bflo(pk.z), ac[4]); ac[5] = fmaf(wj, bfhi(pk.z), ac[5]);
            ac[6] = fmaf(wj, bflo(pk.w), ac[6]); ac[7] = fmaf(wj, bfhi(pk.w), ac[7]);
        }
    }
#pragma unroll
    for (int d = 1; d < 16; d <<= 1) den += __shfl_xor(den, d);
    const float den_f = __shfl(den, fh * 16);
    const float ws_f  = __shfl(wself, fh * 16);
#pragma unroll
    for (int k = 0; k < 8; k++) {
        ac[k] += __shfl_xor(ac[k], 16);
        ac[k] += __shfl_xor(ac[k], 32);
    }
    if (q == 0) {
        uint4 sp = *(const uint4*)(h1b + (size_t)n * C1 + ll * 8);
        float sv[8] = {bflo(sp.x), bfhi(sp.x), bflo(sp.y), bfhi(sp.y),
                       bflo(sp.z), bfhi(sp.z), bflo(sp.w), bfhi(sp.w)};
        float4 bv0 = *(const float4*)(b1 + ll * 8);
        float4 bv1 = *(const float4*)(b1 + ll * 8 + 4);
        float bb[8] = {bv0.x, bv0.y, bv0.z, bv0.w, bv1.x, bv1.y, bv1.z, bv1.w};
        float o[8];
#pragma unroll
        for (int k = 0; k < 8; k++)
            o[k] = fmaxf((ac[k] + ws_f * sv[k]) / den_f + bb[k], 0.f);
        *(float4*)(out1 + (size_t)n * C1 + ll * 8) =
            make_float4(o[0], o[1], o[2], o[3]);
        *(float4*)(out1 + (size_t)n * C1 + ll * 8 + 4) =
            make_float4(o[4], o[5], o[6], o[7]);
    }
}

// ---- GEMM2: h2[N,40](fp32) + h2b[N,64-stride](bf16) = out1 @ W2 ----
__global__ __launch_bounds__(320) void k_gemm2(const float* __restrict__ A,
                                               const float* __restrict__ W,
                                               float* __restrict__ H,
                                               unsigned short* __restrict__ h2b) {
    __shared__ float xs[64][132];
    __shared__ float ws2[128 * 40];
    const int tid = threadIdx.x;
    const int row0 = blockIdx.x * 64;
    for (int q = tid; q < 1280; q += 320)
        *(float4*)(ws2 + q * 4) = *(const float4*)(W + q * 4);
    for (int q = tid; q < 2048; q += 320) {
        int r = q >> 5, kq = (q & 31) * 4;
        int gr = row0 + r;
        float4 v = make_float4(0.f, 0.f, 0.f, 0.f);
        if (gr < NODES) v = *(const float4*)(A + (size_t)gr * FIN + kq);
        *(float4*)(&xs[r][kq]) = v;
    }
    __syncthreads();
    const int r = tid / 5;
    const int c0 = (tid % 5) * 8;
    float acc[8];
#pragma unroll
    for (int j = 0; j < 8; j++) acc[j] = 0.f;
    for (int k = 0; k < 128; k++) {
        float a = xs[r][k];
        float4 b0 = *(float4*)(ws2 + k * CLS + c0);
        float4 b1 = *(float4*)(ws2 + k * CLS + c0 + 4);
        acc[0] = fmaf(a, b0.x, acc[0]); acc[1] = fmaf(a, b0.y, acc[1]);
        acc[2] = fmaf(a, b0.z, acc[2]); acc[3] = fmaf(a, b0.w, acc[3]);
        acc[4] = fmaf(a, b1.x, acc[4]); acc[5] = fmaf(a, b1.y, acc[5]);
        acc[6] = fmaf(a, b1.z, acc[6]); acc[7] = fmaf(a, b1.w, acc[7]);
    }
    int gr = row0 + r;
    if (gr < NODES) {
        *(float4*)(H + (size_t)gr * CLS + c0) =
            make_float4(acc[0], acc[1], acc[2], acc[3]);
        *(float4*)(H + (size_t)gr * CLS + c0 + 4) =
            make_float4(acc[4], acc[5], acc[6], acc[7]);
        unsigned short tb[8];
#pragma unroll
        for (int j = 0; j < 8; j++) tb[j] = f2bf(acc[j]);
        uint4 pk;
        pk.x = (unsigned)tb[0] | ((unsigned)tb[1] << 16);
        pk.y = (unsigned)tb[2] | ((unsigned)tb[3] << 16);
        pk.z = (unsigned)tb[4] | ((unsigned)tb[5] << 16);
        pk.w = (unsigned)tb[6] | ((unsigned)tb[7] << 16);
        *(uint4*)(h2b + (size_t)gr * 64 + c0) = pk;
    }
}

// ---------------- per-node attention dots, layer 2 (fp32-exact) ----------------
__global__ void k_att2(const float* __restrict__ H2, const float* __restrict__ AS,
                       const float* __restrict__ AD, float* __restrict__ as2,
                       float* __restrict__ ad2) {
    int n = blockIdx.x * 256 + threadIdx.x;
    if (n >= NODES) return;
    const float* hp = H2 + (size_t)n * CLS;
    float s = 0.f, d = 0.f;
#pragma unroll
    for (int c = 0; c < CLS; c++) {
        float v = hp[c];
        s = fmaf(v, AS[c], s);
        d = fmaf(v, AD[c], d);
    }
    as2[n] = s;
    ad2[n] = d;
}

// ---------------- layer-2 aggregation: one wave per dst node ----------------
__global__ __launch_bounds__(256) void k_agg2(const unsigned short* __restrict__ h2b,
                                              const float* __restrict__ as2,
                                              const float* __restrict__ ad2,
                                              const int* __restrict__ rowptr,
                                              const int* __restrict__ col,
                                              const float* __restrict__ b2,
                                              float* __restrict__ out) {
    int wid = (blockIdx.x * 256 + threadIdx.x) >> 6;
    if (wid >= NODES) return;
    const int lane = threadIdx.x & 63;
    const int q8 = lane >> 3, l8 = lane & 7;
    const int n = wid;
    const float adn = ad2[n];
    const int rs = rowptr[n], re = rowptr[n + 1];
    const float e_self = lrelu(as2[n] + adn);

    float m = e_self;
    float e0 = -INFINITY, e1 = -INFINITY;
    int   c0v = 0, c1v = 0;
    int ch = 0;
    for (int base = rs; base < re; base += 64, ch++) {
        int i = base + lane;
        float e = -INFINITY;
        int c = 0;
        if (i < re) {
            c = col[i];
            e = lrelu(as2[c] + adn);
        }
        if (ch == 0)      { e0 = e; c0v = c; }
        else if (ch == 1) { e1 = e; c1v = c; }
        m = fmaxf(m, e);
    }
#pragma unroll
    for (int d = 1; d < 64; d <<= 1) m = fmaxf(m, __shfl_xor(m, d));

    const float wself = __expf(e_self - m);
    float den = (lane == 0) ? wself : 0.f;
    float ac[8];
#pragma unroll
    for (int k = 0; k < 8; k++) ac[k] = 0.f;
    ch = 0;
    for (int base = rs; base < re; base += 64, ch++) {
        int i = base + lane;
        float e; int c;
        if (ch == 0)      { e = e0; c = c0v; }
        else if (ch == 1) { e = e1; c = c1v; }
        else {
            e = -INFINITY; c = 0;
            if (i < re) { c = col[i]; e = lrelu(as2[c] + adn); }
        }
        float w = (i < re) ? __expf(e - m) : 0.f;
        den += w;
        int cnt = re - base; if (cnt > 64) cnt = 64;
        for (int j = 0; j < cnt; j += 8) {
            int jj = j + q8;
            int   sj = __shfl(c, jj);
            float wj = __shfl(w, jj);
            if (l8 < 5) {
                uint4 pk = *(const uint4*)(h2b + (size_t)sj * 64 + l8 * 8);
                ac[0] = fmaf(wj, bflo(pk.x), ac[0]); ac[1] = fmaf(wj, bfhi(pk.x), ac[1]);
                ac[2] = fmaf(wj, bflo(pk.y), ac[2]); ac[3] = fmaf(wj, bfhi(pk.y), ac[3]);
                ac[4] = fmaf(wj, bflo(pk.z), ac[4]); ac[5] = fmaf(wj, bfhi(pk.z), ac[5]);
                ac[6] = fmaf(wj, bflo(pk.w), ac[6]); ac[7] = fmaf(wj, bfhi(pk.w), ac[7]);
            }
        }
    }
#pragma unroll
    for (int d = 1; d < 64; d <<= 1) den += __shfl_xor(den, d);
#pragma unroll
    for (int k = 0; k < 8; k++) {
        ac[k] += __shfl_xor(ac[k], 8);
        ac[k] += __shfl_xor(ac[k], 16);
        ac[k] += __shfl_xor(ac[k], 32);
    }
    if (q8 == 0 && l8 < 5) {
        uint4 sp = *(const uint4*)(h2b + (size_t)n * 64 + l8 * 8);
        float sv[8] = {bflo(sp.x), bfhi(sp.x), bflo(sp.y), bfhi(sp.y),
                       bflo(sp.z), bfhi(sp.z), bflo(sp.w), bfhi(sp.w)};
        float4 bv0 = *(const float4*)(b2 + l8 * 8);
        float4 bv1 = *(const float4*)(b2 + l8 * 8 + 4);
        float bb[8] = {bv0.x, bv0.y, bv0.z, bv0.w, bv1.x, bv1.y, bv1.z, bv1.w};
        float o[8];
#pragma unroll
        for (int k = 0; k < 8; k++)
            o[k] = (ac[k] + wself * sv[k]) / den + bb[k];
        *(float4*)(out + (size_t)n * CLS + l8 * 8) =
            make_float4(o[0], o[1], o[2], o[3]);
        *(float4*)(out + (size_t)n * CLS + l8 * 8 + 4) =
            make_float4(o[4], o[5], o[6], o[7]);
    }
}

extern "C" void kernel_launch(void* const* d_in, const int* in_sizes, int n_in,
                              void* d_out, int out_size, void* d_ws, size_t ws_size,
                              hipStream_t stream) {
    const float* x     = (const float*)d_in[0];
    const int*   ei    = (const int*)d_in[1];
    const float* W1    = (const float*)d_in[2];
    const float* aS1   = (const float*)d_in[3];
    const float* aD1   = (const float*)d_in[4];
    const float* b1    = (const float*)d_in[5];
    const float* W2    = (const float*)d_in[6];
    const float* aS2   = (const float*)d_in[7];
    const float* aD2   = (const float*)d_in[8];
    const float* b2    = (const float*)d_in[9];
    float* out = (float*)d_out;
    const int E = in_sizes[1] / 2;
    const int* src = ei;
    const int* dst = ei + E;

    char* ws = (char*)d_ws;
    size_t off = 0;
    auto alloc = [&](size_t bytes) -> char* {
        char* p = ws + off;
        off += (bytes + 255) & ~(size_t)255;
        return p;
    };
    unsigned short* h1b = (unsigned short*)alloc((size_t)NODES * C1 * 2);
    float* out1   = (float*)alloc((size_t)NODES * C1 * 4);
    float* h2     = (float*)alloc((size_t)NODES * CLS * 4);
    unsigned short* h2b = (unsigned short*)alloc((size_t)NODES * 64 * 2);
    float* as1    = (float*)alloc((size_t)NODES * HEADS * 4);
    float* ad1    = (float*)alloc((size_t)NODES * HEADS * 4);
    float* as2    = (float*)alloc((size_t)NODES * 4);
    float* ad2    = (float*)alloc((size_t)NODES * 4);
    int* deg      = (int*)alloc((size_t)NODES * 4);
    int* rowptr   = (int*)alloc((size_t)(NODES + 1) * 4);
    int* col      = (int*)alloc((size_t)E * 4);
    int* tmp      = (int*)alloc((size_t)E * 4);
    int* part     = (int*)alloc((size_t)SCAN_BLOCKS * 4);
    int* partpfx  = (int*)alloc((size_t)SCAN_BLOCKS * 4);
    int* bwp      = (int*)alloc((size_t)NBUCK * 4);

    k_zero<<<(NODES + 255) / 256, 256, 0, stream>>>(deg, NODES);
    k_gemm1<<<(NODES + 63) / 64, 256, 0, stream>>>(x, W1, aS1, aD1, h1b, as1, ad1);
    k_hist<<<(E + 255) / 256, 256, 0, stream>>>(dst, E, deg);
    k_part<<<SCAN_BLOCKS, 256, 0, stream>>>(deg, part);
    k_scan_part<<<1, 64, 0, stream>>>(part, partpfx, rowptr);
    k_scan_write<<<SCAN_BLOCKS, 256, 0, stream>>>(deg, partpfx, rowptr);
    k_binit<<<(NBUCK + 63) / 64, 64, 0, stream>>>(rowptr, bwp);
    k_bucketA<<<(E + EPB - 1) / EPB, 256, 0, stream>>>(src, dst, E, bwp, tmp);
    k_bucketB<<<NBUCK, 256, 0, stream>>>(rowptr, tmp, col);
    k_agg1<<<(NODES * 64) / 256, 256, 0, stream>>>(h1b, as1, ad1, rowptr, col, b1, out1);
    k_gemm2<<<(NODES + 63) / 64, 320, 0, stream>>>(out1, W2, h2, h2b);
    k_att2<<<(NODES + 255) / 256, 256, 0, stream>>>(h2, aS2, aD2, as2, ad2);
    k_agg2<<<(NODES * 64) / 256, 256, 0, stream>>>(h2b, as2, ad2, rowptr, col, b2, out);
}

// Round 7
// 270.840 us; speedup vs baseline: 2.2416x; 1.0542x over previous
//
#include <hip/hip_runtime.h>
#include <cstdint>

#define NODES 50000
#define FIN   128
#define C1    128   // HEADS*HID
#define HEADS 4
#define HID   32
#define CLS   40
#define SLOPE 0.2f

#define NBUCK ((NODES + 255) >> 8)   // 196
#define EPB 2048                     // edges per bucketA/bhist block

__device__ __forceinline__ float lrelu(float v) { return v > 0.f ? v : SLOPE * v; }

__device__ __forceinline__ unsigned short f2bf(float f) {
    union { float f; unsigned u; } v; v.f = f;
    unsigned u = v.u;
    return (unsigned short)((u + 0x7FFFu + ((u >> 16) & 1u)) >> 16);
}
__device__ __forceinline__ float bflo(unsigned u) {
    union { unsigned x; float f; } v; v.x = u << 16; return v.f;
}
__device__ __forceinline__ float bfhi(unsigned u) {
    union { unsigned x; float f; } v; v.x = u & 0xffff0000u; return v.f;
}

// ---------------- zero int buffer ----------------
__global__ void k_zero(int* __restrict__ p, int n) {
    int i = blockIdx.x * 256 + threadIdx.x;
    if (i < n) p[i] = 0;
}

// ---- GEMM1: h1b[N,128](bf16) = x @ W1 ; also as1/ad1 from fp32 acc ----
__global__ __launch_bounds__(256) void k_gemm1(const float* __restrict__ X,
                                               const float* __restrict__ W,
                                               const float* __restrict__ AS,
                                               const float* __restrict__ AD,
                                               unsigned short* __restrict__ h1b,
                                               float* __restrict__ as1,
                                               float* __restrict__ ad1) {
    __shared__ float As[64][17];
    __shared__ float Bs[16][128];
    const int tid = threadIdx.x;
    const int tx = tid & 15, ty = tid >> 4;
    const int row0 = blockIdx.x * 64;
    float acc[4][8];
#pragma unroll
    for (int i = 0; i < 4; i++)
#pragma unroll
        for (int j = 0; j < 8; j++) acc[i][j] = 0.f;

    for (int k0 = 0; k0 < FIN; k0 += 16) {
        {
            int r = tid >> 2, kq = (tid & 3) * 4;
            int gr = row0 + r;
            float4 va = make_float4(0.f, 0.f, 0.f, 0.f);
            if (gr < NODES) va = *(const float4*)(X + (size_t)gr * FIN + k0 + kq);
            As[r][kq + 0] = va.x; As[r][kq + 1] = va.y;
            As[r][kq + 2] = va.z; As[r][kq + 3] = va.w;
        }
#pragma unroll
        for (int i = 0; i < 2; i++) {
            int qq = tid * 2 + i;
            int rr = qq >> 5, cq = (qq & 31) * 4;
            *(float4*)(&Bs[rr][cq]) = *(const float4*)(W + (size_t)(k0 + rr) * C1 + cq);
        }
        __syncthreads();
#pragma unroll
        for (int kk = 0; kk < 16; kk++) {
            float a[4];
#pragma unroll
            for (int i = 0; i < 4; i++) a[i] = As[ty * 4 + i][kk];
            float4 b0 = *(float4*)(&Bs[kk][tx * 8]);
            float4 b1 = *(float4*)(&Bs[kk][tx * 8 + 4]);
            float b[8] = {b0.x, b0.y, b0.z, b0.w, b1.x, b1.y, b1.z, b1.w};
#pragma unroll
            for (int i = 0; i < 4; i++)
#pragma unroll
                for (int j = 0; j < 8; j++) acc[i][j] = fmaf(a[i], b[j], acc[i][j]);
        }
        __syncthreads();
    }
#pragma unroll
    for (int i = 0; i < 4; i++) {
        int gr = row0 + ty * 4 + i;
        if (gr < NODES) {
            unsigned short tb[8];
#pragma unroll
            for (int j = 0; j < 8; j++) tb[j] = f2bf(acc[i][j]);
            uint4 pk;
            pk.x = (unsigned)tb[0] | ((unsigned)tb[1] << 16);
            pk.y = (unsigned)tb[2] | ((unsigned)tb[3] << 16);
            pk.z = (unsigned)tb[4] | ((unsigned)tb[5] << 16);
            pk.w = (unsigned)tb[6] | ((unsigned)tb[7] << 16);
            *(uint4*)(h1b + (size_t)gr * C1 + tx * 8) = pk;
        }
    }
    const int h = tx >> 2;
    const int co = (tx & 3) * 8;
    float ps[4], pd[4];
#pragma unroll
    for (int i = 0; i < 4; i++) {
        float s = 0.f, d = 0.f;
#pragma unroll
        for (int j = 0; j < 8; j++) {
            s = fmaf(acc[i][j], AS[h * HID + co + j], s);
            d = fmaf(acc[i][j], AD[h * HID + co + j], d);
        }
        ps[i] = s; pd[i] = d;
    }
#pragma unroll
    for (int i = 0; i < 4; i++) {
        ps[i] += __shfl_xor(ps[i], 1); ps[i] += __shfl_xor(ps[i], 2);
        pd[i] += __shfl_xor(pd[i], 1); pd[i] += __shfl_xor(pd[i], 2);
    }
    if ((tx & 3) == 0) {
#pragma unroll
        for (int i = 0; i < 4; i++) {
            int gr = row0 + ty * 4 + i;
            if (gr < NODES) {
                as1[gr * HEADS + h] = ps[i];
                ad1[gr * HEADS + h] = pd[i];
            }
        }
    }
}

// ---------------- bucket histogram: bcnt[b] = #edges with dst>>8 == b ----------------
__global__ __launch_bounds__(256) void k_bhist(const int* __restrict__ dst, int E,
                                               int* __restrict__ bcnt) {
    __shared__ int cnt[NBUCK];
    const int t = threadIdx.x;
    for (int i = t; i < NBUCK; i += 256) cnt[i] = 0;
    __syncthreads();
    const int e0 = blockIdx.x * EPB;
#pragma unroll
    for (int k = 0; k < 8; k++) {
        int e = e0 + k * 256 + t;
        if (e < E) atomicAdd(&cnt[dst[e] >> 8], 1);
    }
    __syncthreads();
    for (int i = t; i < NBUCK; i += 256) {
        int c = cnt[i];
        if (c) atomicAdd(&bcnt[i], c);
    }
}

// ---------------- one-block scan of bucket counts -> bbase, bwp ----------------
__global__ __launch_bounds__(256) void k_bscan(const int* __restrict__ bcnt,
                                               int* __restrict__ bbase,
                                               int* __restrict__ bwp) {
    __shared__ int ws[4];
    const int t = threadIdx.x;
    const int lane = t & 63, w = t >> 6;
    int v = (t < NBUCK) ? bcnt[t] : 0;
    int incl = v;
#pragma unroll
    for (int s = 1; s < 64; s <<= 1) {
        int u = __shfl_up(incl, s);
        if (lane >= s) incl += u;
    }
    if (lane == 63) ws[w] = incl;
    __syncthreads();
    if (t == 0) {
        int r = 0;
#pragma unroll
        for (int i = 0; i < 4; i++) { int x = ws[i]; ws[i] = r; r += x; }
    }
    __syncthreads();
    int excl = incl - v + ws[w];
    if (t < NBUCK) { bbase[t] = excl; bwp[t] = excl; }
    if (t == NBUCK) bbase[NBUCK] = excl;   // total E
}

// ---------------- pass A: bucket edges by dst>>8 into staging ----------------
__global__ __launch_bounds__(256) void k_bucketA(const int* __restrict__ src,
                                                 const int* __restrict__ dst, int E,
                                                 int* __restrict__ bwp,
                                                 int* __restrict__ tmp) {
    __shared__ int cnt[NBUCK];
    __shared__ int bbs[NBUCK];
    const int t = threadIdx.x;
    for (int i = t; i < NBUCK; i += 256) cnt[i] = 0;
    __syncthreads();
    const int e0 = blockIdx.x * EPB;
    int v[8], rb[8];
#pragma unroll
    for (int k = 0; k < 8; k++) {
        int e = e0 + k * 256 + t;
        rb[k] = -1;
        if (e < E) {
            int d = dst[e], s = src[e];
            int b = d >> 8;
            int r = atomicAdd(&cnt[b], 1);
            v[k] = (s << 8) | (d & 255);
            rb[k] = (r << 8) | b;
        }
    }
    __syncthreads();
    for (int i = t; i < NBUCK; i += 256) {
        int c = cnt[i];
        bbs[i] = c ? atomicAdd(&bwp[i], c) : 0;
    }
    __syncthreads();
#pragma unroll
    for (int k = 0; k < 8; k++) {
        if (rb[k] >= 0) {
            int b = rb[k] & 255;
            int r = rb[k] >> 8;
            tmp[bbs[b] + r] = v[k];
        }
    }
}

// ---------------- pass B: per-bucket degree+scan+rowptr, scatter col ----------------
__global__ __launch_bounds__(256) void k_bucketB(const int* __restrict__ bbase,
                                                 const int* __restrict__ tmp,
                                                 int* __restrict__ col,
                                                 int* __restrict__ rowptr, int E) {
    __shared__ int degs[256];
    __shared__ int wp[256];
    __shared__ int wsum[4];
    const int b = blockIdx.x, t = threadIdx.x;
    const int n0 = b << 8;
    const int beg = bbase[b], end = bbase[b + 1];
    degs[t] = 0;
    __syncthreads();
    for (int e = beg + t; e < end; e += 256)
        atomicAdd(&degs[tmp[e] & 255], 1);
    __syncthreads();
    const int d = degs[t];
    int incl = d;
    const int lane = t & 63, w = t >> 6;
#pragma unroll
    for (int s = 1; s < 64; s <<= 1) {
        int u = __shfl_up(incl, s);
        if (lane >= s) incl += u;
    }
    if (lane == 63) wsum[w] = incl;
    __syncthreads();
    if (t == 0) {
        int r = 0;
#pragma unroll
        for (int i = 0; i < 4; i++) { int x = wsum[i]; wsum[i] = r; r += x; }
    }
    __syncthreads();
    const int excl = incl - d + wsum[w] + beg;
    const int nidx = n0 + t;
    if (nidx < NODES) rowptr[nidx] = excl;
    wp[t] = excl;
    if (b == 0 && t == 0) rowptr[NODES] = E;
    __syncthreads();
    for (int e = beg + t; e < end; e += 256) {
        int v = tmp[e];
        int p = atomicAdd(&wp[v & 255], 1);
        col[p] = v >> 8;
    }
}

// ---------------- layer-1 aggregation: TWO waves per dst node ----------------
// block = 256 = 4 waves = 2 nodes; wave w of a node handles chunks rs+16w, +32,...
// partial m/den/acc combined via LDS; wave1 finalizes (self term, bias, relu).
__global__ __launch_bounds__(256) void k_agg1(const unsigned short* __restrict__ h1b,
                                              const float* __restrict__ as1,
                                              const float* __restrict__ ad1,
                                              const int* __restrict__ rowptr,
                                              const int* __restrict__ col,
                                              const float* __restrict__ b1,
                                              float* __restrict__ out1) {
    __shared__ float s_m[2][4][2];
    __shared__ float s_den[2][4][2];
    __shared__ float s_ac[2][128];
    const int t = threadIdx.x;
    const int wv = t >> 6;
    const int nl = wv >> 1;          // node slot in block
    const int w  = wv & 1;           // wave half
    const int n  = blockIdx.x * 2 + nl;   // grid is exactly NODES/2: no tail
    const int lane = t & 63;
    const int sub = lane & 15;
    const int head = lane >> 4;
    const int q  = lane >> 4;        // feature edge slot
    const int ll = lane & 15;        // feature channel group (8 ch)
    const int fh = ll >> 2;          // head owning channel group
    const float adn = ad1[n * HEADS + head];
    const int rs = rowptr[n], re = rowptr[n + 1];
    const float e_self = lrelu(as1[n * HEADS + head] + adn);

    // pass 1: partial max over this wave's chunks
    float m = e_self;
    float e0 = -INFINITY, e1 = -INFINITY;
    int   c0v = 0, c1v = 0;
    int ch = 0;
    for (int base = rs + 16 * w; base < re; base += 32, ch++) {
        int i = base + sub;
        float e = -INFINITY;
        int c = 0;
        if (i < re) {
            c = col[i];
            e = lrelu(as1[c * HEADS + head] + adn);
        }
        if (ch == 0)      { e0 = e; c0v = c; }
        else if (ch == 1) { e1 = e; c1v = c; }
        m = fmaxf(m, e);
    }
#pragma unroll
    for (int d = 1; d < 16; d <<= 1) m = fmaxf(m, __shfl_xor(m, d));
    if (sub == 0) s_m[nl][head][w] = m;
    __syncthreads();
    m = fmaxf(s_m[nl][head][0], s_m[nl][head][1]);   // global max for this head

    // pass 2: partial den + weighted features over this wave's chunks
    float den = 0.f;
    float ac[8];
#pragma unroll
    for (int k = 0; k < 8; k++) ac[k] = 0.f;
    ch = 0;
    for (int base = rs + 16 * w; base < re; base += 32, ch++) {
        int i = base + sub;
        float e; int c;
        if (ch == 0)      { e = e0; c = c0v; }
        else if (ch == 1) { e = e1; c = c1v; }
        else {
            e = -INFINITY; c = 0;
            if (i < re) { c = col[i]; e = lrelu(as1[c * HEADS + head] + adn); }
        }
        float wgt = (i < re) ? __expf(e - m) : 0.f;
        den += wgt;
        int cnt = re - base; if (cnt > 16) cnt = 16;
        for (int j = 0; j < cnt; j += 4) {
            int jj = j + q;                       // <= 15 always
            int sl = fh * 16 + jj;
            int   sj = __shfl(c, sl);
            float wj = __shfl(wgt, sl);           // 0 for jj >= cnt
            unsigned off = ((unsigned)sj << 8) + (unsigned)(ll << 4);
            uint4 pk = *(const uint4*)((const char*)h1b + off);
            ac[0] = fmaf(wj, bflo(pk.x), ac[0]); ac[1] = fmaf(wj, bfhi(pk.x), ac[1]);
            ac[2] = fmaf(wj, bflo(pk.y), ac[2]); ac[3] = fmaf(wj, bfhi(pk.y), ac[3]);
            ac[4] = fmaf(wj, bflo(pk.z), ac[4]); ac[5] = fmaf(wj, bfhi(pk.z), ac[5]);
            ac[6] = fmaf(wj, bflo(pk.w), ac[6]); ac[7] = fmaf(wj, bfhi(pk.w), ac[7]);
        }
    }
#pragma unroll
    for (int d = 1; d < 16; d <<= 1) den += __shfl_xor(den, d);
    if (sub == 0) s_den[nl][head][w] = den;
#pragma unroll
    for (int k = 0; k < 8; k++) {
        ac[k] += __shfl_xor(ac[k], 16);
        ac[k] += __shfl_xor(ac[k], 32);
    }
    if (w == 0 && q == 0) {
        *(float4*)(&s_ac[nl][ll * 8])     = make_float4(ac[0], ac[1], ac[2], ac[3]);
        *(float4*)(&s_ac[nl][ll * 8 + 4]) = make_float4(ac[4], ac[5], ac[6], ac[7]);
    }
    __syncthreads();
    if (w == 1 && q == 0) {
        float m_h   = fmaxf(s_m[nl][fh][0], s_m[nl][fh][1]);
        float den_t = s_den[nl][fh][0] + s_den[nl][fh][1];
        float es    = lrelu(as1[n * HEADS + fh] + ad1[n * HEADS + fh]);
        float wself = __expf(es - m_h);
        den_t += wself;
        unsigned offs = ((unsigned)n << 8) + (unsigned)(ll << 4);
        uint4 sp = *(const uint4*)((const char*)h1b + offs);
        float sv[8] = {bflo(sp.x), bfhi(sp.x), bflo(sp.y), bfhi(sp.y),
                       bflo(sp.z), bfhi(sp.z), bflo(sp.w), bfhi(sp.w)};
        float4 bv0 = *(const float4*)(b1 + ll * 8);
        float4 bv1 = *(const float4*)(b1 + ll * 8 + 4);
        float bb[8] = {bv0.x, bv0.y, bv0.z, bv0.w, bv1.x, bv1.y, bv1.z, bv1.w};
        float o[8];
#pragma unroll
        for (int k = 0; k < 8; k++)
            o[k] = fmaxf((s_ac[nl][ll * 8 + k] + ac[k] + wself * sv[k]) / den_t + bb[k], 0.f);
        *(float4*)(out1 + (size_t)n * C1 + ll * 8) =
            make_float4(o[0], o[1], o[2], o[3]);
        *(float4*)(out1 + (size_t)n * C1 + ll * 8 + 4) =
            make_float4(o[4], o[5], o[6], o[7]);
    }
}

// ---- GEMM2: h2[N,40](fp32) + h2b[N,64-stride](bf16) = out1 @ W2 ----
__global__ __launch_bounds__(320) void k_gemm2(const float* __restrict__ A,
                                               const float* __restrict__ W,
                                               float* __restrict__ H,
                                               unsigned short* __restrict__ h2b) {
    __shared__ float xs[64][132];
    __shared__ float ws2[128 * 40];
    const int tid = threadIdx.x;
    const int row0 = blockIdx.x * 64;
    for (int q = tid; q < 1280; q += 320)
        *(float4*)(ws2 + q * 4) = *(const float4*)(W + q * 4);
    for (int q = tid; q < 2048; q += 320) {
        int r = q >> 5, kq = (q & 31) * 4;
        int gr = row0 + r;
        float4 v = make_float4(0.f, 0.f, 0.f, 0.f);
        if (gr < NODES) v = *(const float4*)(A + (size_t)gr * FIN + kq);
        *(float4*)(&xs[r][kq]) = v;
    }
    __syncthreads();
    const int r = tid / 5;
    const int c0 = (tid % 5) * 8;
    float acc[8];
#pragma unroll
    for (int j = 0; j < 8; j++) acc[j] = 0.f;
    for (int k = 0; k < 128; k++) {
        float a = xs[r][k];
        float4 b0 = *(float4*)(ws2 + k * CLS + c0);
        float4 b1 = *(float4*)(ws2 + k * CLS + c0 + 4);
        acc[0] = fmaf(a, b0.x, acc[0]); acc[1] = fmaf(a, b0.y, acc[1]);
        acc[2] = fmaf(a, b0.z, acc[2]); acc[3] = fmaf(a, b0.w, acc[3]);
        acc[4] = fmaf(a, b1.x, acc[4]); acc[5] = fmaf(a, b1.y, acc[5]);
        acc[6] = fmaf(a, b1.z, acc[6]); acc[7] = fmaf(a, b1.w, acc[7]);
    }
    int gr = row0 + r;
    if (gr < NODES) {
        *(float4*)(H + (size_t)gr * CLS + c0) =
            make_float4(acc[0], acc[1], acc[2], acc[3]);
        *(float4*)(H + (size_t)gr * CLS + c0 + 4) =
            make_float4(acc[4], acc[5], acc[6], acc[7]);
        unsigned short tb[8];
#pragma unroll
        for (int j = 0; j < 8; j++) tb[j] = f2bf(acc[j]);
        uint4 pk;
        pk.x = (unsigned)tb[0] | ((unsigned)tb[1] << 16);
        pk.y = (unsigned)tb[2] | ((unsigned)tb[3] << 16);
        pk.z = (unsigned)tb[4] | ((unsigned)tb[5] << 16);
        pk.w = (unsigned)tb[6] | ((unsigned)tb[7] << 16);
        *(uint4*)(h2b + (size_t)gr * 64 + c0) = pk;
    }
}

// ---------------- per-node attention dots, layer 2 (fp32-exact) ----------------
__global__ void k_att2(const float* __restrict__ H2, const float* __restrict__ AS,
                       const float* __restrict__ AD, float* __restrict__ as2,
                       float* __restrict__ ad2) {
    int n = blockIdx.x * 256 + threadIdx.x;
    if (n >= NODES) return;
    const float* hp = H2 + (size_t)n * CLS;
    float s = 0.f, d = 0.f;
#pragma unroll
    for (int c = 0; c < CLS; c++) {
        float v = hp[c];
        s = fmaf(v, AS[c], s);
        d = fmaf(v, AD[c], d);
    }
    as2[n] = s;
    ad2[n] = d;
}

// ---------------- layer-2 aggregation: one wave per dst node ----------------
__global__ __launch_bounds__(256) void k_agg2(const unsigned short* __restrict__ h2b,
                                              const float* __restrict__ as2,
                                              const float* __restrict__ ad2,
                                              const int* __restrict__ rowptr,
                                              const int* __restrict__ col,
                                              const float* __restrict__ b2,
                                              float* __restrict__ out) {
    int wid = (blockIdx.x * 256 + threadIdx.x) >> 6;
    if (wid >= NODES) return;
    const int lane = threadIdx.x & 63;
    const int q8 = lane >> 3, l8 = lane & 7;
    const int n = wid;
    const float adn = ad2[n];
    const int rs = rowptr[n], re = rowptr[n + 1];
    const float e_self = lrelu(as2[n] + adn);

    float m = e_self;
    float e0 = -INFINITY, e1 = -INFINITY;
    int   c0v = 0, c1v = 0;
    int ch = 0;
    for (int base = rs; base < re; base += 64, ch++) {
        int i = base + lane;
        float e = -INFINITY;
        int c = 0;
        if (i < re) {
            c = col[i];
            e = lrelu(as2[c] + adn);
        }
        if (ch == 0)      { e0 = e; c0v = c; }
        else if (ch == 1) { e1 = e; c1v = c; }
        m = fmaxf(m, e);
    }
#pragma unroll
    for (int d = 1; d < 64; d <<= 1) m = fmaxf(m, __shfl_xor(m, d));

    const float wself = __expf(e_self - m);
    float den = (lane == 0) ? wself : 0.f;
    float ac[8];
#pragma unroll
    for (int k = 0; k < 8; k++) ac[k] = 0.f;
    ch = 0;
    for (int base = rs; base < re; base += 64, ch++) {
        int i = base + lane;
        float e; int c;
        if (ch == 0)      { e = e0; c = c0v; }
        else if (ch == 1) { e = e1; c = c1v; }
        else {
            e = -INFINITY; c = 0;
            if (i < re) { c = col[i]; e = lrelu(as2[c] + adn); }
        }
        float w = (i < re) ? __expf(e - m) : 0.f;
        den += w;
        int cnt = re - base; if (cnt > 64) cnt = 64;
        for (int j = 0; j < cnt; j += 8) {
            int jj = j + q8;
            int   sj = __shfl(c, jj);
            float wj = __shfl(w, jj);
            if (l8 < 5) {
                unsigned off = ((unsigned)sj << 7) + (unsigned)(l8 << 4);
                uint4 pk = *(const uint4*)((const char*)h2b + off);
                ac[0] = fmaf(wj, bflo(pk.x), ac[0]); ac[1] = fmaf(wj, bfhi(pk.x), ac[1]);
                ac[2] = fmaf(wj, bflo(pk.y), ac[2]); ac[3] = fmaf(wj, bfhi(pk.y), ac[3]);
                ac[4] = fmaf(wj, bflo(pk.z), ac[4]); ac[5] = fmaf(wj, bfhi(pk.z), ac[5]);
                ac[6] = fmaf(wj, bflo(pk.w), ac[6]); ac[7] = fmaf(wj, bfhi(pk.w), ac[7]);
            }
        }
    }
#pragma unroll
    for (int d = 1; d < 64; d <<= 1) den += __shfl_xor(den, d);
#pragma unroll
    for (int k = 0; k < 8; k++) {
        ac[k] += __shfl_xor(ac[k], 8);
        ac[k] += __shfl_xor(ac[k], 16);
        ac[k] += __shfl_xor(ac[k], 32);
    }
    if (q8 == 0 && l8 < 5) {
        unsigned offs = ((unsigned)n << 7) + (unsigned)(l8 << 4);
        uint4 sp = *(const uint4*)((const char*)h2b + offs);
        float sv[8] = {bflo(sp.x), bfhi(sp.x), bflo(sp.y), bfhi(sp.y),
                       bflo(sp.z), bfhi(sp.z), bflo(sp.w), bfhi(sp.w)};
        float4 bv0 = *(const float4*)(b2 + l8 * 8);
        float4 bv1 = *(const float4*)(b2 + l8 * 8 + 4);
        float bb[8] = {bv0.x, bv0.y, bv0.z, bv0.w, bv1.x, bv1.y, bv1.z, bv1.w};
        float o[8];
#pragma unroll
        for (int k = 0; k < 8; k++)
            o[k] = (ac[k] + wself * sv[k]) / den + bb[k];
        *(float4*)(out + (size_t)n * CLS + l8 * 8) =
            make_float4(o[0], o[1], o[2], o[3]);
        *(float4*)(out + (size_t)n * CLS + l8 * 8 + 4) =
            make_float4(o[4], o[5], o[6], o[7]);
    }
}

extern "C" void kernel_launch(void* const* d_in, const int* in_sizes, int n_in,
                              void* d_out, int out_size, void* d_ws, size_t ws_size,
                              hipStream_t stream) {
    const float* x     = (const float*)d_in[0];
    const int*   ei    = (const int*)d_in[1];
    const float* W1    = (const float*)d_in[2];
    const float* aS1   = (const float*)d_in[3];
    const float* aD1   = (const float*)d_in[4];
    const float* b1    = (const float*)d_in[5];
    const float* W2    = (const float*)d_in[6];
    const float* aS2   = (const float*)d_in[7];
    const float* aD2   = (const float*)d_in[8];
    const float* b2    = (const float*)d_in[9];
    float* out = (float*)d_out;
    const int E = in_sizes[1] / 2;
    const int* src = ei;
    const int* dst = ei + E;

    char* ws = (char*)d_ws;
    size_t off = 0;
    auto alloc = [&](size_t bytes) -> char* {
        char* p = ws + off;
        off += (bytes + 255) & ~(size_t)255;
        return p;
    };
    unsigned short* h1b = (unsigned short*)alloc((size_t)NODES * C1 * 2);
    float* out1   = (float*)alloc((size_t)NODES * C1 * 4);
    float* h2     = (float*)alloc((size_t)NODES * CLS * 4);
    unsigned short* h2b = (unsigned short*)alloc((size_t)NODES * 64 * 2);
    float* as1    = (float*)alloc((size_t)NODES * HEADS * 4);
    float* ad1    = (float*)alloc((size_t)NODES * HEADS * 4);
    float* as2    = (float*)alloc((size_t)NODES * 4);
    float* ad2    = (float*)alloc((size_t)NODES * 4);
    int* rowptr   = (int*)alloc((size_t)(NODES + 1) * 4);
    int* col      = (int*)alloc((size_t)E * 4);
    int* tmp      = (int*)alloc((size_t)E * 4);
    int* bcnt     = (int*)alloc((size_t)NBUCK * 4);
    int* bbase    = (int*)alloc((size_t)(NBUCK + 1) * 4);
    int* bwp      = (int*)alloc((size_t)NBUCK * 4);

    k_zero<<<1, 256, 0, stream>>>(bcnt, NBUCK);
    k_gemm1<<<(NODES + 63) / 64, 256, 0, stream>>>(x, W1, aS1, aD1, h1b, as1, ad1);
    k_bhist<<<(E + EPB - 1) / EPB, 256, 0, stream>>>(dst, E, bcnt);
    k_bscan<<<1, 256, 0, stream>>>(bcnt, bbase, bwp);
    k_bucketA<<<(E + EPB - 1) / EPB, 256, 0, stream>>>(src, dst, E, bwp, tmp);
    k_bucketB<<<NBUCK, 256, 0, stream>>>(bbase, tmp, col, rowptr, E);
    k_agg1<<<NODES / 2, 256, 0, stream>>>(h1b, as1, ad1, rowptr, col, b1, out1);
    k_gemm2<<<(NODES + 63) / 64, 320, 0, stream>>>(out1, W2, h2, h2b);
    k_att2<<<(NODES + 255) / 256, 256, 0, stream>>>(h2, aS2, aD2, as2, ad2);
    k_agg2<<<(NODES * 64) / 256, 256, 0, stream>>>(h2b, as2, ad2, rowptr, col, b2, out);
}

// Round 8
// 251.291 us; speedup vs baseline: 2.4160x; 1.0778x over previous
//
#include <hip/hip_runtime.h>
#include <cstdint>

#define NODES 50000
#define FIN   128
#define C1    128   // HEADS*HID
#define HEADS 4
#define HID   32
#define CLS   40
#define SLOPE 0.2f

#define NBUCK ((NODES + 255) >> 8)   // 196
#define EPB 2048                     // edges per bucketA/bhist block

__device__ __forceinline__ float lrelu(float v) { return v > 0.f ? v : SLOPE * v; }

__device__ __forceinline__ unsigned short f2bf(float f) {
    union { float f; unsigned u; } v; v.f = f;
    unsigned u = v.u;
    return (unsigned short)((u + 0x7FFFu + ((u >> 16) & 1u)) >> 16);
}
__device__ __forceinline__ float bflo(unsigned u) {
    union { unsigned x; float f; } v; v.x = u << 16; return v.f;
}
__device__ __forceinline__ float bfhi(unsigned u) {
    union { unsigned x; float f; } v; v.x = u & 0xffff0000u; return v.f;
}

// ---------------- zero int buffer ----------------
__global__ void k_zero(int* __restrict__ p, int n) {
    int i = blockIdx.x * 256 + threadIdx.x;
    if (i < n) p[i] = 0;
}

// ---- GEMM1: h1b[N,128](bf16) = x @ W1 ; also as1/ad1 from fp32 acc ----
__global__ __launch_bounds__(256) void k_gemm1(const float* __restrict__ X,
                                               const float* __restrict__ W,
                                               const float* __restrict__ AS,
                                               const float* __restrict__ AD,
                                               unsigned short* __restrict__ h1b,
                                               float* __restrict__ as1,
                                               float* __restrict__ ad1) {
    __shared__ float As[64][17];
    __shared__ float Bs[16][128];
    const int tid = threadIdx.x;
    const int tx = tid & 15, ty = tid >> 4;
    const int row0 = blockIdx.x * 64;
    float acc[4][8];
#pragma unroll
    for (int i = 0; i < 4; i++)
#pragma unroll
        for (int j = 0; j < 8; j++) acc[i][j] = 0.f;

    for (int k0 = 0; k0 < FIN; k0 += 16) {
        {
            int r = tid >> 2, kq = (tid & 3) * 4;
            int gr = row0 + r;
            float4 va = make_float4(0.f, 0.f, 0.f, 0.f);
            if (gr < NODES) va = *(const float4*)(X + (size_t)gr * FIN + k0 + kq);
            As[r][kq + 0] = va.x; As[r][kq + 1] = va.y;
            As[r][kq + 2] = va.z; As[r][kq + 3] = va.w;
        }
#pragma unroll
        for (int i = 0; i < 2; i++) {
            int qq = tid * 2 + i;
            int rr = qq >> 5, cq = (qq & 31) * 4;
            *(float4*)(&Bs[rr][cq]) = *(const float4*)(W + (size_t)(k0 + rr) * C1 + cq);
        }
        __syncthreads();
#pragma unroll
        for (int kk = 0; kk < 16; kk++) {
            float a[4];
#pragma unroll
            for (int i = 0; i < 4; i++) a[i] = As[ty * 4 + i][kk];
            float4 b0 = *(float4*)(&Bs[kk][tx * 8]);
            float4 b1 = *(float4*)(&Bs[kk][tx * 8 + 4]);
            float b[8] = {b0.x, b0.y, b0.z, b0.w, b1.x, b1.y, b1.z, b1.w};
#pragma unroll
            for (int i = 0; i < 4; i++)
#pragma unroll
                for (int j = 0; j < 8; j++) acc[i][j] = fmaf(a[i], b[j], acc[i][j]);
        }
        __syncthreads();
    }
#pragma unroll
    for (int i = 0; i < 4; i++) {
        int gr = row0 + ty * 4 + i;
        if (gr < NODES) {
            unsigned short tb[8];
#pragma unroll
            for (int j = 0; j < 8; j++) tb[j] = f2bf(acc[i][j]);
            uint4 pk;
            pk.x = (unsigned)tb[0] | ((unsigned)tb[1] << 16);
            pk.y = (unsigned)tb[2] | ((unsigned)tb[3] << 16);
            pk.z = (unsigned)tb[4] | ((unsigned)tb[5] << 16);
            pk.w = (unsigned)tb[6] | ((unsigned)tb[7] << 16);
            *(uint4*)(h1b + (size_t)gr * C1 + tx * 8) = pk;
        }
    }
    const int h = tx >> 2;
    const int co = (tx & 3) * 8;
    float ps[4], pd[4];
#pragma unroll
    for (int i = 0; i < 4; i++) {
        float s = 0.f, d = 0.f;
#pragma unroll
        for (int j = 0; j < 8; j++) {
            s = fmaf(acc[i][j], AS[h * HID + co + j], s);
            d = fmaf(acc[i][j], AD[h * HID + co + j], d);
        }
        ps[i] = s; pd[i] = d;
    }
#pragma unroll
    for (int i = 0; i < 4; i++) {
        ps[i] += __shfl_xor(ps[i], 1); ps[i] += __shfl_xor(ps[i], 2);
        pd[i] += __shfl_xor(pd[i], 1); pd[i] += __shfl_xor(pd[i], 2);
    }
    if ((tx & 3) == 0) {
#pragma unroll
        for (int i = 0; i < 4; i++) {
            int gr = row0 + ty * 4 + i;
            if (gr < NODES) {
                as1[gr * HEADS + h] = ps[i];
                ad1[gr * HEADS + h] = pd[i];
            }
        }
    }
}

// ---------------- bucket histogram: bcnt[b] = #edges with dst>>8 == b ----------------
__global__ __launch_bounds__(256) void k_bhist(const int* __restrict__ dst, int E,
                                               int* __restrict__ bcnt) {
    __shared__ int cnt[NBUCK];
    const int t = threadIdx.x;
    for (int i = t; i < NBUCK; i += 256) cnt[i] = 0;
    __syncthreads();
    const int e0 = blockIdx.x * EPB;
#pragma unroll
    for (int k = 0; k < 8; k++) {
        int e = e0 + k * 256 + t;
        if (e < E) atomicAdd(&cnt[dst[e] >> 8], 1);
    }
    __syncthreads();
    for (int i = t; i < NBUCK; i += 256) {
        int c = cnt[i];
        if (c) atomicAdd(&bcnt[i], c);
    }
}

// ---------------- one-block scan of bucket counts -> bbase, bwp ----------------
__global__ __launch_bounds__(256) void k_bscan(const int* __restrict__ bcnt,
                                               int* __restrict__ bbase,
                                               int* __restrict__ bwp) {
    __shared__ int ws[4];
    const int t = threadIdx.x;
    const int lane = t & 63, w = t >> 6;
    int v = (t < NBUCK) ? bcnt[t] : 0;
    int incl = v;
#pragma unroll
    for (int s = 1; s < 64; s <<= 1) {
        int u = __shfl_up(incl, s);
        if (lane >= s) incl += u;
    }
    if (lane == 63) ws[w] = incl;
    __syncthreads();
    if (t == 0) {
        int r = 0;
#pragma unroll
        for (int i = 0; i < 4; i++) { int x = ws[i]; ws[i] = r; r += x; }
    }
    __syncthreads();
    int excl = incl - v + ws[w];
    if (t < NBUCK) { bbase[t] = excl; bwp[t] = excl; }
    if (t == NBUCK) bbase[NBUCK] = excl;   // total E
}

// ---------------- pass A: bucket edges by dst>>8 into staging ----------------
__global__ __launch_bounds__(256) void k_bucketA(const int* __restrict__ src,
                                                 const int* __restrict__ dst, int E,
                                                 int* __restrict__ bwp,
                                                 int* __restrict__ tmp) {
    __shared__ int cnt[NBUCK];
    __shared__ int bbs[NBUCK];
    const int t = threadIdx.x;
    for (int i = t; i < NBUCK; i += 256) cnt[i] = 0;
    __syncthreads();
    const int e0 = blockIdx.x * EPB;
    int v[8], rb[8];
#pragma unroll
    for (int k = 0; k < 8; k++) {
        int e = e0 + k * 256 + t;
        rb[k] = -1;
        if (e < E) {
            int d = dst[e], s = src[e];
            int b = d >> 8;
            int r = atomicAdd(&cnt[b], 1);
            v[k] = (s << 8) | (d & 255);
            rb[k] = (r << 8) | b;
        }
    }
    __syncthreads();
    for (int i = t; i < NBUCK; i += 256) {
        int c = cnt[i];
        bbs[i] = c ? atomicAdd(&bwp[i], c) : 0;
    }
    __syncthreads();
#pragma unroll
    for (int k = 0; k < 8; k++) {
        if (rb[k] >= 0) {
            int b = rb[k] & 255;
            int r = rb[k] >> 8;
            tmp[bbs[b] + r] = v[k];
        }
    }
}

// ---------------- pass B: per-bucket degree+scan+rowptr, scatter col ----------------
__global__ __launch_bounds__(256) void k_bucketB(const int* __restrict__ bbase,
                                                 const int* __restrict__ tmp,
                                                 int* __restrict__ col,
                                                 int* __restrict__ rowptr, int E) {
    __shared__ int degs[256];
    __shared__ int wp[256];
    __shared__ int wsum[4];
    const int b = blockIdx.x, t = threadIdx.x;
    const int n0 = b << 8;
    const int beg = bbase[b], end = bbase[b + 1];
    degs[t] = 0;
    __syncthreads();
    for (int e = beg + t; e < end; e += 256)
        atomicAdd(&degs[tmp[e] & 255], 1);
    __syncthreads();
    const int d = degs[t];
    int incl = d;
    const int lane = t & 63, w = t >> 6;
#pragma unroll
    for (int s = 1; s < 64; s <<= 1) {
        int u = __shfl_up(incl, s);
        if (lane >= s) incl += u;
    }
    if (lane == 63) wsum[w] = incl;
    __syncthreads();
    if (t == 0) {
        int r = 0;
#pragma unroll
        for (int i = 0; i < 4; i++) { int x = wsum[i]; wsum[i] = r; r += x; }
    }
    __syncthreads();
    const int excl = incl - d + wsum[w] + beg;
    const int nidx = n0 + t;
    if (nidx < NODES) rowptr[nidx] = excl;
    wp[t] = excl;
    if (b == 0 && t == 0) rowptr[NODES] = E;
    __syncthreads();
    for (int e = beg + t; e < end; e += 256) {
        int v = tmp[e];
        int p = atomicAdd(&wp[v & 255], 1);
        col[p] = v >> 8;
    }
}

// ---------------- layer-1 aggregation: one wave per dst node, SINGLE PASS ----------------
// No segment-max (scores are O(1); softmax is shift-invariant).
// lane = head*16 + sub for scores; lane = q*16 + ll for features (4 edges/iter).
__global__ __launch_bounds__(256) void k_agg1(const unsigned short* __restrict__ h1b,
                                              const float* __restrict__ as1,
                                              const float* __restrict__ ad1,
                                              const int* __restrict__ rowptr,
                                              const int* __restrict__ col,
                                              const float* __restrict__ b1,
                                              float* __restrict__ out1) {
    int wid = (blockIdx.x * 256 + threadIdx.x) >> 6;
    if (wid >= NODES) return;
    const int lane = threadIdx.x & 63;
    const int sub = lane & 15;
    const int head = lane >> 4;
    const int q  = lane >> 4;       // feature edge slot
    const int ll = lane & 15;       // feature channel group (8 ch)
    const int fh = ll >> 2;         // head owning channel group
    const int n = wid;
    const float adn = ad1[n * HEADS + head];
    const int rs = rowptr[n], re = rowptr[n + 1];
    const float wself = __expf(lrelu(as1[n * HEADS + head] + adn));

    float den = (sub == 0) ? wself : 0.f;
    float ac[8];
#pragma unroll
    for (int k = 0; k < 8; k++) ac[k] = 0.f;

    for (int base = rs; base < re; base += 16) {
        int i = base + sub;
        float w = 0.f; int c = 0;
        if (i < re) {
            c = col[i];
            unsigned aoff = ((unsigned)c << 4) + (unsigned)(head << 2);
            w = __expf(lrelu(*(const float*)((const char*)as1 + aoff) + adn));
        }
        den += w;
        int cnt = re - base; if (cnt > 16) cnt = 16;
        for (int j = 0; j < cnt; j += 4) {
            int sl = fh * 16 + j + q;             // j+q <= 15 always
            int   sj = __shfl(c, sl);
            float wj = __shfl(w, sl);             // 0 beyond cnt
            unsigned off = ((unsigned)sj << 8) + (unsigned)(ll << 4);
            uint4 pk = *(const uint4*)((const char*)h1b + off);
            ac[0] = fmaf(wj, bflo(pk.x), ac[0]); ac[1] = fmaf(wj, bfhi(pk.x), ac[1]);
            ac[2] = fmaf(wj, bflo(pk.y), ac[2]); ac[3] = fmaf(wj, bfhi(pk.y), ac[3]);
            ac[4] = fmaf(wj, bflo(pk.z), ac[4]); ac[5] = fmaf(wj, bfhi(pk.z), ac[5]);
            ac[6] = fmaf(wj, bflo(pk.w), ac[6]); ac[7] = fmaf(wj, bfhi(pk.w), ac[7]);
        }
    }
#pragma unroll
    for (int d = 1; d < 16; d <<= 1) den += __shfl_xor(den, d);
    const float den_f = __shfl(den, fh * 16);
    const float ws_f  = __shfl(wself, fh * 16);
#pragma unroll
    for (int k = 0; k < 8; k++) {
        ac[k] += __shfl_xor(ac[k], 16);
        ac[k] += __shfl_xor(ac[k], 32);
    }
    if (q == 0) {
        unsigned offs = ((unsigned)n << 8) + (unsigned)(ll << 4);
        uint4 sp = *(const uint4*)((const char*)h1b + offs);
        float sv[8] = {bflo(sp.x), bfhi(sp.x), bflo(sp.y), bfhi(sp.y),
                       bflo(sp.z), bfhi(sp.z), bflo(sp.w), bfhi(sp.w)};
        float4 bv0 = *(const float4*)(b1 + ll * 8);
        float4 bv1 = *(const float4*)(b1 + ll * 8 + 4);
        float bb[8] = {bv0.x, bv0.y, bv0.z, bv0.w, bv1.x, bv1.y, bv1.z, bv1.w};
        float o[8];
#pragma unroll
        for (int k = 0; k < 8; k++)
            o[k] = fmaxf((ac[k] + ws_f * sv[k]) / den_f + bb[k], 0.f);
        *(float4*)(out1 + (size_t)n * C1 + ll * 8) =
            make_float4(o[0], o[1], o[2], o[3]);
        *(float4*)(out1 + (size_t)n * C1 + ll * 8 + 4) =
            make_float4(o[4], o[5], o[6], o[7]);
    }
}

// ---- GEMM2: h2[N,40](fp32) + h2b[N,64-stride](bf16) = out1 @ W2 ----
__global__ __launch_bounds__(320) void k_gemm2(const float* __restrict__ A,
                                               const float* __restrict__ W,
                                               float* __restrict__ H,
                                               unsigned short* __restrict__ h2b) {
    __shared__ float xs[64][132];
    __shared__ float ws2[128 * 40];
    const int tid = threadIdx.x;
    const int row0 = blockIdx.x * 64;
    for (int q = tid; q < 1280; q += 320)
        *(float4*)(ws2 + q * 4) = *(const float4*)(W + q * 4);
    for (int q = tid; q < 2048; q += 320) {
        int r = q >> 5, kq = (q & 31) * 4;
        int gr = row0 + r;
        float4 v = make_float4(0.f, 0.f, 0.f, 0.f);
        if (gr < NODES) v = *(const float4*)(A + (size_t)gr * FIN + kq);
        *(float4*)(&xs[r][kq]) = v;
    }
    __syncthreads();
    const int r = tid / 5;
    const int c0 = (tid % 5) * 8;
    float acc[8];
#pragma unroll
    for (int j = 0; j < 8; j++) acc[j] = 0.f;
    for (int k = 0; k < 128; k++) {
        float a = xs[r][k];
        float4 b0 = *(float4*)(ws2 + k * CLS + c0);
        float4 b1 = *(float4*)(ws2 + k * CLS + c0 + 4);
        acc[0] = fmaf(a, b0.x, acc[0]); acc[1] = fmaf(a, b0.y, acc[1]);
        acc[2] = fmaf(a, b0.z, acc[2]); acc[3] = fmaf(a, b0.w, acc[3]);
        acc[4] = fmaf(a, b1.x, acc[4]); acc[5] = fmaf(a, b1.y, acc[5]);
        acc[6] = fmaf(a, b1.z, acc[6]); acc[7] = fmaf(a, b1.w, acc[7]);
    }
    int gr = row0 + r;
    if (gr < NODES) {
        *(float4*)(H + (size_t)gr * CLS + c0) =
            make_float4(acc[0], acc[1], acc[2], acc[3]);
        *(float4*)(H + (size_t)gr * CLS + c0 + 4) =
            make_float4(acc[4], acc[5], acc[6], acc[7]);
        unsigned short tb[8];
#pragma unroll
        for (int j = 0; j < 8; j++) tb[j] = f2bf(acc[j]);
        uint4 pk;
        pk.x = (unsigned)tb[0] | ((unsigned)tb[1] << 16);
        pk.y = (unsigned)tb[2] | ((unsigned)tb[3] << 16);
        pk.z = (unsigned)tb[4] | ((unsigned)tb[5] << 16);
        pk.w = (unsigned)tb[6] | ((unsigned)tb[7] << 16);
        *(uint4*)(h2b + (size_t)gr * 64 + c0) = pk;
    }
}

// ---------------- per-node attention dots, layer 2 (fp32-exact) ----------------
__global__ void k_att2(const float* __restrict__ H2, const float* __restrict__ AS,
                       const float* __restrict__ AD, float* __restrict__ as2,
                       float* __restrict__ ad2) {
    int n = blockIdx.x * 256 + threadIdx.x;
    if (n >= NODES) return;
    const float* hp = H2 + (size_t)n * CLS;
    float s = 0.f, d = 0.f;
#pragma unroll
    for (int c = 0; c < CLS; c++) {
        float v = hp[c];
        s = fmaf(v, AS[c], s);
        d = fmaf(v, AD[c], d);
    }
    as2[n] = s;
    ad2[n] = d;
}

// ---------------- layer-2 aggregation: one wave per dst node, SINGLE PASS ----------------
__global__ __launch_bounds__(256) void k_agg2(const unsigned short* __restrict__ h2b,
                                              const float* __restrict__ as2,
                                              const float* __restrict__ ad2,
                                              const int* __restrict__ rowptr,
                                              const int* __restrict__ col,
                                              const float* __restrict__ b2,
                                              float* __restrict__ out) {
    int wid = (blockIdx.x * 256 + threadIdx.x) >> 6;
    if (wid >= NODES) return;
    const int lane = threadIdx.x & 63;
    const int q8 = lane >> 3, l8 = lane & 7;
    const int n = wid;
    const float adn = ad2[n];
    const int rs = rowptr[n], re = rowptr[n + 1];
    const float wself = __expf(lrelu(as2[n] + adn));

    float den = (lane == 0) ? wself : 0.f;
    float ac[8];
#pragma unroll
    for (int k = 0; k < 8; k++) ac[k] = 0.f;
    for (int base = rs; base < re; base += 64) {
        int i = base + lane;
        float w = 0.f; int c = 0;
        if (i < re) {
            c = col[i];
            w = __expf(lrelu(as2[c] + adn));
        }
        den += w;
        int cnt = re - base; if (cnt > 64) cnt = 64;
        for (int j = 0; j < cnt; j += 8) {
            int jj = j + q8;                   // <= 63 always
            int   sj = __shfl(c, jj);
            float wj = __shfl(w, jj);          // 0 beyond cnt
            if (l8 < 5) {
                unsigned off = ((unsigned)sj << 7) + (unsigned)(l8 << 4);
                uint4 pk = *(const uint4*)((const char*)h2b + off);
                ac[0] = fmaf(wj, bflo(pk.x), ac[0]); ac[1] = fmaf(wj, bfhi(pk.x), ac[1]);
                ac[2] = fmaf(wj, bflo(pk.y), ac[2]); ac[3] = fmaf(wj, bfhi(pk.y), ac[3]);
                ac[4] = fmaf(wj, bflo(pk.z), ac[4]); ac[5] = fmaf(wj, bfhi(pk.z), ac[5]);
                ac[6] = fmaf(wj, bflo(pk.w), ac[6]); ac[7] = fmaf(wj, bfhi(pk.w), ac[7]);
            }
        }
    }
#pragma unroll
    for (int d = 1; d < 64; d <<= 1) den += __shfl_xor(den, d);
#pragma unroll
    for (int k = 0; k < 8; k++) {
        ac[k] += __shfl_xor(ac[k], 8);
        ac[k] += __shfl_xor(ac[k], 16);
        ac[k] += __shfl_xor(ac[k], 32);
    }
    if (q8 == 0 && l8 < 5) {
        unsigned offs = ((unsigned)n << 7) + (unsigned)(l8 << 4);
        uint4 sp = *(const uint4*)((const char*)h2b + offs);
        float sv[8] = {bflo(sp.x), bfhi(sp.x), bflo(sp.y), bfhi(sp.y),
                       bflo(sp.z), bfhi(sp.z), bflo(sp.w), bfhi(sp.w)};
        float4 bv0 = *(const float4*)(b2 + l8 * 8);
        float4 bv1 = *(const float4*)(b2 + l8 * 8 + 4);
        float bb[8] = {bv0.x, bv0.y, bv0.z, bv0.w, bv1.x, bv1.y, bv1.z, bv1.w};
        float o[8];
#pragma unroll
        for (int k = 0; k < 8; k++)
            o[k] = (ac[k] + wself * sv[k]) / den + bb[k];
        *(float4*)(out + (size_t)n * CLS + l8 * 8) =
            make_float4(o[0], o[1], o[2], o[3]);
        *(float4*)(out + (size_t)n * CLS + l8 * 8 + 4) =
            make_float4(o[4], o[5], o[6], o[7]);
    }
}

extern "C" void kernel_launch(void* const* d_in, const int* in_sizes, int n_in,
                              void* d_out, int out_size, void* d_ws, size_t ws_size,
                              hipStream_t stream) {
    const float* x     = (const float*)d_in[0];
    const int*   ei    = (const int*)d_in[1];
    const float* W1    = (const float*)d_in[2];
    const float* aS1   = (const float*)d_in[3];
    const float* aD1   = (const float*)d_in[4];
    const float* b1    = (const float*)d_in[5];
    const float* W2    = (const float*)d_in[6];
    const float* aS2   = (const float*)d_in[7];
    const float* aD2   = (const float*)d_in[8];
    const float* b2    = (const float*)d_in[9];
    float* out = (float*)d_out;
    const int E = in_sizes[1] / 2;
    const int* src = ei;
    const int* dst = ei + E;

    char* ws = (char*)d_ws;
    size_t off = 0;
    auto alloc = [&](size_t bytes) -> char* {
        char* p = ws + off;
        off += (bytes + 255) & ~(size_t)255;
        return p;
    };
    unsigned short* h1b = (unsigned short*)alloc((size_t)NODES * C1 * 2);
    float* out1   = (float*)alloc((size_t)NODES * C1 * 4);
    float* h2     = (float*)alloc((size_t)NODES * CLS * 4);
    unsigned short* h2b = (unsigned short*)alloc((size_t)NODES * 64 * 2);
    float* as1    = (float*)alloc((size_t)NODES * HEADS * 4);
    float* ad1    = (float*)alloc((size_t)NODES * HEADS * 4);
    float* as2    = (float*)alloc((size_t)NODES * 4);
    float* ad2    = (float*)alloc((size_t)NODES * 4);
    int* rowptr   = (int*)alloc((size_t)(NODES + 1) * 4);
    int* col      = (int*)alloc((size_t)E * 4);
    int* tmp      = (int*)alloc((size_t)E * 4);
    int* bcnt     = (int*)alloc((size_t)NBUCK * 4);
    int* bbase    = (int*)alloc((size_t)(NBUCK + 1) * 4);
    int* bwp      = (int*)alloc((size_t)NBUCK * 4);

    k_zero<<<1, 256, 0, stream>>>(bcnt, NBUCK);
    k_gemm1<<<(NODES + 63) / 64, 256, 0, stream>>>(x, W1, aS1, aD1, h1b, as1, ad1);
    k_bhist<<<(E + EPB - 1) / EPB, 256, 0, stream>>>(dst, E, bcnt);
    k_bscan<<<1, 256, 0, stream>>>(bcnt, bbase, bwp);
    k_bucketA<<<(E + EPB - 1) / EPB, 256, 0, stream>>>(src, dst, E, bwp, tmp);
    k_bucketB<<<NBUCK, 256, 0, stream>>>(bbase, tmp, col, rowptr, E);
    k_agg1<<<(NODES * 64) / 256, 256, 0, stream>>>(h1b, as1, ad1, rowptr, col, b1, out1);
    k_gemm2<<<(NODES + 63) / 64, 320, 0, stream>>>(out1, W2, h2, h2b);
    k_att2<<<(NODES + 255) / 256, 256, 0, stream>>>(h2, aS2, aD2, as2, ad2);
    k_agg2<<<(NODES * 64) / 256, 256, 0, stream>>>(h2b, as2, ad2, rowptr, col, b2, out);
}

// Round 9
// 246.539 us; speedup vs baseline: 2.4626x; 1.0193x over previous
//
#include <hip/hip_runtime.h>
#include <cstdint>

#define NODES 50000
#define FIN   128
#define C1    128   // HEADS*HID
#define HEADS 4
#define HID   32
#define CLS   40
#define SLOPE 0.2f

#define NBUCK ((NODES + 255) >> 8)   // 196
#define EPB 2048                     // edges per bucketA/bhist block

__device__ __forceinline__ float lrelu(float v) { return v > 0.f ? v : SLOPE * v; }

__device__ __forceinline__ unsigned short f2bf(float f) {
    union { float f; unsigned u; } v; v.f = f;
    unsigned u = v.u;
    return (unsigned short)((u + 0x7FFFu + ((u >> 16) & 1u)) >> 16);
}
__device__ __forceinline__ float bflo(unsigned u) {
    union { unsigned x; float f; } v; v.x = u << 16; return v.f;
}
__device__ __forceinline__ float bfhi(unsigned u) {
    union { unsigned x; float f; } v; v.x = u & 0xffff0000u; return v.f;
}

// ---------------- zero int buffer ----------------
__global__ void k_zero(int* __restrict__ p, int n) {
    int i = blockIdx.x * 256 + threadIdx.x;
    if (i < n) p[i] = 0;
}

// ---- GEMM1: h1b[N,128](bf16) = x @ W1 ; also as1/ad1 from fp32 acc ----
__global__ __launch_bounds__(256) void k_gemm1(const float* __restrict__ X,
                                               const float* __restrict__ W,
                                               const float* __restrict__ AS,
                                               const float* __restrict__ AD,
                                               unsigned short* __restrict__ h1b,
                                               float* __restrict__ as1,
                                               float* __restrict__ ad1) {
    __shared__ float As[64][17];
    __shared__ float Bs[16][128];
    const int tid = threadIdx.x;
    const int tx = tid & 15, ty = tid >> 4;
    const int row0 = blockIdx.x * 64;
    float acc[4][8];
#pragma unroll
    for (int i = 0; i < 4; i++)
#pragma unroll
        for (int j = 0; j < 8; j++) acc[i][j] = 0.f;

    for (int k0 = 0; k0 < FIN; k0 += 16) {
        {
            int r = tid >> 2, kq = (tid & 3) * 4;
            int gr = row0 + r;
            float4 va = make_float4(0.f, 0.f, 0.f, 0.f);
            if (gr < NODES) va = *(const float4*)(X + (size_t)gr * FIN + k0 + kq);
            As[r][kq + 0] = va.x; As[r][kq + 1] = va.y;
            As[r][kq + 2] = va.z; As[r][kq + 3] = va.w;
        }
#pragma unroll
        for (int i = 0; i < 2; i++) {
            int qq = tid * 2 + i;
            int rr = qq >> 5, cq = (qq & 31) * 4;
            *(float4*)(&Bs[rr][cq]) = *(const float4*)(W + (size_t)(k0 + rr) * C1 + cq);
        }
        __syncthreads();
#pragma unroll
        for (int kk = 0; kk < 16; kk++) {
            float a[4];
#pragma unroll
            for (int i = 0; i < 4; i++) a[i] = As[ty * 4 + i][kk];
            float4 b0 = *(float4*)(&Bs[kk][tx * 8]);
            float4 b1 = *(float4*)(&Bs[kk][tx * 8 + 4]);
            float b[8] = {b0.x, b0.y, b0.z, b0.w, b1.x, b1.y, b1.z, b1.w};
#pragma unroll
            for (int i = 0; i < 4; i++)
#pragma unroll
                for (int j = 0; j < 8; j++) acc[i][j] = fmaf(a[i], b[j], acc[i][j]);
        }
        __syncthreads();
    }
#pragma unroll
    for (int i = 0; i < 4; i++) {
        int gr = row0 + ty * 4 + i;
        if (gr < NODES) {
            unsigned short tb[8];
#pragma unroll
            for (int j = 0; j < 8; j++) tb[j] = f2bf(acc[i][j]);
            uint4 pk;
            pk.x = (unsigned)tb[0] | ((unsigned)tb[1] << 16);
            pk.y = (unsigned)tb[2] | ((unsigned)tb[3] << 16);
            pk.z = (unsigned)tb[4] | ((unsigned)tb[5] << 16);
            pk.w = (unsigned)tb[6] | ((unsigned)tb[7] << 16);
            *(uint4*)(h1b + (size_t)gr * C1 + tx * 8) = pk;
        }
    }
    const int h = tx >> 2;
    const int co = (tx & 3) * 8;
    float ps[4], pd[4];
#pragma unroll
    for (int i = 0; i < 4; i++) {
        float s = 0.f, d = 0.f;
#pragma unroll
        for (int j = 0; j < 8; j++) {
            s = fmaf(acc[i][j], AS[h * HID + co + j], s);
            d = fmaf(acc[i][j], AD[h * HID + co + j], d);
        }
        ps[i] = s; pd[i] = d;
    }
#pragma unroll
    for (int i = 0; i < 4; i++) {
        ps[i] += __shfl_xor(ps[i], 1); ps[i] += __shfl_xor(ps[i], 2);
        pd[i] += __shfl_xor(pd[i], 1); pd[i] += __shfl_xor(pd[i], 2);
    }
    if ((tx & 3) == 0) {
#pragma unroll
        for (int i = 0; i < 4; i++) {
            int gr = row0 + ty * 4 + i;
            if (gr < NODES) {
                as1[gr * HEADS + h] = ps[i];
                ad1[gr * HEADS + h] = pd[i];
            }
        }
    }
}

// ---------------- bucket histogram: bcnt[b] = #edges with dst>>8 == b ----------------
__global__ __launch_bounds__(256) void k_bhist(const int* __restrict__ dst, int E,
                                               int* __restrict__ bcnt) {
    __shared__ int cnt[NBUCK];
    const int t = threadIdx.x;
    for (int i = t; i < NBUCK; i += 256) cnt[i] = 0;
    __syncthreads();
    const int e0 = blockIdx.x * EPB;
#pragma unroll
    for (int k = 0; k < 8; k++) {
        int e = e0 + k * 256 + t;
        if (e < E) atomicAdd(&cnt[dst[e] >> 8], 1);
    }
    __syncthreads();
    for (int i = t; i < NBUCK; i += 256) {
        int c = cnt[i];
        if (c) atomicAdd(&bcnt[i], c);
    }
}

// ---------------- one-block scan of bucket counts -> bbase, bwp ----------------
__global__ __launch_bounds__(256) void k_bscan(const int* __restrict__ bcnt,
                                               int* __restrict__ bbase,
                                               int* __restrict__ bwp) {
    __shared__ int ws[4];
    const int t = threadIdx.x;
    const int lane = t & 63, w = t >> 6;
    int v = (t < NBUCK) ? bcnt[t] : 0;
    int incl = v;
#pragma unroll
    for (int s = 1; s < 64; s <<= 1) {
        int u = __shfl_up(incl, s);
        if (lane >= s) incl += u;
    }
    if (lane == 63) ws[w] = incl;
    __syncthreads();
    if (t == 0) {
        int r = 0;
#pragma unroll
        for (int i = 0; i < 4; i++) { int x = ws[i]; ws[i] = r; r += x; }
    }
    __syncthreads();
    int excl = incl - v + ws[w];
    if (t < NBUCK) { bbase[t] = excl; bwp[t] = excl; }
    if (t == NBUCK) bbase[NBUCK] = excl;   // total E
}

// ---------------- pass A: bucket edges by dst>>8 into staging ----------------
__global__ __launch_bounds__(256) void k_bucketA(const int* __restrict__ src,
                                                 const int* __restrict__ dst, int E,
                                                 int* __restrict__ bwp,
                                                 int* __restrict__ tmp) {
    __shared__ int cnt[NBUCK];
    __shared__ int bbs[NBUCK];
    const int t = threadIdx.x;
    for (int i = t; i < NBUCK; i += 256) cnt[i] = 0;
    __syncthreads();
    const int e0 = blockIdx.x * EPB;
    int v[8], rb[8];
#pragma unroll
    for (int k = 0; k < 8; k++) {
        int e = e0 + k * 256 + t;
        rb[k] = -1;
        if (e < E) {
            int d = dst[e], s = src[e];
            int b = d >> 8;
            int r = atomicAdd(&cnt[b], 1);
            v[k] = (s << 8) | (d & 255);
            rb[k] = (r << 8) | b;
        }
    }
    __syncthreads();
    for (int i = t; i < NBUCK; i += 256) {
        int c = cnt[i];
        bbs[i] = c ? atomicAdd(&bwp[i], c) : 0;
    }
    __syncthreads();
#pragma unroll
    for (int k = 0; k < 8; k++) {
        if (rb[k] >= 0) {
            int b = rb[k] & 255;
            int r = rb[k] >> 8;
            tmp[bbs[b] + r] = v[k];
        }
    }
}

// ---------------- pass B: per-bucket degree+scan+rowptr, scatter col ----------------
__global__ __launch_bounds__(256) void k_bucketB(const int* __restrict__ bbase,
                                                 const int* __restrict__ tmp,
                                                 int* __restrict__ col,
                                                 int* __restrict__ rowptr, int E) {
    __shared__ int degs[256];
    __shared__ int wp[256];
    __shared__ int wsum[4];
    const int b = blockIdx.x, t = threadIdx.x;
    const int n0 = b << 8;
    const int beg = bbase[b], end = bbase[b + 1];
    degs[t] = 0;
    __syncthreads();
    for (int e = beg + t; e < end; e += 256)
        atomicAdd(&degs[tmp[e] & 255], 1);
    __syncthreads();
    const int d = degs[t];
    int incl = d;
    const int lane = t & 63, w = t >> 6;
#pragma unroll
    for (int s = 1; s < 64; s <<= 1) {
        int u = __shfl_up(incl, s);
        if (lane >= s) incl += u;
    }
    if (lane == 63) wsum[w] = incl;
    __syncthreads();
    if (t == 0) {
        int r = 0;
#pragma unroll
        for (int i = 0; i < 4; i++) { int x = wsum[i]; wsum[i] = r; r += x; }
    }
    __syncthreads();
    const int excl = incl - d + wsum[w] + beg;
    const int nidx = n0 + t;
    if (nidx < NODES) rowptr[nidx] = excl;
    wp[t] = excl;
    if (b == 0 && t == 0) rowptr[NODES] = E;
    __syncthreads();
    for (int e = beg + t; e < end; e += 256) {
        int v = tmp[e];
        int p = atomicAdd(&wp[v & 255], 1);
        col[p] = v >> 8;
    }
}

// ---------------- layer-1 aggregation: one wave per dst node ----------------
// lane = q*16 + ll: q = edge slot (4 edges/group), ll = channel group (8 ch),
// fh = ll>>2 = head. Each lane computes its edge's weight INLINE (redundant
// across the 4 ll-groups of a head — free: issue cost is per-wave). No shfl
// in the hot loop. Main loop unrolled 2x (8 edges, no guards); guarded tail.
__global__ __launch_bounds__(256) void k_agg1(const unsigned short* __restrict__ h1b,
                                              const float* __restrict__ as1,
                                              const float* __restrict__ ad1,
                                              const int* __restrict__ rowptr,
                                              const int* __restrict__ col,
                                              const float* __restrict__ b1,
                                              float* __restrict__ out1) {
    int wid = (blockIdx.x * 256 + threadIdx.x) >> 6;
    if (wid >= NODES) return;
    const int lane = threadIdx.x & 63;
    const int q  = lane >> 4;       // edge slot
    const int ll = lane & 15;       // channel group
    const int fh = ll >> 2;         // head
    const int n = wid;
    const float adn = ad1[n * HEADS + fh];
    const int rs = rowptr[n], re = rowptr[n + 1];

    float den = 0.f;
    float ac[8];
#pragma unroll
    for (int k = 0; k < 8; k++) ac[k] = 0.f;

    int base = rs;
    for (; base + 8 <= re; base += 8) {
        int i0 = base + q, i1 = base + 4 + q;
        int c0 = col[i0], c1 = col[i1];
        float w0 = __expf(lrelu(as1[c0 * HEADS + fh] + adn));
        float w1 = __expf(lrelu(as1[c1 * HEADS + fh] + adn));
        den += w0 + w1;
        unsigned o0 = ((unsigned)c0 << 8) + (unsigned)(ll << 4);
        unsigned o1 = ((unsigned)c1 << 8) + (unsigned)(ll << 4);
        uint4 p0 = *(const uint4*)((const char*)h1b + o0);
        uint4 p1 = *(const uint4*)((const char*)h1b + o1);
        ac[0] = fmaf(w0, bflo(p0.x), ac[0]); ac[1] = fmaf(w0, bfhi(p0.x), ac[1]);
        ac[2] = fmaf(w0, bflo(p0.y), ac[2]); ac[3] = fmaf(w0, bfhi(p0.y), ac[3]);
        ac[4] = fmaf(w0, bflo(p0.z), ac[4]); ac[5] = fmaf(w0, bfhi(p0.z), ac[5]);
        ac[6] = fmaf(w0, bflo(p0.w), ac[6]); ac[7] = fmaf(w0, bfhi(p0.w), ac[7]);
        ac[0] = fmaf(w1, bflo(p1.x), ac[0]); ac[1] = fmaf(w1, bfhi(p1.x), ac[1]);
        ac[2] = fmaf(w1, bflo(p1.y), ac[2]); ac[3] = fmaf(w1, bfhi(p1.y), ac[3]);
        ac[4] = fmaf(w1, bflo(p1.z), ac[4]); ac[5] = fmaf(w1, bfhi(p1.z), ac[5]);
        ac[6] = fmaf(w1, bflo(p1.w), ac[6]); ac[7] = fmaf(w1, bfhi(p1.w), ac[7]);
    }
    for (; base < re; base += 4) {
        int i = base + q;
        int c = (i < re) ? col[i] : n;
        float w = __expf(lrelu(as1[c * HEADS + fh] + adn));
        if (i >= re) w = 0.f;
        den += w;
        unsigned off = ((unsigned)c << 8) + (unsigned)(ll << 4);
        uint4 pk = *(const uint4*)((const char*)h1b + off);
        ac[0] = fmaf(w, bflo(pk.x), ac[0]); ac[1] = fmaf(w, bfhi(pk.x), ac[1]);
        ac[2] = fmaf(w, bflo(pk.y), ac[2]); ac[3] = fmaf(w, bfhi(pk.y), ac[3]);
        ac[4] = fmaf(w, bflo(pk.z), ac[4]); ac[5] = fmaf(w, bfhi(pk.z), ac[5]);
        ac[6] = fmaf(w, bflo(pk.w), ac[6]); ac[7] = fmaf(w, bfhi(pk.w), ac[7]);
    }
    // reduce across edge slots q (lane bits 4,5); stays within the same head
    den += __shfl_xor(den, 16);
    den += __shfl_xor(den, 32);
#pragma unroll
    for (int k = 0; k < 8; k++) {
        ac[k] += __shfl_xor(ac[k], 16);
        ac[k] += __shfl_xor(ac[k], 32);
    }
    const float wself = __expf(lrelu(as1[n * HEADS + fh] + adn));
    den += wself;
    if (q == 0) {
        unsigned offs = ((unsigned)n << 8) + (unsigned)(ll << 4);
        uint4 sp = *(const uint4*)((const char*)h1b + offs);
        float sv[8] = {bflo(sp.x), bfhi(sp.x), bflo(sp.y), bfhi(sp.y),
                       bflo(sp.z), bfhi(sp.z), bflo(sp.w), bfhi(sp.w)};
        float4 bv0 = *(const float4*)(b1 + ll * 8);
        float4 bv1 = *(const float4*)(b1 + ll * 8 + 4);
        float bb[8] = {bv0.x, bv0.y, bv0.z, bv0.w, bv1.x, bv1.y, bv1.z, bv1.w};
        float o[8];
#pragma unroll
        for (int k = 0; k < 8; k++)
            o[k] = fmaxf((ac[k] + wself * sv[k]) / den + bb[k], 0.f);
        *(float4*)(out1 + (size_t)n * C1 + ll * 8) =
            make_float4(o[0], o[1], o[2], o[3]);
        *(float4*)(out1 + (size_t)n * C1 + ll * 8 + 4) =
            make_float4(o[4], o[5], o[6], o[7]);
    }
}

// ---- GEMM2: h2[N,40](fp32) + h2b[N,64-stride](bf16) = out1 @ W2 ----
__global__ __launch_bounds__(320) void k_gemm2(const float* __restrict__ A,
                                               const float* __restrict__ W,
                                               float* __restrict__ H,
                                               unsigned short* __restrict__ h2b) {
    __shared__ float xs[64][132];
    __shared__ float ws2[128 * 40];
    const int tid = threadIdx.x;
    const int row0 = blockIdx.x * 64;
    for (int q = tid; q < 1280; q += 320)
        *(float4*)(ws2 + q * 4) = *(const float4*)(W + q * 4);
    for (int q = tid; q < 2048; q += 320) {
        int r = q >> 5, kq = (q & 31) * 4;
        int gr = row0 + r;
        float4 v = make_float4(0.f, 0.f, 0.f, 0.f);
        if (gr < NODES) v = *(const float4*)(A + (size_t)gr * FIN + kq);
        *(float4*)(&xs[r][kq]) = v;
    }
    __syncthreads();
    const int r = tid / 5;
    const int c0 = (tid % 5) * 8;
    float acc[8];
#pragma unroll
    for (int j = 0; j < 8; j++) acc[j] = 0.f;
    for (int k = 0; k < 128; k++) {
        float a = xs[r][k];
        float4 b0 = *(float4*)(ws2 + k * CLS + c0);
        float4 b1 = *(float4*)(ws2 + k * CLS + c0 + 4);
        acc[0] = fmaf(a, b0.x, acc[0]); acc[1] = fmaf(a, b0.y, acc[1]);
        acc[2] = fmaf(a, b0.z, acc[2]); acc[3] = fmaf(a, b0.w, acc[3]);
        acc[4] = fmaf(a, b1.x, acc[4]); acc[5] = fmaf(a, b1.y, acc[5]);
        acc[6] = fmaf(a, b1.z, acc[6]); acc[7] = fmaf(a, b1.w, acc[7]);
    }
    int gr = row0 + r;
    if (gr < NODES) {
        *(float4*)(H + (size_t)gr * CLS + c0) =
            make_float4(acc[0], acc[1], acc[2], acc[3]);
        *(float4*)(H + (size_t)gr * CLS + c0 + 4) =
            make_float4(acc[4], acc[5], acc[6], acc[7]);
        unsigned short tb[8];
#pragma unroll
        for (int j = 0; j < 8; j++) tb[j] = f2bf(acc[j]);
        uint4 pk;
        pk.x = (unsigned)tb[0] | ((unsigned)tb[1] << 16);
        pk.y = (unsigned)tb[2] | ((unsigned)tb[3] << 16);
        pk.z = (unsigned)tb[4] | ((unsigned)tb[5] << 16);
        pk.w = (unsigned)tb[6] | ((unsigned)tb[7] << 16);
        *(uint4*)(h2b + (size_t)gr * 64 + c0) = pk;
    }
}

// ---------------- per-node attention dots, layer 2 (fp32-exact) ----------------
__global__ void k_att2(const float* __restrict__ H2, const float* __restrict__ AS,
                       const float* __restrict__ AD, float* __restrict__ as2,
                       float* __restrict__ ad2) {
    int n = blockIdx.x * 256 + threadIdx.x;
    if (n >= NODES) return;
    const float* hp = H2 + (size_t)n * CLS;
    float s = 0.f, d = 0.f;
#pragma unroll
    for (int c = 0; c < CLS; c++) {
        float v = hp[c];
        s = fmaf(v, AS[c], s);
        d = fmaf(v, AD[c], d);
    }
    as2[n] = s;
    ad2[n] = d;
}

// ---------------- layer-2 aggregation: one wave per dst node ----------------
// lane = q8*8 + l8: 8 edge slots, l8<5 own channels l8*8..+7. Inline weights,
// no hot-loop shfl; 2x-unrolled main loop (16 edges), guarded tail.
__global__ __launch_bounds__(256) void k_agg2(const unsigned short* __restrict__ h2b,
                                              const float* __restrict__ as2,
                                              const float* __restrict__ ad2,
                                              const int* __restrict__ rowptr,
                                              const int* __restrict__ col,
                                              const float* __restrict__ b2,
                                              float* __restrict__ out) {
    int wid = (blockIdx.x * 256 + threadIdx.x) >> 6;
    if (wid >= NODES) return;
    const int lane = threadIdx.x & 63;
    const int q8 = lane >> 3, l8 = lane & 7;
    const int n = wid;
    const float adn = ad2[n];
    const int rs = rowptr[n], re = rowptr[n + 1];

    float den = 0.f;
    float ac[8];
#pragma unroll
    for (int k = 0; k < 8; k++) ac[k] = 0.f;

    int base = rs;
    for (; base + 16 <= re; base += 16) {
        int i0 = base + q8, i1 = base + 8 + q8;
        int c0 = col[i0], c1 = col[i1];
        float w0 = __expf(lrelu(as2[c0] + adn));
        float w1 = __expf(lrelu(as2[c1] + adn));
        den += w0 + w1;
        if (l8 < 5) {
            unsigned o0 = ((unsigned)c0 << 7) + (unsigned)(l8 << 4);
            unsigned o1 = ((unsigned)c1 << 7) + (unsigned)(l8 << 4);
            uint4 p0 = *(const uint4*)((const char*)h2b + o0);
            uint4 p1 = *(const uint4*)((const char*)h2b + o1);
            ac[0] = fmaf(w0, bflo(p0.x), ac[0]); ac[1] = fmaf(w0, bfhi(p0.x), ac[1]);
            ac[2] = fmaf(w0, bflo(p0.y), ac[2]); ac[3] = fmaf(w0, bfhi(p0.y), ac[3]);
            ac[4] = fmaf(w0, bflo(p0.z), ac[4]); ac[5] = fmaf(w0, bfhi(p0.z), ac[5]);
            ac[6] = fmaf(w0, bflo(p0.w), ac[6]); ac[7] = fmaf(w0, bfhi(p0.w), ac[7]);
            ac[0] = fmaf(w1, bflo(p1.x), ac[0]); ac[1] = fmaf(w1, bfhi(p1.x), ac[1]);
            ac[2] = fmaf(w1, bflo(p1.y), ac[2]); ac[3] = fmaf(w1, bfhi(p1.y), ac[3]);
            ac[4] = fmaf(w1, bflo(p1.z), ac[4]); ac[5] = fmaf(w1, bfhi(p1.z), ac[5]);
            ac[6] = fmaf(w1, bflo(p1.w), ac[6]); ac[7] = fmaf(w1, bfhi(p1.w), ac[7]);
        }
    }
    for (; base < re; base += 8) {
        int i = base + q8;
        int c = (i < re) ? col[i] : n;
        float w = __expf(lrelu(as2[c] + adn));
        if (i >= re) w = 0.f;
        den += w;
        if (l8 < 5) {
            unsigned off = ((unsigned)c << 7) + (unsigned)(l8 << 4);
            uint4 pk = *(const uint4*)((const char*)h2b + off);
            ac[0] = fmaf(w, bflo(pk.x), ac[0]); ac[1] = fmaf(w, bfhi(pk.x), ac[1]);
            ac[2] = fmaf(w, bflo(pk.y), ac[2]); ac[3] = fmaf(w, bfhi(pk.y), ac[3]);
            ac[4] = fmaf(w, bflo(pk.z), ac[4]); ac[5] = fmaf(w, bfhi(pk.z), ac[5]);
            ac[6] = fmaf(w, bflo(pk.w), ac[6]); ac[7] = fmaf(w, bfhi(pk.w), ac[7]);
        }
    }
    // reduce across edge slots q8 (lane bits 3,4,5)
    den += __shfl_xor(den, 8);
    den += __shfl_xor(den, 16);
    den += __shfl_xor(den, 32);
#pragma unroll
    for (int k = 0; k < 8; k++) {
        ac[k] += __shfl_xor(ac[k], 8);
        ac[k] += __shfl_xor(ac[k], 16);
        ac[k] += __shfl_xor(ac[k], 32);
    }
    const float wself = __expf(lrelu(as2[n] + adn));
    den += wself;
    if (q8 == 0 && l8 < 5) {
        unsigned offs = ((unsigned)n << 7) + (unsigned)(l8 << 4);
        uint4 sp = *(const uint4*)((const char*)h2b + offs);
        float sv[8] = {bflo(sp.x), bfhi(sp.x), bflo(sp.y), bfhi(sp.y),
                       bflo(sp.z), bfhi(sp.z), bflo(sp.w), bfhi(sp.w)};
        float4 bv0 = *(const float4*)(b2 + l8 * 8);
        float4 bv1 = *(const float4*)(b2 + l8 * 8 + 4);
        float bb[8] = {bv0.x, bv0.y, bv0.z, bv0.w, bv1.x, bv1.y, bv1.z, bv1.w};
        float o[8];
#pragma unroll
        for (int k = 0; k < 8; k++)
            o[k] = (ac[k] + wself * sv[k]) / den + bb[k];
        *(float4*)(out + (size_t)n * CLS + l8 * 8) =
            make_float4(o[0], o[1], o[2], o[3]);
        *(float4*)(out + (size_t)n * CLS + l8 * 8 + 4) =
            make_float4(o[4], o[5], o[6], o[7]);
    }
}

extern "C" void kernel_launch(void* const* d_in, const int* in_sizes, int n_in,
                              void* d_out, int out_size, void* d_ws, size_t ws_size,
                              hipStream_t stream) {
    const float* x     = (const float*)d_in[0];
    const int*   ei    = (const int*)d_in[1];
    const float* W1    = (const float*)d_in[2];
    const float* aS1   = (const float*)d_in[3];
    const float* aD1   = (const float*)d_in[4];
    const float* b1    = (const float*)d_in[5];
    const float* W2    = (const float*)d_in[6];
    const float* aS2   = (const float*)d_in[7];
    const float* aD2   = (const float*)d_in[8];
    const float* b2    = (const float*)d_in[9];
    float* out = (float*)d_out;
    const int E = in_sizes[1] / 2;
    const int* src = ei;
    const int* dst = ei + E;

    char* ws = (char*)d_ws;
    size_t off = 0;
    auto alloc = [&](size_t bytes) -> char* {
        char* p = ws + off;
        off += (bytes + 255) & ~(size_t)255;
        return p;
    };
    unsigned short* h1b = (unsigned short*)alloc((size_t)NODES * C1 * 2);
    float* out1   = (float*)alloc((size_t)NODES * C1 * 4);
    float* h2     = (float*)alloc((size_t)NODES * CLS * 4);
    unsigned short* h2b = (unsigned short*)alloc((size_t)NODES * 64 * 2);
    float* as1    = (float*)alloc((size_t)NODES * HEADS * 4);
    float* ad1    = (float*)alloc((size_t)NODES * HEADS * 4);
    float* as2    = (float*)alloc((size_t)NODES * 4);
    float* ad2    = (float*)alloc((size_t)NODES * 4);
    int* rowptr   = (int*)alloc((size_t)(NODES + 1) * 4);
    int* col      = (int*)alloc((size_t)E * 4);
    int* tmp      = (int*)alloc((size_t)E * 4);
    int* bcnt     = (int*)alloc((size_t)NBUCK * 4);
    int* bbase    = (int*)alloc((size_t)(NBUCK + 1) * 4);
    int* bwp      = (int*)alloc((size_t)NBUCK * 4);

    k_zero<<<1, 256, 0, stream>>>(bcnt, NBUCK);
    k_gemm1<<<(NODES + 63) / 64, 256, 0, stream>>>(x, W1, aS1, aD1, h1b, as1, ad1);
    k_bhist<<<(E + EPB - 1) / EPB, 256, 0, stream>>>(dst, E, bcnt);
    k_bscan<<<1, 256, 0, stream>>>(bcnt, bbase, bwp);
    k_bucketA<<<(E + EPB - 1) / EPB, 256, 0, stream>>>(src, dst, E, bwp, tmp);
    k_bucketB<<<NBUCK, 256, 0, stream>>>(bbase, tmp, col, rowptr, E);
    k_agg1<<<(NODES * 64) / 256, 256, 0, stream>>>(h1b, as1, ad1, rowptr, col, b1, out1);
    k_gemm2<<<(NODES + 63) / 64, 320, 0, stream>>>(out1, W2, h2, h2b);
    k_att2<<<(NODES + 255) / 256, 256, 0, stream>>>(h2, aS2, aD2, as2, ad2);
    k_agg2<<<(NODES * 64) / 256, 256, 0, stream>>>(h2b, as2, ad2, rowptr, col, b2, out);
}

// Round 10
// 240.161 us; speedup vs baseline: 2.5280x; 1.0266x over previous
//
#include <hip/hip_runtime.h>
#include <cstdint>

#define NODES 50000
#define FIN   128
#define C1    128   // HEADS*HID
#define HEADS 4
#define HID   32
#define CLS   40
#define SLOPE 0.2f

#define NBUCK ((NODES + 255) >> 8)   // 196
#define EPB 2048                     // edges per bucketA/bhist block

__device__ __forceinline__ float lrelu(float v) { return v > 0.f ? v : SLOPE * v; }

__device__ __forceinline__ unsigned short f2bf(float f) {
    union { float f; unsigned u; } v; v.f = f;
    unsigned u = v.u;
    return (unsigned short)((u + 0x7FFFu + ((u >> 16) & 1u)) >> 16);
}
__device__ __forceinline__ float bf2f(unsigned short b) {
    union { unsigned u; float f; } v; v.u = ((unsigned)b) << 16;
    return v.f;
}
__device__ __forceinline__ float bflo(unsigned u) {
    union { unsigned x; float f; } v; v.x = u << 16; return v.f;
}
__device__ __forceinline__ float bfhi(unsigned u) {
    union { unsigned x; float f; } v; v.x = u & 0xffff0000u; return v.f;
}

typedef __attribute__((ext_vector_type(8))) short bf16x8;
typedef __attribute__((ext_vector_type(4))) float f32x4;

// ---------------- zero int buffer ----------------
__global__ void k_zero(int* __restrict__ p, int n) {
    int i = blockIdx.x * 256 + threadIdx.x;
    if (i < n) p[i] = 0;
}

// ---- GEMM1 (MFMA bf16): h1b[N,128](bf16) = x @ W1 ; as1/ad1 fused ----
// block = 256 = 4 waves, 64 rows. Wt[n][k] bf16 in LDS (transposed W1).
// wave w: rows w*16..+15; 8 col-tiles x 4 k-steps of mfma_f32_16x16x32_bf16.
// A frag: lane l -> A[m=l&15][k=quad*8+j]; B frag: B[k=quad*8+j][n=l&15];
// D: lane l reg r -> D[row=quad*4+r][col=l&15].  C bounced via LDS for
// coalesced stores + attention dots.
__global__ __launch_bounds__(256) void k_gemm1(const float* __restrict__ X,
                                               const float* __restrict__ W,
                                               const float* __restrict__ AS,
                                               const float* __restrict__ AD,
                                               unsigned short* __restrict__ h1b,
                                               float* __restrict__ as1,
                                               float* __restrict__ ad1) {
    __shared__ unsigned short Asm[64][136];   // also reused as C output
    __shared__ unsigned short Wt[128][136];   // Wt[n][k]
    const int t = threadIdx.x;
    const int row0 = blockIdx.x * 64;

    // stage Wt: W[k][n] fp32 -> Wt[n][k] bf16, 2 k's per write (b32)
    for (int i = 0; i < 32; i++) {
        int p = i * 256 + t;            // pair index: kp = p>>7, n = p&127
        int kp = p >> 7, n = p & 127;
        float v0 = W[(size_t)(2 * kp) * C1 + n];
        float v1 = W[(size_t)(2 * kp + 1) * C1 + n];
        *(unsigned*)(&Wt[n][2 * kp]) =
            (unsigned)f2bf(v0) | ((unsigned)f2bf(v1) << 16);
    }
    // stage Asm: 64 rows of X as bf16
    {
        int r = t >> 2, c0 = (t & 3) * 32;
        int gr = row0 + r;
        unsigned short tb[32];
        if (gr < NODES) {
#pragma unroll
            for (int i = 0; i < 8; i++) {
                float4 v = *(const float4*)(X + (size_t)gr * FIN + c0 + i * 4);
                tb[i * 4 + 0] = f2bf(v.x); tb[i * 4 + 1] = f2bf(v.y);
                tb[i * 4 + 2] = f2bf(v.z); tb[i * 4 + 3] = f2bf(v.w);
            }
        } else {
#pragma unroll
            for (int i = 0; i < 32; i++) tb[i] = 0;
        }
#pragma unroll
        for (int i = 0; i < 4; i++) {
            uint4 pk;
            pk.x = (unsigned)tb[i*8+0] | ((unsigned)tb[i*8+1] << 16);
            pk.y = (unsigned)tb[i*8+2] | ((unsigned)tb[i*8+3] << 16);
            pk.z = (unsigned)tb[i*8+4] | ((unsigned)tb[i*8+5] << 16);
            pk.w = (unsigned)tb[i*8+6] | ((unsigned)tb[i*8+7] << 16);
            *(uint4*)(&Asm[r][c0 + i * 8]) = pk;
        }
    }
    __syncthreads();

    const int w = t >> 6, l = t & 63;
    const int lm = l & 15, quad = l >> 4;
    f32x4 acc[8];
#pragma unroll
    for (int ct = 0; ct < 8; ct++) acc[ct] = (f32x4){0.f, 0.f, 0.f, 0.f};
#pragma unroll
    for (int kt = 0; kt < 4; kt++) {
        bf16x8 a = *(const bf16x8*)(&Asm[w * 16 + lm][kt * 32 + quad * 8]);
#pragma unroll
        for (int ct = 0; ct < 8; ct++) {
            bf16x8 b = *(const bf16x8*)(&Wt[ct * 16 + lm][kt * 32 + quad * 8]);
            acc[ct] = __builtin_amdgcn_mfma_f32_16x16x32_bf16(a, b, acc[ct], 0, 0, 0);
        }
    }
    __syncthreads();
    // scatter C (bf16) into Asm
#pragma unroll
    for (int ct = 0; ct < 8; ct++)
#pragma unroll
        for (int r = 0; r < 4; r++)
            Asm[w * 16 + quad * 4 + r][ct * 16 + lm] = f2bf(acc[ct][r]);
    __syncthreads();
    // coalesced h1b write
    {
        int r = t >> 2, c0 = (t & 3) * 32;
        int gr = row0 + r;
        if (gr < NODES) {
#pragma unroll
            for (int i = 0; i < 4; i++)
                *(uint4*)(h1b + (size_t)gr * C1 + c0 + i * 8) =
                    *(uint4*)(&Asm[r][c0 + i * 8]);
        }
    }
    // attention dots from LDS C: thread -> (row, head)
    {
        int r = t >> 2, h = t & 3;
        int gr = row0 + r;
        if (gr < NODES) {
            float s = 0.f, d = 0.f;
#pragma unroll
            for (int j = 0; j < 32; j++) {
                float v = bf2f(Asm[r][h * 32 + j]);
                s = fmaf(v, AS[h * HID + j], s);
                d = fmaf(v, AD[h * HID + j], d);
            }
            as1[gr * HEADS + h] = s;
            ad1[gr * HEADS + h] = d;
        }
    }
}

// ---------------- bucket histogram: bcnt[b] = #edges with dst>>8 == b ----------------
__global__ __launch_bounds__(256) void k_bhist(const int* __restrict__ dst, int E,
                                               int* __restrict__ bcnt) {
    __shared__ int cnt[NBUCK];
    const int t = threadIdx.x;
    for (int i = t; i < NBUCK; i += 256) cnt[i] = 0;
    __syncthreads();
    const int e0 = blockIdx.x * EPB;
#pragma unroll
    for (int k = 0; k < 8; k++) {
        int e = e0 + k * 256 + t;
        if (e < E) atomicAdd(&cnt[dst[e] >> 8], 1);
    }
    __syncthreads();
    for (int i = t; i < NBUCK; i += 256) {
        int c = cnt[i];
        if (c) atomicAdd(&bcnt[i], c);
    }
}

// ---------------- one-block scan of bucket counts -> bbase, bwp ----------------
__global__ __launch_bounds__(256) void k_bscan(const int* __restrict__ bcnt,
                                               int* __restrict__ bbase,
                                               int* __restrict__ bwp) {
    __shared__ int ws[4];
    const int t = threadIdx.x;
    const int lane = t & 63, w = t >> 6;
    int v = (t < NBUCK) ? bcnt[t] : 0;
    int incl = v;
#pragma unroll
    for (int s = 1; s < 64; s <<= 1) {
        int u = __shfl_up(incl, s);
        if (lane >= s) incl += u;
    }
    if (lane == 63) ws[w] = incl;
    __syncthreads();
    if (t == 0) {
        int r = 0;
#pragma unroll
        for (int i = 0; i < 4; i++) { int x = ws[i]; ws[i] = r; r += x; }
    }
    __syncthreads();
    int excl = incl - v + ws[w];
    if (t < NBUCK) { bbase[t] = excl; bwp[t] = excl; }
    if (t == NBUCK) bbase[NBUCK] = excl;   // total E
}

// ---------------- pass A: bucket edges by dst>>8 into staging ----------------
__global__ __launch_bounds__(256) void k_bucketA(const int* __restrict__ src,
                                                 const int* __restrict__ dst, int E,
                                                 int* __restrict__ bwp,
                                                 int* __restrict__ tmp) {
    __shared__ int cnt[NBUCK];
    __shared__ int bbs[NBUCK];
    const int t = threadIdx.x;
    for (int i = t; i < NBUCK; i += 256) cnt[i] = 0;
    __syncthreads();
    const int e0 = blockIdx.x * EPB;
    int v[8], rb[8];
#pragma unroll
    for (int k = 0; k < 8; k++) {
        int e = e0 + k * 256 + t;
        rb[k] = -1;
        if (e < E) {
            int d = dst[e], s = src[e];
            int b = d >> 8;
            int r = atomicAdd(&cnt[b], 1);
            v[k] = (s << 8) | (d & 255);
            rb[k] = (r << 8) | b;
        }
    }
    __syncthreads();
    for (int i = t; i < NBUCK; i += 256) {
        int c = cnt[i];
        bbs[i] = c ? atomicAdd(&bwp[i], c) : 0;
    }
    __syncthreads();
#pragma unroll
    for (int k = 0; k < 8; k++) {
        if (rb[k] >= 0) {
            int b = rb[k] & 255;
            int r = rb[k] >> 8;
            tmp[bbs[b] + r] = v[k];
        }
    }
}

// ---------------- pass B: per-bucket degree+scan+rowptr, scatter col ----------------
__global__ __launch_bounds__(256) void k_bucketB(const int* __restrict__ bbase,
                                                 const int* __restrict__ tmp,
                                                 int* __restrict__ col,
                                                 int* __restrict__ rowptr, int E) {
    __shared__ int degs[256];
    __shared__ int wp[256];
    __shared__ int wsum[4];
    const int b = blockIdx.x, t = threadIdx.x;
    const int n0 = b << 8;
    const int beg = bbase[b], end = bbase[b + 1];
    degs[t] = 0;
    __syncthreads();
    for (int e = beg + t; e < end; e += 256)
        atomicAdd(&degs[tmp[e] & 255], 1);
    __syncthreads();
    const int d = degs[t];
    int incl = d;
    const int lane = t & 63, w = t >> 6;
#pragma unroll
    for (int s = 1; s < 64; s <<= 1) {
        int u = __shfl_up(incl, s);
        if (lane >= s) incl += u;
    }
    if (lane == 63) wsum[w] = incl;
    __syncthreads();
    if (t == 0) {
        int r = 0;
#pragma unroll
        for (int i = 0; i < 4; i++) { int x = wsum[i]; wsum[i] = r; r += x; }
    }
    __syncthreads();
    const int excl = incl - d + wsum[w] + beg;
    const int nidx = n0 + t;
    if (nidx < NODES) rowptr[nidx] = excl;
    wp[t] = excl;
    if (b == 0 && t == 0) rowptr[NODES] = E;
    __syncthreads();
    for (int e = beg + t; e < end; e += 256) {
        int v = tmp[e];
        int p = atomicAdd(&wp[v & 255], 1);
        col[p] = v >> 8;
    }
}

// ---------------- layer-1 aggregation: one wave per dst node ----------------
__global__ __launch_bounds__(256) void k_agg1(const unsigned short* __restrict__ h1b,
                                              const float* __restrict__ as1,
                                              const float* __restrict__ ad1,
                                              const int* __restrict__ rowptr,
                                              const int* __restrict__ col,
                                              const float* __restrict__ b1,
                                              float* __restrict__ out1) {
    int wid = (blockIdx.x * 256 + threadIdx.x) >> 6;
    if (wid >= NODES) return;
    const int lane = threadIdx.x & 63;
    const int q  = lane >> 4;       // edge slot
    const int ll = lane & 15;       // channel group
    const int fh = ll >> 2;         // head
    const int n = wid;
    const float adn = ad1[n * HEADS + fh];
    const int rs = rowptr[n], re = rowptr[n + 1];

    float den = 0.f;
    float ac[8];
#pragma unroll
    for (int k = 0; k < 8; k++) ac[k] = 0.f;

    int base = rs;
    for (; base + 8 <= re; base += 8) {
        int i0 = base + q, i1 = base + 4 + q;
        int c0 = col[i0], c1 = col[i1];
        float w0 = __expf(lrelu(as1[c0 * HEADS + fh] + adn));
        float w1 = __expf(lrelu(as1[c1 * HEADS + fh] + adn));
        den += w0 + w1;
        unsigned o0 = ((unsigned)c0 << 8) + (unsigned)(ll << 4);
        unsigned o1 = ((unsigned)c1 << 8) + (unsigned)(ll << 4);
        uint4 p0 = *(const uint4*)((const char*)h1b + o0);
        uint4 p1 = *(const uint4*)((const char*)h1b + o1);
        ac[0] = fmaf(w0, bflo(p0.x), ac[0]); ac[1] = fmaf(w0, bfhi(p0.x), ac[1]);
        ac[2] = fmaf(w0, bflo(p0.y), ac[2]); ac[3] = fmaf(w0, bfhi(p0.y), ac[3]);
        ac[4] = fmaf(w0, bflo(p0.z), ac[4]); ac[5] = fmaf(w0, bfhi(p0.z), ac[5]);
        ac[6] = fmaf(w0, bflo(p0.w), ac[6]); ac[7] = fmaf(w0, bfhi(p0.w), ac[7]);
        ac[0] = fmaf(w1, bflo(p1.x), ac[0]); ac[1] = fmaf(w1, bfhi(p1.x), ac[1]);
        ac[2] = fmaf(w1, bflo(p1.y), ac[2]); ac[3] = fmaf(w1, bfhi(p1.y), ac[3]);
        ac[4] = fmaf(w1, bflo(p1.z), ac[4]); ac[5] = fmaf(w1, bfhi(p1.z), ac[5]);
        ac[6] = fmaf(w1, bflo(p1.w), ac[6]); ac[7] = fmaf(w1, bfhi(p1.w), ac[7]);
    }
    for (; base < re; base += 4) {
        int i = base + q;
        int c = (i < re) ? col[i] : n;
        float w = __expf(lrelu(as1[c * HEADS + fh] + adn));
        if (i >= re) w = 0.f;
        den += w;
        unsigned off = ((unsigned)c << 8) + (unsigned)(ll << 4);
        uint4 pk = *(const uint4*)((const char*)h1b + off);
        ac[0] = fmaf(w, bflo(pk.x), ac[0]); ac[1] = fmaf(w, bfhi(pk.x), ac[1]);
        ac[2] = fmaf(w, bflo(pk.y), ac[2]); ac[3] = fmaf(w, bfhi(pk.y), ac[3]);
        ac[4] = fmaf(w, bflo(pk.z), ac[4]); ac[5] = fmaf(w, bfhi(pk.z), ac[5]);
        ac[6] = fmaf(w, bflo(pk.w), ac[6]); ac[7] = fmaf(w, bfhi(pk.w), ac[7]);
    }
    den += __shfl_xor(den, 16);
    den += __shfl_xor(den, 32);
#pragma unroll
    for (int k = 0; k < 8; k++) {
        ac[k] += __shfl_xor(ac[k], 16);
        ac[k] += __shfl_xor(ac[k], 32);
    }
    const float wself = __expf(lrelu(as1[n * HEADS + fh] + adn));
    den += wself;
    if (q == 0) {
        unsigned offs = ((unsigned)n << 8) + (unsigned)(ll << 4);
        uint4 sp = *(const uint4*)((const char*)h1b + offs);
        float sv[8] = {bflo(sp.x), bfhi(sp.x), bflo(sp.y), bfhi(sp.y),
                       bflo(sp.z), bfhi(sp.z), bflo(sp.w), bfhi(sp.w)};
        float4 bv0 = *(const float4*)(b1 + ll * 8);
        float4 bv1 = *(const float4*)(b1 + ll * 8 + 4);
        float bb[8] = {bv0.x, bv0.y, bv0.z, bv0.w, bv1.x, bv1.y, bv1.z, bv1.w};
        float o[8];
#pragma unroll
        for (int k = 0; k < 8; k++)
            o[k] = fmaxf((ac[k] + wself * sv[k]) / den + bb[k], 0.f);
        *(float4*)(out1 + (size_t)n * C1 + ll * 8) =
            make_float4(o[0], o[1], o[2], o[3]);
        *(float4*)(out1 + (size_t)n * C1 + ll * 8 + 4) =
            make_float4(o[4], o[5], o[6], o[7]);
    }
}

// ---- GEMM2 (+fused att2): h2b[N,64](bf16) = out1 @ W2 ; as2/ad2 from fp32 acc ----
__global__ __launch_bounds__(320) void k_gemm2(const float* __restrict__ A,
                                               const float* __restrict__ W,
                                               const float* __restrict__ AS,
                                               const float* __restrict__ AD,
                                               unsigned short* __restrict__ h2b,
                                               float* __restrict__ as2,
                                               float* __restrict__ ad2) {
    __shared__ float xs[64][132];
    __shared__ float ws2[128 * 40];
    __shared__ float sS[320];
    __shared__ float sD[320];
    const int tid = threadIdx.x;
    const int row0 = blockIdx.x * 64;
    for (int q = tid; q < 1280; q += 320)
        *(float4*)(ws2 + q * 4) = *(const float4*)(W + q * 4);
    for (int q = tid; q < 2048; q += 320) {
        int r = q >> 5, kq = (q & 31) * 4;
        int gr = row0 + r;
        float4 v = make_float4(0.f, 0.f, 0.f, 0.f);
        if (gr < NODES) v = *(const float4*)(A + (size_t)gr * FIN + kq);
        *(float4*)(&xs[r][kq]) = v;
    }
    __syncthreads();
    const int r = tid / 5;
    const int c0 = (tid % 5) * 8;
    float acc[8];
#pragma unroll
    for (int j = 0; j < 8; j++) acc[j] = 0.f;
    for (int k = 0; k < 128; k++) {
        float a = xs[r][k];
        float4 b0 = *(float4*)(ws2 + k * CLS + c0);
        float4 b1 = *(float4*)(ws2 + k * CLS + c0 + 4);
        acc[0] = fmaf(a, b0.x, acc[0]); acc[1] = fmaf(a, b0.y, acc[1]);
        acc[2] = fmaf(a, b0.z, acc[2]); acc[3] = fmaf(a, b0.w, acc[3]);
        acc[4] = fmaf(a, b1.x, acc[4]); acc[5] = fmaf(a, b1.y, acc[5]);
        acc[6] = fmaf(a, b1.z, acc[6]); acc[7] = fmaf(a, b1.w, acc[7]);
    }
    // partial attention dots (fp32-exact)
    {
        float s = 0.f, d = 0.f;
#pragma unroll
        for (int j = 0; j < 8; j++) {
            s = fmaf(acc[j], AS[c0 + j], s);
            d = fmaf(acc[j], AD[c0 + j], d);
        }
        sS[tid] = s; sD[tid] = d;
    }
    int gr = row0 + r;
    if (gr < NODES) {
        unsigned short tb[8];
#pragma unroll
        for (int j = 0; j < 8; j++) tb[j] = f2bf(acc[j]);
        uint4 pk;
        pk.x = (unsigned)tb[0] | ((unsigned)tb[1] << 16);
        pk.y = (unsigned)tb[2] | ((unsigned)tb[3] << 16);
        pk.z = (unsigned)tb[4] | ((unsigned)tb[5] << 16);
        pk.w = (unsigned)tb[6] | ((unsigned)tb[7] << 16);
        *(uint4*)(h2b + (size_t)gr * 64 + c0) = pk;
    }
    __syncthreads();
    if (tid < 64) {
        int grr = row0 + tid;
        if (grr < NODES) {
            int b5 = tid * 5;
            as2[grr] = sS[b5] + sS[b5+1] + sS[b5+2] + sS[b5+3] + sS[b5+4];
            ad2[grr] = sD[b5] + sD[b5+1] + sD[b5+2] + sD[b5+3] + sD[b5+4];
        }
    }
}

// ---------------- layer-2 aggregation: one wave per dst node ----------------
__global__ __launch_bounds__(256) void k_agg2(const unsigned short* __restrict__ h2b,
                                              const float* __restrict__ as2,
                                              const float* __restrict__ ad2,
                                              const int* __restrict__ rowptr,
                                              const int* __restrict__ col,
                                              const float* __restrict__ b2,
                                              float* __restrict__ out) {
    int wid = (blockIdx.x * 256 + threadIdx.x) >> 6;
    if (wid >= NODES) return;
    const int lane = threadIdx.x & 63;
    const int q8 = lane >> 3, l8 = lane & 7;
    const int n = wid;
    const float adn = ad2[n];
    const int rs = rowptr[n], re = rowptr[n + 1];

    float den = 0.f;
    float ac[8];
#pragma unroll
    for (int k = 0; k < 8; k++) ac[k] = 0.f;

    int base = rs;
    for (; base + 16 <= re; base += 16) {
        int i0 = base + q8, i1 = base + 8 + q8;
        int c0 = col[i0], c1 = col[i1];
        float w0 = __expf(lrelu(as2[c0] + adn));
        float w1 = __expf(lrelu(as2[c1] + adn));
        den += w0 + w1;
        if (l8 < 5) {
            unsigned o0 = ((unsigned)c0 << 7) + (unsigned)(l8 << 4);
            unsigned o1 = ((unsigned)c1 << 7) + (unsigned)(l8 << 4);
            uint4 p0 = *(const uint4*)((const char*)h2b + o0);
            uint4 p1 = *(const uint4*)((const char*)h2b + o1);
            ac[0] = fmaf(w0, bflo(p0.x), ac[0]); ac[1] = fmaf(w0, bfhi(p0.x), ac[1]);
            ac[2] = fmaf(w0, bflo(p0.y), ac[2]); ac[3] = fmaf(w0, bfhi(p0.y), ac[3]);
            ac[4] = fmaf(w0, bflo(p0.z), ac[4]); ac[5] = fmaf(w0, bfhi(p0.z), ac[5]);
            ac[6] = fmaf(w0, bflo(p0.w), ac[6]); ac[7] = fmaf(w0, bfhi(p0.w), ac[7]);
            ac[0] = fmaf(w1, bflo(p1.x), ac[0]); ac[1] = fmaf(w1, bfhi(p1.x), ac[1]);
            ac[2] = fmaf(w1, bflo(p1.y), ac[2]); ac[3] = fmaf(w1, bfhi(p1.y), ac[3]);
            ac[4] = fmaf(w1, bflo(p1.z), ac[4]); ac[5] = fmaf(w1, bfhi(p1.z), ac[5]);
            ac[6] = fmaf(w1, bflo(p1.w), ac[6]); ac[7] = fmaf(w1, bfhi(p1.w), ac[7]);
        }
    }
    for (; base < re; base += 8) {
        int i = base + q8;
        int c = (i < re) ? col[i] : n;
        float w = __expf(lrelu(as2[c] + adn));
        if (i >= re) w = 0.f;
        den += w;
        if (l8 < 5) {
            unsigned off = ((unsigned)c << 7) + (unsigned)(l8 << 4);
            uint4 pk = *(const uint4*)((const char*)h2b + off);
            ac[0] = fmaf(w, bflo(pk.x), ac[0]); ac[1] = fmaf(w, bfhi(pk.x), ac[1]);
            ac[2] = fmaf(w, bflo(pk.y), ac[2]); ac[3] = fmaf(w, bfhi(pk.y), ac[3]);
            ac[4] = fmaf(w, bflo(pk.z), ac[4]); ac[5] = fmaf(w, bfhi(pk.z), ac[5]);
            ac[6] = fmaf(w, bflo(pk.w), ac[6]); ac[7] = fmaf(w, bfhi(pk.w), ac[7]);
        }
    }
    den += __shfl_xor(den, 8);
    den += __shfl_xor(den, 16);
    den += __shfl_xor(den, 32);
#pragma unroll
    for (int k = 0; k < 8; k++) {
        ac[k] += __shfl_xor(ac[k], 8);
        ac[k] += __shfl_xor(ac[k], 16);
        ac[k] += __shfl_xor(ac[k], 32);
    }
    const float wself = __expf(lrelu(as2[n] + adn));
    den += wself;
    if (q8 == 0 && l8 < 5) {
        unsigned offs = ((unsigned)n << 7) + (unsigned)(l8 << 4);
        uint4 sp = *(const uint4*)((const char*)h2b + offs);
        float sv[8] = {bflo(sp.x), bfhi(sp.x), bflo(sp.y), bfhi(sp.y),
                       bflo(sp.z), bfhi(sp.z), bflo(sp.w), bfhi(sp.w)};
        float4 bv0 = *(const float4*)(b2 + l8 * 8);
        float4 bv1 = *(const float4*)(b2 + l8 * 8 + 4);
        float bb[8] = {bv0.x, bv0.y, bv0.z, bv0.w, bv1.x, bv1.y, bv1.z, bv1.w};
        float o[8];
#pragma unroll
        for (int k = 0; k < 8; k++)
            o[k] = (ac[k] + wself * sv[k]) / den + bb[k];
        *(float4*)(out + (size_t)n * CLS + l8 * 8) =
            make_float4(o[0], o[1], o[2], o[3]);
        *(float4*)(out + (size_t)n * CLS + l8 * 8 + 4) =
            make_float4(o[4], o[5], o[6], o[7]);
    }
}

extern "C" void kernel_launch(void* const* d_in, const int* in_sizes, int n_in,
                              void* d_out, int out_size, void* d_ws, size_t ws_size,
                              hipStream_t stream) {
    const float* x     = (const float*)d_in[0];
    const int*   ei    = (const int*)d_in[1];
    const float* W1    = (const float*)d_in[2];
    const float* aS1   = (const float*)d_in[3];
    const float* aD1   = (const float*)d_in[4];
    const float* b1    = (const float*)d_in[5];
    const float* W2    = (const float*)d_in[6];
    const float* aS2   = (const float*)d_in[7];
    const float* aD2   = (const float*)d_in[8];
    const float* b2    = (const float*)d_in[9];
    float* out = (float*)d_out;
    const int E = in_sizes[1] / 2;
    const int* src = ei;
    const int* dst = ei + E;

    char* ws = (char*)d_ws;
    size_t off = 0;
    auto alloc = [&](size_t bytes) -> char* {
        char* p = ws + off;
        off += (bytes + 255) & ~(size_t)255;
        return p;
    };
    unsigned short* h1b = (unsigned short*)alloc((size_t)NODES * C1 * 2);
    float* out1   = (float*)alloc((size_t)NODES * C1 * 4);
    unsigned short* h2b = (unsigned short*)alloc((size_t)NODES * 64 * 2);
    float* as1    = (float*)alloc((size_t)NODES * HEADS * 4);
    float* ad1    = (float*)alloc((size_t)NODES * HEADS * 4);
    float* as2    = (float*)alloc((size_t)NODES * 4);
    float* ad2    = (float*)alloc((size_t)NODES * 4);
    int* rowptr   = (int*)alloc((size_t)(NODES + 1) * 4);
    int* col      = (int*)alloc((size_t)E * 4);
    int* tmp      = (int*)alloc((size_t)E * 4);
    int* bcnt     = (int*)alloc((size_t)NBUCK * 4);
    int* bbase    = (int*)alloc((size_t)(NBUCK + 1) * 4);
    int* bwp      = (int*)alloc((size_t)NBUCK * 4);

    k_zero<<<1, 256, 0, stream>>>(bcnt, NBUCK);
    k_gemm1<<<(NODES + 63) / 64, 256, 0, stream>>>(x, W1, aS1, aD1, h1b, as1, ad1);
    k_bhist<<<(E + EPB - 1) / EPB, 256, 0, stream>>>(dst, E, bcnt);
    k_bscan<<<1, 256, 0, stream>>>(bcnt, bbase, bwp);
    k_bucketA<<<(E + EPB - 1) / EPB, 256, 0, stream>>>(src, dst, E, bwp, tmp);
    k_bucketB<<<NBUCK, 256, 0, stream>>>(bbase, tmp, col, rowptr, E);
    k_agg1<<<(NODES * 64) / 256, 256, 0, stream>>>(h1b, as1, ad1, rowptr, col, b1, out1);
    k_gemm2<<<(NODES + 63) / 64, 320, 0, stream>>>(out1, W2, aS2, aD2, h2b, as2, ad2);
    k_agg2<<<(NODES * 64) / 256, 256, 0, stream>>>(h2b, as2, ad2, rowptr, col, b2, out);
}

// Round 11
// 237.558 us; speedup vs baseline: 2.5557x; 1.0110x over previous
//
#include <hip/hip_runtime.h>
#include <cstdint>

#define NODES 50000
#define FIN   128
#define C1    128   // HEADS*HID
#define HEADS 4
#define HID   32
#define CLS   40
#define SLOPE 0.2f

#define NBUCK ((NODES + 255) >> 8)   // 196
#define EPB 2048                     // edges per bucketA/bhist block

__device__ __forceinline__ float lrelu(float v) { return v > 0.f ? v : SLOPE * v; }

__device__ __forceinline__ unsigned short f2bf(float f) {
    union { float f; unsigned u; } v; v.f = f;
    unsigned u = v.u;
    return (unsigned short)((u + 0x7FFFu + ((u >> 16) & 1u)) >> 16);
}
__device__ __forceinline__ float bf2f(unsigned short b) {
    union { unsigned u; float f; } v; v.u = ((unsigned)b) << 16;
    return v.f;
}
__device__ __forceinline__ float bflo(unsigned u) {
    union { unsigned x; float f; } v; v.x = u << 16; return v.f;
}
__device__ __forceinline__ float bfhi(unsigned u) {
    union { unsigned x; float f; } v; v.x = u & 0xffff0000u; return v.f;
}

typedef __attribute__((ext_vector_type(8))) short bf16x8;
typedef __attribute__((ext_vector_type(4))) float f32x4;
// 4-byte-aligned vector int types for unaligned CSR segment loads
typedef __attribute__((ext_vector_type(4), aligned(4))) int int4a;
typedef __attribute__((ext_vector_type(2), aligned(4))) int int2a;

// ---- GEMM1 (MFMA bf16): h1b[N,128](bf16) = x @ W1 ; as1/ad1 fused ----
// block = 256 = 4 waves, 64 rows. Wt[n][k] bf16 in LDS (transposed W1).
// A frag: lane l -> A[m=l&15][k=quad*8+j]; B frag: B[k=quad*8+j][n=l&15];
// D: lane l reg r -> D[row=quad*4+r][col=l&15].  C bounced via LDS.
// Block 0 also zeroes bcnt for the downstream CSR build (no race: k_bhist
// launches after this kernel fully retires).
__global__ __launch_bounds__(256) void k_gemm1(const float* __restrict__ X,
                                               const float* __restrict__ W,
                                               const float* __restrict__ AS,
                                               const float* __restrict__ AD,
                                               unsigned short* __restrict__ h1b,
                                               float* __restrict__ as1,
                                               float* __restrict__ ad1,
                                               int* __restrict__ bcnt) {
    __shared__ unsigned short Asm[64][136];   // also reused as C output
    __shared__ unsigned short Wt[128][136];   // Wt[n][k]
    const int t = threadIdx.x;
    const int row0 = blockIdx.x * 64;
    if (blockIdx.x == 0 && t < NBUCK) bcnt[t] = 0;

    // stage Wt: W[k][n] fp32 -> Wt[n][k] bf16, 2 k's per write (b32)
    for (int i = 0; i < 32; i++) {
        int p = i * 256 + t;            // pair index: kp = p>>7, n = p&127
        int kp = p >> 7, n = p & 127;
        float v0 = W[(size_t)(2 * kp) * C1 + n];
        float v1 = W[(size_t)(2 * kp + 1) * C1 + n];
        *(unsigned*)(&Wt[n][2 * kp]) =
            (unsigned)f2bf(v0) | ((unsigned)f2bf(v1) << 16);
    }
    // stage Asm: 64 rows of X as bf16
    {
        int r = t >> 2, c0 = (t & 3) * 32;
        int gr = row0 + r;
        unsigned short tb[32];
        if (gr < NODES) {
#pragma unroll
            for (int i = 0; i < 8; i++) {
                float4 v = *(const float4*)(X + (size_t)gr * FIN + c0 + i * 4);
                tb[i * 4 + 0] = f2bf(v.x); tb[i * 4 + 1] = f2bf(v.y);
                tb[i * 4 + 2] = f2bf(v.z); tb[i * 4 + 3] = f2bf(v.w);
            }
        } else {
#pragma unroll
            for (int i = 0; i < 32; i++) tb[i] = 0;
        }
#pragma unroll
        for (int i = 0; i < 4; i++) {
            uint4 pk;
            pk.x = (unsigned)tb[i*8+0] | ((unsigned)tb[i*8+1] << 16);
            pk.y = (unsigned)tb[i*8+2] | ((unsigned)tb[i*8+3] << 16);
            pk.z = (unsigned)tb[i*8+4] | ((unsigned)tb[i*8+5] << 16);
            pk.w = (unsigned)tb[i*8+6] | ((unsigned)tb[i*8+7] << 16);
            *(uint4*)(&Asm[r][c0 + i * 8]) = pk;
        }
    }
    __syncthreads();

    const int w = t >> 6, l = t & 63;
    const int lm = l & 15, quad = l >> 4;
    f32x4 acc[8];
#pragma unroll
    for (int ct = 0; ct < 8; ct++) acc[ct] = (f32x4){0.f, 0.f, 0.f, 0.f};
#pragma unroll
    for (int kt = 0; kt < 4; kt++) {
        bf16x8 a = *(const bf16x8*)(&Asm[w * 16 + lm][kt * 32 + quad * 8]);
#pragma unroll
        for (int ct = 0; ct < 8; ct++) {
            bf16x8 b = *(const bf16x8*)(&Wt[ct * 16 + lm][kt * 32 + quad * 8]);
            acc[ct] = __builtin_amdgcn_mfma_f32_16x16x32_bf16(a, b, acc[ct], 0, 0, 0);
        }
    }
    __syncthreads();
    // scatter C (bf16) into Asm
#pragma unroll
    for (int ct = 0; ct < 8; ct++)
#pragma unroll
        for (int r = 0; r < 4; r++)
            Asm[w * 16 + quad * 4 + r][ct * 16 + lm] = f2bf(acc[ct][r]);
    __syncthreads();
    // coalesced h1b write
    {
        int r = t >> 2, c0 = (t & 3) * 32;
        int gr = row0 + r;
        if (gr < NODES) {
#pragma unroll
            for (int i = 0; i < 4; i++)
                *(uint4*)(h1b + (size_t)gr * C1 + c0 + i * 8) =
                    *(uint4*)(&Asm[r][c0 + i * 8]);
        }
    }
    // attention dots from LDS C: thread -> (row, head)
    {
        int r = t >> 2, h = t & 3;
        int gr = row0 + r;
        if (gr < NODES) {
            float s = 0.f, d = 0.f;
#pragma unroll
            for (int j = 0; j < 32; j++) {
                float v = bf2f(Asm[r][h * 32 + j]);
                s = fmaf(v, AS[h * HID + j], s);
                d = fmaf(v, AD[h * HID + j], d);
            }
            as1[gr * HEADS + h] = s;
            ad1[gr * HEADS + h] = d;
        }
    }
}

// ---------------- bucket histogram: bcnt[b] = #edges with dst>>8 == b ----------------
__global__ __launch_bounds__(256) void k_bhist(const int* __restrict__ dst, int E,
                                               int* __restrict__ bcnt) {
    __shared__ int cnt[NBUCK];
    const int t = threadIdx.x;
    for (int i = t; i < NBUCK; i += 256) cnt[i] = 0;
    __syncthreads();
    const int e0 = blockIdx.x * EPB;
#pragma unroll
    for (int k = 0; k < 8; k++) {
        int e = e0 + k * 256 + t;
        if (e < E) atomicAdd(&cnt[dst[e] >> 8], 1);
    }
    __syncthreads();
    for (int i = t; i < NBUCK; i += 256) {
        int c = cnt[i];
        if (c) atomicAdd(&bcnt[i], c);
    }
}

// ---------------- one-block scan of bucket counts -> bbase, bwp ----------------
__global__ __launch_bounds__(256) void k_bscan(const int* __restrict__ bcnt,
                                               int* __restrict__ bbase,
                                               int* __restrict__ bwp) {
    __shared__ int ws[4];
    const int t = threadIdx.x;
    const int lane = t & 63, w = t >> 6;
    int v = (t < NBUCK) ? bcnt[t] : 0;
    int incl = v;
#pragma unroll
    for (int s = 1; s < 64; s <<= 1) {
        int u = __shfl_up(incl, s);
        if (lane >= s) incl += u;
    }
    if (lane == 63) ws[w] = incl;
    __syncthreads();
    if (t == 0) {
        int r = 0;
#pragma unroll
        for (int i = 0; i < 4; i++) { int x = ws[i]; ws[i] = r; r += x; }
    }
    __syncthreads();
    int excl = incl - v + ws[w];
    if (t < NBUCK) { bbase[t] = excl; bwp[t] = excl; }
    if (t == NBUCK) bbase[NBUCK] = excl;   // total E
}

// ---------------- pass A: bucket edges by dst>>8 into staging ----------------
__global__ __launch_bounds__(256) void k_bucketA(const int* __restrict__ src,
                                                 const int* __restrict__ dst, int E,
                                                 int* __restrict__ bwp,
                                                 int* __restrict__ tmp) {
    __shared__ int cnt[NBUCK];
    __shared__ int bbs[NBUCK];
    const int t = threadIdx.x;
    for (int i = t; i < NBUCK; i += 256) cnt[i] = 0;
    __syncthreads();
    const int e0 = blockIdx.x * EPB;
    int v[8], rb[8];
#pragma unroll
    for (int k = 0; k < 8; k++) {
        int e = e0 + k * 256 + t;
        rb[k] = -1;
        if (e < E) {
            int d = dst[e], s = src[e];
            int b = d >> 8;
            int r = atomicAdd(&cnt[b], 1);
            v[k] = (s << 8) | (d & 255);
            rb[k] = (r << 8) | b;
        }
    }
    __syncthreads();
    for (int i = t; i < NBUCK; i += 256) {
        int c = cnt[i];
        bbs[i] = c ? atomicAdd(&bwp[i], c) : 0;
    }
    __syncthreads();
#pragma unroll
    for (int k = 0; k < 8; k++) {
        if (rb[k] >= 0) {
            int b = rb[k] & 255;
            int r = rb[k] >> 8;
            tmp[bbs[b] + r] = v[k];
        }
    }
}

// ---------------- pass B: per-bucket degree+scan+rowptr, scatter col ----------------
__global__ __launch_bounds__(256) void k_bucketB(const int* __restrict__ bbase,
                                                 const int* __restrict__ tmp,
                                                 int* __restrict__ col,
                                                 int* __restrict__ rowptr, int E) {
    __shared__ int degs[256];
    __shared__ int wp[256];
    __shared__ int wsum[4];
    const int b = blockIdx.x, t = threadIdx.x;
    const int n0 = b << 8;
    const int beg = bbase[b], end = bbase[b + 1];
    degs[t] = 0;
    __syncthreads();
    for (int e = beg + t; e < end; e += 256)
        atomicAdd(&degs[tmp[e] & 255], 1);
    __syncthreads();
    const int d = degs[t];
    int incl = d;
    const int lane = t & 63, w = t >> 6;
#pragma unroll
    for (int s = 1; s < 64; s <<= 1) {
        int u = __shfl_up(incl, s);
        if (lane >= s) incl += u;
    }
    if (lane == 63) wsum[w] = incl;
    __syncthreads();
    if (t == 0) {
        int r = 0;
#pragma unroll
        for (int i = 0; i < 4; i++) { int x = wsum[i]; wsum[i] = r; r += x; }
    }
    __syncthreads();
    const int excl = incl - d + wsum[w] + beg;
    const int nidx = n0 + t;
    if (nidx < NODES) rowptr[nidx] = excl;
    wp[t] = excl;
    if (b == 0 && t == 0) rowptr[NODES] = E;
    __syncthreads();
    for (int e = beg + t; e < end; e += 256) {
        int v = tmp[e];
        int p = atomicAdd(&wp[v & 255], 1);
        col[p] = v >> 8;
    }
}

// ---------------- layer-1 aggregation: one wave per dst node ----------------
// lane = q*16 + ll: q = edge slot, ll = channel group (8 ch), fh = head.
// Main loop: 16 edges/iter — slot q owns edges base+q*4..+3 via ONE 16B col
// load, giving 4 independent gather chains per lane (MLP). Inline weights
// (redundant across ll-groups — free, issue is per-wave). Guarded 4-edge tail.
__global__ __launch_bounds__(256) void k_agg1(const unsigned short* __restrict__ h1b,
                                              const float* __restrict__ as1,
                                              const float* __restrict__ ad1,
                                              const int* __restrict__ rowptr,
                                              const int* __restrict__ col,
                                              const float* __restrict__ b1,
                                              float* __restrict__ out1) {
    int wid = (blockIdx.x * 256 + threadIdx.x) >> 6;
    if (wid >= NODES) return;
    const int lane = threadIdx.x & 63;
    const int q  = lane >> 4;       // edge slot
    const int ll = lane & 15;       // channel group
    const int fh = ll >> 2;         // head
    const int n = wid;
    const float adn = ad1[n * HEADS + fh];
    const int rs = rowptr[n], re = rowptr[n + 1];

    float den = 0.f;
    float ac[8];
#pragma unroll
    for (int k = 0; k < 8; k++) ac[k] = 0.f;

    int base = rs;
    for (; base + 16 <= re; base += 16) {
        int4a cc = *(const int4a*)(col + base + q * 4);
        float w0 = __expf(lrelu(as1[cc.x * HEADS + fh] + adn));
        float w1 = __expf(lrelu(as1[cc.y * HEADS + fh] + adn));
        float w2 = __expf(lrelu(as1[cc.z * HEADS + fh] + adn));
        float w3 = __expf(lrelu(as1[cc.w * HEADS + fh] + adn));
        den += (w0 + w1) + (w2 + w3);
        uint4 p0 = *(const uint4*)((const char*)h1b + (((unsigned)cc.x << 8) + (unsigned)(ll << 4)));
        uint4 p1 = *(const uint4*)((const char*)h1b + (((unsigned)cc.y << 8) + (unsigned)(ll << 4)));
        uint4 p2 = *(const uint4*)((const char*)h1b + (((unsigned)cc.z << 8) + (unsigned)(ll << 4)));
        uint4 p3 = *(const uint4*)((const char*)h1b + (((unsigned)cc.w << 8) + (unsigned)(ll << 4)));
        ac[0] = fmaf(w0, bflo(p0.x), ac[0]); ac[1] = fmaf(w0, bfhi(p0.x), ac[1]);
        ac[2] = fmaf(w0, bflo(p0.y), ac[2]); ac[3] = fmaf(w0, bfhi(p0.y), ac[3]);
        ac[4] = fmaf(w0, bflo(p0.z), ac[4]); ac[5] = fmaf(w0, bfhi(p0.z), ac[5]);
        ac[6] = fmaf(w0, bflo(p0.w), ac[6]); ac[7] = fmaf(w0, bfhi(p0.w), ac[7]);
        ac[0] = fmaf(w1, bflo(p1.x), ac[0]); ac[1] = fmaf(w1, bfhi(p1.x), ac[1]);
        ac[2] = fmaf(w1, bflo(p1.y), ac[2]); ac[3] = fmaf(w1, bfhi(p1.y), ac[3]);
        ac[4] = fmaf(w1, bflo(p1.z), ac[4]); ac[5] = fmaf(w1, bfhi(p1.z), ac[5]);
        ac[6] = fmaf(w1, bflo(p1.w), ac[6]); ac[7] = fmaf(w1, bfhi(p1.w), ac[7]);
        ac[0] = fmaf(w2, bflo(p2.x), ac[0]); ac[1] = fmaf(w2, bfhi(p2.x), ac[1]);
        ac[2] = fmaf(w2, bflo(p2.y), ac[2]); ac[3] = fmaf(w2, bfhi(p2.y), ac[3]);
        ac[4] = fmaf(w2, bflo(p2.z), ac[4]); ac[5] = fmaf(w2, bfhi(p2.z), ac[5]);
        ac[6] = fmaf(w2, bflo(p2.w), ac[6]); ac[7] = fmaf(w2, bfhi(p2.w), ac[7]);
        ac[0] = fmaf(w3, bflo(p3.x), ac[0]); ac[1] = fmaf(w3, bfhi(p3.x), ac[1]);
        ac[2] = fmaf(w3, bflo(p3.y), ac[2]); ac[3] = fmaf(w3, bfhi(p3.y), ac[3]);
        ac[4] = fmaf(w3, bflo(p3.z), ac[4]); ac[5] = fmaf(w3, bfhi(p3.z), ac[5]);
        ac[6] = fmaf(w3, bflo(p3.w), ac[6]); ac[7] = fmaf(w3, bfhi(p3.w), ac[7]);
    }
    for (; base < re; base += 4) {
        int i = base + q;
        int c = (i < re) ? col[i] : n;
        float w = __expf(lrelu(as1[c * HEADS + fh] + adn));
        if (i >= re) w = 0.f;
        den += w;
        unsigned off = ((unsigned)c << 8) + (unsigned)(ll << 4);
        uint4 pk = *(const uint4*)((const char*)h1b + off);
        ac[0] = fmaf(w, bflo(pk.x), ac[0]); ac[1] = fmaf(w, bfhi(pk.x), ac[1]);
        ac[2] = fmaf(w, bflo(pk.y), ac[2]); ac[3] = fmaf(w, bfhi(pk.y), ac[3]);
        ac[4] = fmaf(w, bflo(pk.z), ac[4]); ac[5] = fmaf(w, bfhi(pk.z), ac[5]);
        ac[6] = fmaf(w, bflo(pk.w), ac[6]); ac[7] = fmaf(w, bfhi(pk.w), ac[7]);
    }
    // reduce across edge slots q (lane bits 4,5); stays within the same head
    den += __shfl_xor(den, 16);
    den += __shfl_xor(den, 32);
#pragma unroll
    for (int k = 0; k < 8; k++) {
        ac[k] += __shfl_xor(ac[k], 16);
        ac[k] += __shfl_xor(ac[k], 32);
    }
    const float wself = __expf(lrelu(as1[n * HEADS + fh] + adn));
    den += wself;
    if (q == 0) {
        unsigned offs = ((unsigned)n << 8) + (unsigned)(ll << 4);
        uint4 sp = *(const uint4*)((const char*)h1b + offs);
        float sv[8] = {bflo(sp.x), bfhi(sp.x), bflo(sp.y), bfhi(sp.y),
                       bflo(sp.z), bfhi(sp.z), bflo(sp.w), bfhi(sp.w)};
        float4 bv0 = *(const float4*)(b1 + ll * 8);
        float4 bv1 = *(const float4*)(b1 + ll * 8 + 4);
        float bb[8] = {bv0.x, bv0.y, bv0.z, bv0.w, bv1.x, bv1.y, bv1.z, bv1.w};
        float o[8];
#pragma unroll
        for (int k = 0; k < 8; k++)
            o[k] = fmaxf((ac[k] + wself * sv[k]) / den + bb[k], 0.f);
        *(float4*)(out1 + (size_t)n * C1 + ll * 8) =
            make_float4(o[0], o[1], o[2], o[3]);
        *(float4*)(out1 + (size_t)n * C1 + ll * 8 + 4) =
            make_float4(o[4], o[5], o[6], o[7]);
    }
}

// ---- GEMM2 (+fused att2): h2b[N,64](bf16) = out1 @ W2 ; as2/ad2 from fp32 acc ----
__global__ __launch_bounds__(320) void k_gemm2(const float* __restrict__ A,
                                               const float* __restrict__ W,
                                               const float* __restrict__ AS,
                                               const float* __restrict__ AD,
                                               unsigned short* __restrict__ h2b,
                                               float* __restrict__ as2,
                                               float* __restrict__ ad2) {
    __shared__ float xs[64][132];
    __shared__ float ws2[128 * 40];
    __shared__ float sS[320];
    __shared__ float sD[320];
    const int tid = threadIdx.x;
    const int row0 = blockIdx.x * 64;
    for (int q = tid; q < 1280; q += 320)
        *(float4*)(ws2 + q * 4) = *(const float4*)(W + q * 4);
    for (int q = tid; q < 2048; q += 320) {
        int r = q >> 5, kq = (q & 31) * 4;
        int gr = row0 + r;
        float4 v = make_float4(0.f, 0.f, 0.f, 0.f);
        if (gr < NODES) v = *(const float4*)(A + (size_t)gr * FIN + kq);
        *(float4*)(&xs[r][kq]) = v;
    }
    __syncthreads();
    const int r = tid / 5;
    const int c0 = (tid % 5) * 8;
    float acc[8];
#pragma unroll
    for (int j = 0; j < 8; j++) acc[j] = 0.f;
    for (int k = 0; k < 128; k++) {
        float a = xs[r][k];
        float4 b0 = *(float4*)(ws2 + k * CLS + c0);
        float4 b1 = *(float4*)(ws2 + k * CLS + c0 + 4);
        acc[0] = fmaf(a, b0.x, acc[0]); acc[1] = fmaf(a, b0.y, acc[1]);
        acc[2] = fmaf(a, b0.z, acc[2]); acc[3] = fmaf(a, b0.w, acc[3]);
        acc[4] = fmaf(a, b1.x, acc[4]); acc[5] = fmaf(a, b1.y, acc[5]);
        acc[6] = fmaf(a, b1.z, acc[6]); acc[7] = fmaf(a, b1.w, acc[7]);
    }
    // partial attention dots (fp32-exact)
    {
        float s = 0.f, d = 0.f;
#pragma unroll
        for (int j = 0; j < 8; j++) {
            s = fmaf(acc[j], AS[c0 + j], s);
            d = fmaf(acc[j], AD[c0 + j], d);
        }
        sS[tid] = s; sD[tid] = d;
    }
    int gr = row0 + r;
    if (gr < NODES) {
        unsigned short tb[8];
#pragma unroll
        for (int j = 0; j < 8; j++) tb[j] = f2bf(acc[j]);
        uint4 pk;
        pk.x = (unsigned)tb[0] | ((unsigned)tb[1] << 16);
        pk.y = (unsigned)tb[2] | ((unsigned)tb[3] << 16);
        pk.z = (unsigned)tb[4] | ((unsigned)tb[5] << 16);
        pk.w = (unsigned)tb[6] | ((unsigned)tb[7] << 16);
        *(uint4*)(h2b + (size_t)gr * 64 + c0) = pk;
    }
    __syncthreads();
    if (tid < 64) {
        int grr = row0 + tid;
        if (grr < NODES) {
            int b5 = tid * 5;
            as2[grr] = sS[b5] + sS[b5+1] + sS[b5+2] + sS[b5+3] + sS[b5+4];
            ad2[grr] = sD[b5] + sD[b5+1] + sD[b5+2] + sD[b5+3] + sD[b5+4];
        }
    }
}

// ---------------- layer-2 aggregation: one wave per dst node ----------------
// lane = q8*8 + l8: 8 edge slots, l8<5 own channels. Slot q8 owns edges
// base+q8*2, +1 via one 8B col load (2 independent chains). 16 edges/iter.
__global__ __launch_bounds__(256) void k_agg2(const unsigned short* __restrict__ h2b,
                                              const float* __restrict__ as2,
                                              const float* __restrict__ ad2,
                                              const int* __restrict__ rowptr,
                                              const int* __restrict__ col,
                                              const float* __restrict__ b2,
                                              float* __restrict__ out) {
    int wid = (blockIdx.x * 256 + threadIdx.x) >> 6;
    if (wid >= NODES) return;
    const int lane = threadIdx.x & 63;
    const int q8 = lane >> 3, l8 = lane & 7;
    const int n = wid;
    const float adn = ad2[n];
    const int rs = rowptr[n], re = rowptr[n + 1];

    float den = 0.f;
    float ac[8];
#pragma unroll
    for (int k = 0; k < 8; k++) ac[k] = 0.f;

    int base = rs;
    for (; base + 16 <= re; base += 16) {
        int2a cc = *(const int2a*)(col + base + q8 * 2);
        float w0 = __expf(lrelu(as2[cc.x] + adn));
        float w1 = __expf(lrelu(as2[cc.y] + adn));
        den += w0 + w1;
        if (l8 < 5) {
            unsigned o0 = ((unsigned)cc.x << 7) + (unsigned)(l8 << 4);
            unsigned o1 = ((unsigned)cc.y << 7) + (unsigned)(l8 << 4);
            uint4 p0 = *(const uint4*)((const char*)h2b + o0);
            uint4 p1 = *(const uint4*)((const char*)h2b + o1);
            ac[0] = fmaf(w0, bflo(p0.x), ac[0]); ac[1] = fmaf(w0, bfhi(p0.x), ac[1]);
            ac[2] = fmaf(w0, bflo(p0.y), ac[2]); ac[3] = fmaf(w0, bfhi(p0.y), ac[3]);
            ac[4] = fmaf(w0, bflo(p0.z), ac[4]); ac[5] = fmaf(w0, bfhi(p0.z), ac[5]);
            ac[6] = fmaf(w0, bflo(p0.w), ac[6]); ac[7] = fmaf(w0, bfhi(p0.w), ac[7]);
            ac[0] = fmaf(w1, bflo(p1.x), ac[0]); ac[1] = fmaf(w1, bfhi(p1.x), ac[1]);
            ac[2] = fmaf(w1, bflo(p1.y), ac[2]); ac[3] = fmaf(w1, bfhi(p1.y), ac[3]);
            ac[4] = fmaf(w1, bflo(p1.z), ac[4]); ac[5] = fmaf(w1, bfhi(p1.z), ac[5]);
            ac[6] = fmaf(w1, bflo(p1.w), ac[6]); ac[7] = fmaf(w1, bfhi(p1.w), ac[7]);
        }
    }
    for (; base < re; base += 8) {
        int i = base + q8;
        int c = (i < re) ? col[i] : n;
        float w = __expf(lrelu(as2[c] + adn));
        if (i >= re) w = 0.f;
        den += w;
        if (l8 < 5) {
            unsigned off = ((unsigned)c << 7) + (unsigned)(l8 << 4);
            uint4 pk = *(const uint4*)((const char*)h2b + off);
            ac[0] = fmaf(w, bflo(pk.x), ac[0]); ac[1] = fmaf(w, bfhi(pk.x), ac[1]);
            ac[2] = fmaf(w, bflo(pk.y), ac[2]); ac[3] = fmaf(w, bfhi(pk.y), ac[3]);
            ac[4] = fmaf(w, bflo(pk.z), ac[4]); ac[5] = fmaf(w, bfhi(pk.z), ac[5]);
            ac[6] = fmaf(w, bflo(pk.w), ac[6]); ac[7] = fmaf(w, bfhi(pk.w), ac[7]);
        }
    }
    den += __shfl_xor(den, 8);
    den += __shfl_xor(den, 16);
    den += __shfl_xor(den, 32);
#pragma unroll
    for (int k = 0; k < 8; k++) {
        ac[k] += __shfl_xor(ac[k], 8);
        ac[k] += __shfl_xor(ac[k], 16);
        ac[k] += __shfl_xor(ac[k], 32);
    }
    const float wself = __expf(lrelu(as2[n] + adn));
    den += wself;
    if (q8 == 0 && l8 < 5) {
        unsigned offs = ((unsigned)n << 7) + (unsigned)(l8 << 4);
        uint4 sp = *(const uint4*)((const char*)h2b + offs);
        float sv[8] = {bflo(sp.x), bfhi(sp.x), bflo(sp.y), bfhi(sp.y),
                       bflo(sp.z), bfhi(sp.z), bflo(sp.w), bfhi(sp.w)};
        float4 bv0 = *(const float4*)(b2 + l8 * 8);
        float4 bv1 = *(const float4*)(b2 + l8 * 8 + 4);
        float bb[8] = {bv0.x, bv0.y, bv0.z, bv0.w, bv1.x, bv1.y, bv1.z, bv1.w};
        float o[8];
#pragma unroll
        for (int k = 0; k < 8; k++)
            o[k] = (ac[k] + wself * sv[k]) / den + bb[k];
        *(float4*)(out + (size_t)n * CLS + l8 * 8) =
            make_float4(o[0], o[1], o[2], o[3]);
        *(float4*)(out + (size_t)n * CLS + l8 * 8 + 4) =
            make_float4(o[4], o[5], o[6], o[7]);
    }
}

extern "C" void kernel_launch(void* const* d_in, const int* in_sizes, int n_in,
                              void* d_out, int out_size, void* d_ws, size_t ws_size,
                              hipStream_t stream) {
    const float* x     = (const float*)d_in[0];
    const int*   ei    = (const int*)d_in[1];
    const float* W1    = (const float*)d_in[2];
    const float* aS1   = (const float*)d_in[3];
    const float* aD1   = (const float*)d_in[4];
    const float* b1    = (const float*)d_in[5];
    const float* W2    = (const float*)d_in[6];
    const float* aS2   = (const float*)d_in[7];
    const float* aD2   = (const float*)d_in[8];
    const float* b2    = (const float*)d_in[9];
    float* out = (float*)d_out;
    const int E = in_sizes[1] / 2;
    const int* src = ei;
    const int* dst = ei + E;

    char* ws = (char*)d_ws;
    size_t off = 0;
    auto alloc = [&](size_t bytes) -> char* {
        char* p = ws + off;
        off += (bytes + 255) & ~(size_t)255;
        return p;
    };
    unsigned short* h1b = (unsigned short*)alloc((size_t)NODES * C1 * 2);
    float* out1   = (float*)alloc((size_t)NODES * C1 * 4);
    unsigned short* h2b = (unsigned short*)alloc((size_t)NODES * 64 * 2);
    float* as1    = (float*)alloc((size_t)NODES * HEADS * 4);
    float* ad1    = (float*)alloc((size_t)NODES * HEADS * 4);
    float* as2    = (float*)alloc((size_t)NODES * 4);
    float* ad2    = (float*)alloc((size_t)NODES * 4);
    int* rowptr   = (int*)alloc((size_t)(NODES + 1) * 4);
    int* col      = (int*)alloc((size_t)E * 4);
    int* tmp      = (int*)alloc((size_t)E * 4);
    int* bcnt     = (int*)alloc((size_t)NBUCK * 4);
    int* bbase    = (int*)alloc((size_t)(NBUCK + 1) * 4);
    int* bwp      = (int*)alloc((size_t)NBUCK * 4);

    k_gemm1<<<(NODES + 63) / 64, 256, 0, stream>>>(x, W1, aS1, aD1, h1b, as1, ad1, bcnt);
    k_bhist<<<(E + EPB - 1) / EPB, 256, 0, stream>>>(dst, E, bcnt);
    k_bscan<<<1, 256, 0, stream>>>(bcnt, bbase, bwp);
    k_bucketA<<<(E + EPB - 1) / EPB, 256, 0, stream>>>(src, dst, E, bwp, tmp);
    k_bucketB<<<NBUCK, 256, 0, stream>>>(bbase, tmp, col, rowptr, E);
    k_agg1<<<(NODES * 64) / 256, 256, 0, stream>>>(h1b, as1, ad1, rowptr, col, b1, out1);
    k_gemm2<<<(NODES + 63) / 64, 320, 0, stream>>>(out1, W2, aS2, aD2, h2b, as2, ad2);
    k_agg2<<<(NODES * 64) / 256, 256, 0, stream>>>(h2b, as2, ad2, rowptr, col, b2, out);
}

// Round 12
// 232.462 us; speedup vs baseline: 2.6117x; 1.0219x over previous
//
#include <hip/hip_runtime.h>
#include <cstdint>

#define NODES 50000
#define FIN   128
#define C1    128   // HEADS*HID
#define HEADS 4
#define HID   32
#define CLS   40
#define SLOPE 0.2f

#define NBUCK ((NODES + 255) >> 8)   // 196
#define EPB 2048                     // edges per bucketA block
#define BCAP 8192                    // fixed bucket capacity (max actual ~4.3k)

__device__ __forceinline__ float lrelu(float v) { return v > 0.f ? v : SLOPE * v; }

__device__ __forceinline__ unsigned short f2bf(float f) {
    union { float f; unsigned u; } v; v.f = f;
    unsigned u = v.u;
    return (unsigned short)((u + 0x7FFFu + ((u >> 16) & 1u)) >> 16);
}
__device__ __forceinline__ float bf2f(unsigned short b) {
    union { unsigned u; float f; } v; v.u = ((unsigned)b) << 16;
    return v.f;
}
__device__ __forceinline__ float bflo(unsigned u) {
    union { unsigned x; float f; } v; v.x = u << 16; return v.f;
}
__device__ __forceinline__ float bfhi(unsigned u) {
    union { unsigned x; float f; } v; v.x = u & 0xffff0000u; return v.f;
}

typedef __attribute__((ext_vector_type(8))) short bf16x8;
typedef __attribute__((ext_vector_type(4))) float f32x4;
typedef __attribute__((ext_vector_type(4), aligned(4))) int int4a;
typedef __attribute__((ext_vector_type(2), aligned(4))) int int2a;

// ---- prep: W1 -> bf16 transposed (w1t[n][k]) + bucket write-ptr init ----
__global__ __launch_bounds__(256) void k_prep(const float* __restrict__ W,
                                              unsigned short* __restrict__ w1t,
                                              int* __restrict__ bwp) {
    const int t = threadIdx.x;
#pragma unroll
    for (int i = 0; i < 64; i++) {
        int p = i * 256 + t;
        int n = p >> 7, k = p & 127;
        w1t[n * 128 + k] = f2bf(W[(size_t)k * C1 + n]);
    }
    if (t < NBUCK) bwp[t] = t * BCAP;
}

// ---- GEMM1 (MFMA bf16): h1b[N,128](bf16) = x @ W1 ; as1/ad1 fused ----
// block = 256 = 4 waves, 64 rows. Wt[n][k] bf16 in LDS from precomputed w1t.
// A frag: lane l -> A[m=l&15][k=quad*8+j]; B frag: B[k=quad*8+j][n=l&15];
// D: lane l reg r -> D[row=quad*4+r][col=l&15].  C bounced via LDS.
__global__ __launch_bounds__(256) void k_gemm1(const float* __restrict__ X,
                                               const unsigned short* __restrict__ w1t,
                                               const float* __restrict__ AS,
                                               const float* __restrict__ AD,
                                               unsigned short* __restrict__ h1b,
                                               float* __restrict__ as1,
                                               float* __restrict__ ad1) {
    __shared__ unsigned short Asm[64][136];   // also reused as C output
    __shared__ unsigned short Wt[128][136];   // Wt[n][k]
    const int t = threadIdx.x;
    const int row0 = blockIdx.x * 64;

    // stage Wt from precomputed bf16 (coalesced uint4)
#pragma unroll
    for (int i = 0; i < 8; i++) {
        int p = i * 256 + t;              // 2048 chunks of 8 bf16
        int n = p >> 4, k8 = (p & 15) * 8;
        *(uint4*)(&Wt[n][k8]) = *(const uint4*)(w1t + n * 128 + k8);
    }
    // stage Asm: 64 rows of X as bf16
    {
        int r = t >> 2, c0 = (t & 3) * 32;
        int gr = row0 + r;
        unsigned short tb[32];
        if (gr < NODES) {
#pragma unroll
            for (int i = 0; i < 8; i++) {
                float4 v = *(const float4*)(X + (size_t)gr * FIN + c0 + i * 4);
                tb[i * 4 + 0] = f2bf(v.x); tb[i * 4 + 1] = f2bf(v.y);
                tb[i * 4 + 2] = f2bf(v.z); tb[i * 4 + 3] = f2bf(v.w);
            }
        } else {
#pragma unroll
            for (int i = 0; i < 32; i++) tb[i] = 0;
        }
#pragma unroll
        for (int i = 0; i < 4; i++) {
            uint4 pk;
            pk.x = (unsigned)tb[i*8+0] | ((unsigned)tb[i*8+1] << 16);
            pk.y = (unsigned)tb[i*8+2] | ((unsigned)tb[i*8+3] << 16);
            pk.z = (unsigned)tb[i*8+4] | ((unsigned)tb[i*8+5] << 16);
            pk.w = (unsigned)tb[i*8+6] | ((unsigned)tb[i*8+7] << 16);
            *(uint4*)(&Asm[r][c0 + i * 8]) = pk;
        }
    }
    __syncthreads();

    const int w = t >> 6, l = t & 63;
    const int lm = l & 15, quad = l >> 4;
    f32x4 acc[8];
#pragma unroll
    for (int ct = 0; ct < 8; ct++) acc[ct] = (f32x4){0.f, 0.f, 0.f, 0.f};
#pragma unroll
    for (int kt = 0; kt < 4; kt++) {
        bf16x8 a = *(const bf16x8*)(&Asm[w * 16 + lm][kt * 32 + quad * 8]);
#pragma unroll
        for (int ct = 0; ct < 8; ct++) {
            bf16x8 b = *(const bf16x8*)(&Wt[ct * 16 + lm][kt * 32 + quad * 8]);
            acc[ct] = __builtin_amdgcn_mfma_f32_16x16x32_bf16(a, b, acc[ct], 0, 0, 0);
        }
    }
    __syncthreads();
    // scatter C (bf16) into Asm
#pragma unroll
    for (int ct = 0; ct < 8; ct++)
#pragma unroll
        for (int r = 0; r < 4; r++)
            Asm[w * 16 + quad * 4 + r][ct * 16 + lm] = f2bf(acc[ct][r]);
    __syncthreads();
    // coalesced h1b write
    {
        int r = t >> 2, c0 = (t & 3) * 32;
        int gr = row0 + r;
        if (gr < NODES) {
#pragma unroll
            for (int i = 0; i < 4; i++)
                *(uint4*)(h1b + (size_t)gr * C1 + c0 + i * 8) =
                    *(uint4*)(&Asm[r][c0 + i * 8]);
        }
    }
    // attention dots from LDS C: thread -> (row, head)
    {
        int r = t >> 2, h = t & 3;
        int gr = row0 + r;
        if (gr < NODES) {
            float s = 0.f, d = 0.f;
#pragma unroll
            for (int j = 0; j < 32; j++) {
                float v = bf2f(Asm[r][h * 32 + j]);
                s = fmaf(v, AS[h * HID + j], s);
                d = fmaf(v, AD[h * HID + j], d);
            }
            as1[gr * HEADS + h] = s;
            ad1[gr * HEADS + h] = d;
        }
    }
}

// ---- pass A: bucket edges by dst>>8 into fixed-capacity segments of tmp ----
__global__ __launch_bounds__(256) void k_bucketA(const int* __restrict__ src,
                                                 const int* __restrict__ dst, int E,
                                                 int* __restrict__ bwp,
                                                 int* __restrict__ tmp) {
    __shared__ int cnt[NBUCK];
    __shared__ int bbs[NBUCK];
    const int t = threadIdx.x;
    for (int i = t; i < NBUCK; i += 256) cnt[i] = 0;
    __syncthreads();
    const int e0 = blockIdx.x * EPB;
    int v[8], rb[8];
#pragma unroll
    for (int k = 0; k < 8; k++) {
        int e = e0 + k * 256 + t;
        rb[k] = -1;
        if (e < E) {
            int d = dst[e], s = src[e];
            int b = d >> 8;
            int r = atomicAdd(&cnt[b], 1);
            v[k] = (s << 8) | (d & 255);
            rb[k] = (r << 8) | b;
        }
    }
    __syncthreads();
    for (int i = t; i < NBUCK; i += 256) {
        int c = cnt[i];
        bbs[i] = c ? atomicAdd(&bwp[i], c) : 0;
    }
    __syncthreads();
#pragma unroll
    for (int k = 0; k < 8; k++) {
        if (rb[k] >= 0) {
            int b = rb[k] & 255;
            int r = rb[k] >> 8;
            tmp[bbs[b] + r] = v[k];
        }
    }
}

// ---- pass B: per-bucket degree+scan -> rowptr/deg, scatter col ----
__global__ __launch_bounds__(256) void k_bucketB(const int* __restrict__ bwp,
                                                 const int* __restrict__ tmp,
                                                 int* __restrict__ col,
                                                 int* __restrict__ rowptr,
                                                 int* __restrict__ degarr) {
    __shared__ int degs[256];
    __shared__ int wp[256];
    __shared__ int wsum[4];
    const int b = blockIdx.x, t = threadIdx.x;
    const int n0 = b << 8;
    const int beg = b * BCAP;
    const int end = bwp[b];
    degs[t] = 0;
    __syncthreads();
    for (int e = beg + t; e < end; e += 256)
        atomicAdd(&degs[tmp[e] & 255], 1);
    __syncthreads();
    const int d = degs[t];
    int incl = d;
    const int lane = t & 63, w = t >> 6;
#pragma unroll
    for (int s = 1; s < 64; s <<= 1) {
        int u = __shfl_up(incl, s);
        if (lane >= s) incl += u;
    }
    if (lane == 63) wsum[w] = incl;
    __syncthreads();
    if (t == 0) {
        int r = 0;
#pragma unroll
        for (int i = 0; i < 4; i++) { int x = wsum[i]; wsum[i] = r; r += x; }
    }
    __syncthreads();
    const int excl = incl - d + wsum[w] + beg;
    const int nidx = n0 + t;
    if (nidx < NODES) { rowptr[nidx] = excl; degarr[nidx] = d; }
    wp[t] = excl;
    __syncthreads();
    for (int e = beg + t; e < end; e += 256) {
        int v = tmp[e];
        int p = atomicAdd(&wp[v & 255], 1);
        col[p] = v >> 8;
    }
}

// ---- layer-1 aggregation: one wave per dst node ----
// lane = q*16 + ll: q = edge slot, ll = channel group (8 ch), fh = head.
// 16 edges/iter: slot q owns edges base+q*4..+3 via one 16B col load
// (4 independent gather chains/lane). Inline weights. 4-edge guarded tail.
__global__ __launch_bounds__(256) void k_agg1(const unsigned short* __restrict__ h1b,
                                              const float* __restrict__ as1,
                                              const float* __restrict__ ad1,
                                              const int* __restrict__ rowptr,
                                              const int* __restrict__ degarr,
                                              const int* __restrict__ col,
                                              const float* __restrict__ b1,
                                              float* __restrict__ out1) {
    int wid = (blockIdx.x * 256 + threadIdx.x) >> 6;
    if (wid >= NODES) return;
    const int lane = threadIdx.x & 63;
    const int q  = lane >> 4;       // edge slot
    const int ll = lane & 15;       // channel group
    const int fh = ll >> 2;         // head
    const int n = wid;
    const float adn = ad1[n * HEADS + fh];
    const int rs = rowptr[n];
    const int re = rs + degarr[n];

    float den = 0.f;
    float ac[8];
#pragma unroll
    for (int k = 0; k < 8; k++) ac[k] = 0.f;

    int base = rs;
    for (; base + 16 <= re; base += 16) {
        int4a cc = *(const int4a*)(col + base + q * 4);
        float w0 = __expf(lrelu(as1[cc.x * HEADS + fh] + adn));
        float w1 = __expf(lrelu(as1[cc.y * HEADS + fh] + adn));
        float w2 = __expf(lrelu(as1[cc.z * HEADS + fh] + adn));
        float w3 = __expf(lrelu(as1[cc.w * HEADS + fh] + adn));
        den += (w0 + w1) + (w2 + w3);
        uint4 p0 = *(const uint4*)((const char*)h1b + (((unsigned)cc.x << 8) + (unsigned)(ll << 4)));
        uint4 p1 = *(const uint4*)((const char*)h1b + (((unsigned)cc.y << 8) + (unsigned)(ll << 4)));
        uint4 p2 = *(const uint4*)((const char*)h1b + (((unsigned)cc.z << 8) + (unsigned)(ll << 4)));
        uint4 p3 = *(const uint4*)((const char*)h1b + (((unsigned)cc.w << 8) + (unsigned)(ll << 4)));
        ac[0] = fmaf(w0, bflo(p0.x), ac[0]); ac[1] = fmaf(w0, bfhi(p0.x), ac[1]);
        ac[2] = fmaf(w0, bflo(p0.y), ac[2]); ac[3] = fmaf(w0, bfhi(p0.y), ac[3]);
        ac[4] = fmaf(w0, bflo(p0.z), ac[4]); ac[5] = fmaf(w0, bfhi(p0.z), ac[5]);
        ac[6] = fmaf(w0, bflo(p0.w), ac[6]); ac[7] = fmaf(w0, bfhi(p0.w), ac[7]);
        ac[0] = fmaf(w1, bflo(p1.x), ac[0]); ac[1] = fmaf(w1, bfhi(p1.x), ac[1]);
        ac[2] = fmaf(w1, bflo(p1.y), ac[2]); ac[3] = fmaf(w1, bfhi(p1.y), ac[3]);
        ac[4] = fmaf(w1, bflo(p1.z), ac[4]); ac[5] = fmaf(w1, bfhi(p1.z), ac[5]);
        ac[6] = fmaf(w1, bflo(p1.w), ac[6]); ac[7] = fmaf(w1, bfhi(p1.w), ac[7]);
        ac[0] = fmaf(w2, bflo(p2.x), ac[0]); ac[1] = fmaf(w2, bfhi(p2.x), ac[1]);
        ac[2] = fmaf(w2, bflo(p2.y), ac[2]); ac[3] = fmaf(w2, bfhi(p2.y), ac[3]);
        ac[4] = fmaf(w2, bflo(p2.z), ac[4]); ac[5] = fmaf(w2, bfhi(p2.z), ac[5]);
        ac[6] = fmaf(w2, bflo(p2.w), ac[6]); ac[7] = fmaf(w2, bfhi(p2.w), ac[7]);
        ac[0] = fmaf(w3, bflo(p3.x), ac[0]); ac[1] = fmaf(w3, bfhi(p3.x), ac[1]);
        ac[2] = fmaf(w3, bflo(p3.y), ac[2]); ac[3] = fmaf(w3, bfhi(p3.y), ac[3]);
        ac[4] = fmaf(w3, bflo(p3.z), ac[4]); ac[5] = fmaf(w3, bfhi(p3.z), ac[5]);
        ac[6] = fmaf(w3, bflo(p3.w), ac[6]); ac[7] = fmaf(w3, bfhi(p3.w), ac[7]);
    }
    for (; base < re; base += 4) {
        int i = base + q;
        int c = (i < re) ? col[i] : n;
        float w = __expf(lrelu(as1[c * HEADS + fh] + adn));
        if (i >= re) w = 0.f;
        den += w;
        unsigned off = ((unsigned)c << 8) + (unsigned)(ll << 4);
        uint4 pk = *(const uint4*)((const char*)h1b + off);
        ac[0] = fmaf(w, bflo(pk.x), ac[0]); ac[1] = fmaf(w, bfhi(pk.x), ac[1]);
        ac[2] = fmaf(w, bflo(pk.y), ac[2]); ac[3] = fmaf(w, bfhi(pk.y), ac[3]);
        ac[4] = fmaf(w, bflo(pk.z), ac[4]); ac[5] = fmaf(w, bfhi(pk.z), ac[5]);
        ac[6] = fmaf(w, bflo(pk.w), ac[6]); ac[7] = fmaf(w, bfhi(pk.w), ac[7]);
    }
    // reduce across edge slots q (lane bits 4,5); stays within the same head
    den += __shfl_xor(den, 16);
    den += __shfl_xor(den, 32);
#pragma unroll
    for (int k = 0; k < 8; k++) {
        ac[k] += __shfl_xor(ac[k], 16);
        ac[k] += __shfl_xor(ac[k], 32);
    }
    const float wself = __expf(lrelu(as1[n * HEADS + fh] + adn));
    den += wself;
    if (q == 0) {
        unsigned offs = ((unsigned)n << 8) + (unsigned)(ll << 4);
        uint4 sp = *(const uint4*)((const char*)h1b + offs);
        float sv[8] = {bflo(sp.x), bfhi(sp.x), bflo(sp.y), bfhi(sp.y),
                       bflo(sp.z), bfhi(sp.z), bflo(sp.w), bfhi(sp.w)};
        float4 bv0 = *(const float4*)(b1 + ll * 8);
        float4 bv1 = *(const float4*)(b1 + ll * 8 + 4);
        float bb[8] = {bv0.x, bv0.y, bv0.z, bv0.w, bv1.x, bv1.y, bv1.z, bv1.w};
        float o[8];
#pragma unroll
        for (int k = 0; k < 8; k++)
            o[k] = fmaxf((ac[k] + wself * sv[k]) / den + bb[k], 0.f);
        *(float4*)(out1 + (size_t)n * C1 + ll * 8) =
            make_float4(o[0], o[1], o[2], o[3]);
        *(float4*)(out1 + (size_t)n * C1 + ll * 8 + 4) =
            make_float4(o[4], o[5], o[6], o[7]);
    }
}

// ---- GEMM2 (+fused att2): h2b[N,64](bf16) = out1 @ W2 ; as2/ad2 from fp32 acc ----
__global__ __launch_bounds__(320) void k_gemm2(const float* __restrict__ A,
                                               const float* __restrict__ W,
                                               const float* __restrict__ AS,
                                               const float* __restrict__ AD,
                                               unsigned short* __restrict__ h2b,
                                               float* __restrict__ as2,
                                               float* __restrict__ ad2) {
    __shared__ float xs[64][132];
    __shared__ float ws2[128 * 40];
    __shared__ float sS[320];
    __shared__ float sD[320];
    const int tid = threadIdx.x;
    const int row0 = blockIdx.x * 64;
    for (int q = tid; q < 1280; q += 320)
        *(float4*)(ws2 + q * 4) = *(const float4*)(W + q * 4);
    for (int q = tid; q < 2048; q += 320) {
        int r = q >> 5, kq = (q & 31) * 4;
        int gr = row0 + r;
        float4 v = make_float4(0.f, 0.f, 0.f, 0.f);
        if (gr < NODES) v = *(const float4*)(A + (size_t)gr * FIN + kq);
        *(float4*)(&xs[r][kq]) = v;
    }
    __syncthreads();
    const int r = tid / 5;
    const int c0 = (tid % 5) * 8;
    float acc[8];
#pragma unroll
    for (int j = 0; j < 8; j++) acc[j] = 0.f;
    for (int k = 0; k < 128; k++) {
        float a = xs[r][k];
        float4 b0 = *(float4*)(ws2 + k * CLS + c0);
        float4 b1 = *(float4*)(ws2 + k * CLS + c0 + 4);
        acc[0] = fmaf(a, b0.x, acc[0]); acc[1] = fmaf(a, b0.y, acc[1]);
        acc[2] = fmaf(a, b0.z, acc[2]); acc[3] = fmaf(a, b0.w, acc[3]);
        acc[4] = fmaf(a, b1.x, acc[4]); acc[5] = fmaf(a, b1.y, acc[5]);
        acc[6] = fmaf(a, b1.z, acc[6]); acc[7] = fmaf(a, b1.w, acc[7]);
    }
    // partial attention dots (fp32-exact)
    {
        float s = 0.f, d = 0.f;
#pragma unroll
        for (int j = 0; j < 8; j++) {
            s = fmaf(acc[j], AS[c0 + j], s);
            d = fmaf(acc[j], AD[c0 + j], d);
        }
        sS[tid] = s; sD[tid] = d;
    }
    int gr = row0 + r;
    if (gr < NODES) {
        unsigned short tb[8];
#pragma unroll
        for (int j = 0; j < 8; j++) tb[j] = f2bf(acc[j]);
        uint4 pk;
        pk.x = (unsigned)tb[0] | ((unsigned)tb[1] << 16);
        pk.y = (unsigned)tb[2] | ((unsigned)tb[3] << 16);
        pk.z = (unsigned)tb[4] | ((unsigned)tb[5] << 16);
        pk.w = (unsigned)tb[6] | ((unsigned)tb[7] << 16);
        *(uint4*)(h2b + (size_t)gr * 64 + c0) = pk;
    }
    __syncthreads();
    if (tid < 64) {
        int grr = row0 + tid;
        if (grr < NODES) {
            int b5 = tid * 5;
            as2[grr] = sS[b5] + sS[b5+1] + sS[b5+2] + sS[b5+3] + sS[b5+4];
            ad2[grr] = sD[b5] + sD[b5+1] + sD[b5+2] + sD[b5+3] + sD[b5+4];
        }
    }
}

// ---- layer-2 aggregation: one wave per dst node ----
__global__ __launch_bounds__(256) void k_agg2(const unsigned short* __restrict__ h2b,
                                              const float* __restrict__ as2,
                                              const float* __restrict__ ad2,
                                              const int* __restrict__ rowptr,
                                              const int* __restrict__ degarr,
                                              const int* __restrict__ col,
                                              const float* __restrict__ b2,
                                              float* __restrict__ out) {
    int wid = (blockIdx.x * 256 + threadIdx.x) >> 6;
    if (wid >= NODES) return;
    const int lane = threadIdx.x & 63;
    const int q8 = lane >> 3, l8 = lane & 7;
    const int n = wid;
    const float adn = ad2[n];
    const int rs = rowptr[n];
    const int re = rs + degarr[n];

    float den = 0.f;
    float ac[8];
#pragma unroll
    for (int k = 0; k < 8; k++) ac[k] = 0.f;

    int base = rs;
    for (; base + 16 <= re; base += 16) {
        int2a cc = *(const int2a*)(col + base + q8 * 2);
        float w0 = __expf(lrelu(as2[cc.x] + adn));
        float w1 = __expf(lrelu(as2[cc.y] + adn));
        den += w0 + w1;
        if (l8 < 5) {
            unsigned o0 = ((unsigned)cc.x << 7) + (unsigned)(l8 << 4);
            unsigned o1 = ((unsigned)cc.y << 7) + (unsigned)(l8 << 4);
            uint4 p0 = *(const uint4*)((const char*)h2b + o0);
            uint4 p1 = *(const uint4*)((const char*)h2b + o1);
            ac[0] = fmaf(w0, bflo(p0.x), ac[0]); ac[1] = fmaf(w0, bfhi(p0.x), ac[1]);
            ac[2] = fmaf(w0, bflo(p0.y), ac[2]); ac[3] = fmaf(w0, bfhi(p0.y), ac[3]);
            ac[4] = fmaf(w0, bflo(p0.z), ac[4]); ac[5] = fmaf(w0, bfhi(p0.z), ac[5]);
            ac[6] = fmaf(w0, bflo(p0.w), ac[6]); ac[7] = fmaf(w0, bfhi(p0.w), ac[7]);
            ac[0] = fmaf(w1, bflo(p1.x), ac[0]); ac[1] = fmaf(w1, bfhi(p1.x), ac[1]);
            ac[2] = fmaf(w1, bflo(p1.y), ac[2]); ac[3] = fmaf(w1, bfhi(p1.y), ac[3]);
            ac[4] = fmaf(w1, bflo(p1.z), ac[4]); ac[5] = fmaf(w1, bfhi(p1.z), ac[5]);
            ac[6] = fmaf(w1, bflo(p1.w), ac[6]); ac[7] = fmaf(w1, bfhi(p1.w), ac[7]);
        }
    }
    for (; base < re; base += 8) {
        int i = base + q8;
        int c = (i < re) ? col[i] : n;
        float w = __expf(lrelu(as2[c] + adn));
        if (i >= re) w = 0.f;
        den += w;
        if (l8 < 5) {
            unsigned off = ((unsigned)c << 7) + (unsigned)(l8 << 4);
            uint4 pk = *(const uint4*)((const char*)h2b + off);
            ac[0] = fmaf(w, bflo(pk.x), ac[0]); ac[1] = fmaf(w, bfhi(pk.x), ac[1]);
            ac[2] = fmaf(w, bflo(pk.y), ac[2]); ac[3] = fmaf(w, bfhi(pk.y), ac[3]);
            ac[4] = fmaf(w, bflo(pk.z), ac[4]); ac[5] = fmaf(w, bfhi(pk.z), ac[5]);
            ac[6] = fmaf(w, bflo(pk.w), ac[6]); ac[7] = fmaf(w, bfhi(pk.w), ac[7]);
        }
    }
    den += __shfl_xor(den, 8);
    den += __shfl_xor(den, 16);
    den += __shfl_xor(den, 32);
#pragma unroll
    for (int k = 0; k < 8; k++) {
        ac[k] += __shfl_xor(ac[k], 8);
        ac[k] += __shfl_xor(ac[k], 16);
        ac[k] += __shfl_xor(ac[k], 32);
    }
    const float wself = __expf(lrelu(as2[n] + adn));
    den += wself;
    if (q8 == 0 && l8 < 5) {
        unsigned offs = ((unsigned)n << 7) + (unsigned)(l8 << 4);
        uint4 sp = *(const uint4*)((const char*)h2b + offs);
        float sv[8] = {bflo(sp.x), bfhi(sp.x), bflo(sp.y), bfhi(sp.y),
                       bflo(sp.z), bfhi(sp.z), bflo(sp.w), bfhi(sp.w)};
        float4 bv0 = *(const float4*)(b2 + l8 * 8);
        float4 bv1 = *(const float4*)(b2 + l8 * 8 + 4);
        float bb[8] = {bv0.x, bv0.y, bv0.z, bv0.w, bv1.x, bv1.y, bv1.z, bv1.w};
        float o[8];
#pragma unroll
        for (int k = 0; k < 8; k++)
            o[k] = (ac[k] + wself * sv[k]) / den + bb[k];
        *(float4*)(out + (size_t)n * CLS + l8 * 8) =
            make_float4(o[0], o[1], o[2], o[3]);
        *(float4*)(out + (size_t)n * CLS + l8 * 8 + 4) =
            make_float4(o[4], o[5], o[6], o[7]);
    }
}

extern "C" void kernel_launch(void* const* d_in, const int* in_sizes, int n_in,
                              void* d_out, int out_size, void* d_ws, size_t ws_size,
                              hipStream_t stream) {
    const float* x     = (const float*)d_in[0];
    const int*   ei    = (const int*)d_in[1];
    const float* W1    = (const float*)d_in[2];
    const float* aS1   = (const float*)d_in[3];
    const float* aD1   = (const float*)d_in[4];
    const float* b1    = (const float*)d_in[5];
    const float* W2    = (const float*)d_in[6];
    const float* aS2   = (const float*)d_in[7];
    const float* aD2   = (const float*)d_in[8];
    const float* b2    = (const float*)d_in[9];
    float* out = (float*)d_out;
    const int E = in_sizes[1] / 2;
    const int* src = ei;
    const int* dst = ei + E;

    char* ws = (char*)d_ws;
    size_t off = 0;
    auto alloc = [&](size_t bytes) -> char* {
        char* p = ws + off;
        off += (bytes + 255) & ~(size_t)255;
        return p;
    };
    unsigned short* h1b = (unsigned short*)alloc((size_t)NODES * C1 * 2);
    float* out1   = (float*)alloc((size_t)NODES * C1 * 4);
    unsigned short* h2b = (unsigned short*)alloc((size_t)NODES * 64 * 2);
    float* as1    = (float*)alloc((size_t)NODES * HEADS * 4);
    float* ad1    = (float*)alloc((size_t)NODES * HEADS * 4);
    float* as2    = (float*)alloc((size_t)NODES * 4);
    float* ad2    = (float*)alloc((size_t)NODES * 4);
    int* rowptr   = (int*)alloc((size_t)NODES * 4);
    int* degarr   = (int*)alloc((size_t)NODES * 4);
    int* col      = (int*)alloc((size_t)NBUCK * BCAP * 4);
    int* tmp      = (int*)alloc((size_t)NBUCK * BCAP * 4);
    unsigned short* w1t = (unsigned short*)alloc((size_t)FIN * C1 * 2);
    int* bwp      = (int*)alloc((size_t)NBUCK * 4);

    k_prep<<<1, 256, 0, stream>>>(W1, w1t, bwp);
    k_gemm1<<<(NODES + 63) / 64, 256, 0, stream>>>(x, w1t, aS1, aD1, h1b, as1, ad1);
    k_bucketA<<<(E + EPB - 1) / EPB, 256, 0, stream>>>(src, dst, E, bwp, tmp);
    k_bucketB<<<NBUCK, 256, 0, stream>>>(bwp, tmp, col, rowptr, degarr);
    k_agg1<<<(NODES * 64) / 256, 256, 0, stream>>>(h1b, as1, ad1, rowptr, degarr, col, b1, out1);
    k_gemm2<<<(NODES + 63) / 64, 320, 0, stream>>>(out1, W2, aS2, aD2, h2b, as2, ad2);
    k_agg2<<<(NODES * 64) / 256, 256, 0, stream>>>(h2b, as2, ad2, rowptr, degarr, col, b2, out);
}

// Round 13
// 211.941 us; speedup vs baseline: 2.8646x; 1.0968x over previous
//
#include <hip/hip_runtime.h>
#include <cstdint>

#define NODES 50000
#define FIN   128
#define C1    128   // HEADS*HID
#define HEADS 4
#define HID   32
#define CLS   40
#define SLOPE 0.2f

#define NBUCK ((NODES + 255) >> 8)   // 196
#define EPB 2048                     // edges per bucketA block
#define BCAP 8192                    // fixed bucket capacity (max actual ~4.3k)

__device__ __forceinline__ float lrelu(float v) { return v > 0.f ? v : SLOPE * v; }

__device__ __forceinline__ unsigned short f2bf(float f) {
    union { float f; unsigned u; } v; v.f = f;
    unsigned u = v.u;
    return (unsigned short)((u + 0x7FFFu + ((u >> 16) & 1u)) >> 16);
}
__device__ __forceinline__ float bf2f(unsigned short b) {
    union { unsigned u; float f; } v; v.u = ((unsigned)b) << 16;
    return v.f;
}
__device__ __forceinline__ float bflo(unsigned u) {
    union { unsigned x; float f; } v; v.x = u << 16; return v.f;
}
__device__ __forceinline__ float bfhi(unsigned u) {
    union { unsigned x; float f; } v; v.x = u & 0xffff0000u; return v.f;
}

typedef __attribute__((ext_vector_type(8))) short bf16x8;
typedef __attribute__((ext_vector_type(4))) float f32x4;
typedef __attribute__((ext_vector_type(4), aligned(4))) int int4a;
typedef __attribute__((ext_vector_type(2), aligned(4))) int int2a;

// ---- prep: W1->bf16 transposed (LDS-coalesced), W2->bf16 transposed, bwp init ----
__global__ __launch_bounds__(256) void k_prep(const float* __restrict__ W1,
                                              const float* __restrict__ W2,
                                              unsigned short* __restrict__ w1t,
                                              unsigned short* __restrict__ w2t,
                                              int* __restrict__ bwp) {
    __shared__ unsigned short Tb[128][136];
    const int t = threadIdx.x;
    // read W1 coalesced (consecutive t -> consecutive n), transpose into LDS
#pragma unroll
    for (int i = 0; i < 64; i++) {
        int p = i * 256 + t;
        int k = p >> 7, n = p & 127;
        Tb[n][k] = f2bf(W1[(size_t)k * C1 + n]);
    }
    __syncthreads();
    // write w1t coalesced (uint4)
#pragma unroll
    for (int i = 0; i < 8; i++) {
        int p = i * 256 + t;
        int n = p >> 4, k8 = (p & 15) * 8;
        *(uint4*)(w1t + n * 128 + k8) = *(uint4*)(&Tb[n][k8]);
    }
    // w2t[n][k] bf16 from W2[k][n] (small: 5120 elems)
    for (int p = t; p < CLS * 128; p += 256) {
        int n = p >> 7, k = p & 127;
        w2t[n * 128 + k] = f2bf(W2[(size_t)k * CLS + n]);
    }
    if (t < NBUCK) bwp[t] = t * BCAP;
}

// ---- GEMM1 (MFMA bf16): h1b[N,128](bf16) = x @ W1 ; as1/ad1 fused ----
__global__ __launch_bounds__(256) void k_gemm1(const float* __restrict__ X,
                                               const unsigned short* __restrict__ w1t,
                                               const float* __restrict__ AS,
                                               const float* __restrict__ AD,
                                               unsigned short* __restrict__ h1b,
                                               float* __restrict__ as1,
                                               float* __restrict__ ad1) {
    __shared__ unsigned short Asm[64][136];   // also reused as C output
    __shared__ unsigned short Wt[128][136];   // Wt[n][k]
    const int t = threadIdx.x;
    const int row0 = blockIdx.x * 64;

#pragma unroll
    for (int i = 0; i < 8; i++) {
        int p = i * 256 + t;
        int n = p >> 4, k8 = (p & 15) * 8;
        *(uint4*)(&Wt[n][k8]) = *(const uint4*)(w1t + n * 128 + k8);
    }
    {
        int r = t >> 2, c0 = (t & 3) * 32;
        int gr = row0 + r;
        unsigned short tb[32];
        if (gr < NODES) {
#pragma unroll
            for (int i = 0; i < 8; i++) {
                float4 v = *(const float4*)(X + (size_t)gr * FIN + c0 + i * 4);
                tb[i * 4 + 0] = f2bf(v.x); tb[i * 4 + 1] = f2bf(v.y);
                tb[i * 4 + 2] = f2bf(v.z); tb[i * 4 + 3] = f2bf(v.w);
            }
        } else {
#pragma unroll
            for (int i = 0; i < 32; i++) tb[i] = 0;
        }
#pragma unroll
        for (int i = 0; i < 4; i++) {
            uint4 pk;
            pk.x = (unsigned)tb[i*8+0] | ((unsigned)tb[i*8+1] << 16);
            pk.y = (unsigned)tb[i*8+2] | ((unsigned)tb[i*8+3] << 16);
            pk.z = (unsigned)tb[i*8+4] | ((unsigned)tb[i*8+5] << 16);
            pk.w = (unsigned)tb[i*8+6] | ((unsigned)tb[i*8+7] << 16);
            *(uint4*)(&Asm[r][c0 + i * 8]) = pk;
        }
    }
    __syncthreads();

    const int w = t >> 6, l = t & 63;
    const int lm = l & 15, quad = l >> 4;
    f32x4 acc[8];
#pragma unroll
    for (int ct = 0; ct < 8; ct++) acc[ct] = (f32x4){0.f, 0.f, 0.f, 0.f};
#pragma unroll
    for (int kt = 0; kt < 4; kt++) {
        bf16x8 a = *(const bf16x8*)(&Asm[w * 16 + lm][kt * 32 + quad * 8]);
#pragma unroll
        for (int ct = 0; ct < 8; ct++) {
            bf16x8 b = *(const bf16x8*)(&Wt[ct * 16 + lm][kt * 32 + quad * 8]);
            acc[ct] = __builtin_amdgcn_mfma_f32_16x16x32_bf16(a, b, acc[ct], 0, 0, 0);
        }
    }
    __syncthreads();
#pragma unroll
    for (int ct = 0; ct < 8; ct++)
#pragma unroll
        for (int r = 0; r < 4; r++)
            Asm[w * 16 + quad * 4 + r][ct * 16 + lm] = f2bf(acc[ct][r]);
    __syncthreads();
    {
        int r = t >> 2, c0 = (t & 3) * 32;
        int gr = row0 + r;
        if (gr < NODES) {
#pragma unroll
            for (int i = 0; i < 4; i++)
                *(uint4*)(h1b + (size_t)gr * C1 + c0 + i * 8) =
                    *(uint4*)(&Asm[r][c0 + i * 8]);
        }
    }
    {
        int r = t >> 2, h = t & 3;
        int gr = row0 + r;
        if (gr < NODES) {
            float s = 0.f, d = 0.f;
#pragma unroll
            for (int j = 0; j < 32; j++) {
                float v = bf2f(Asm[r][h * 32 + j]);
                s = fmaf(v, AS[h * HID + j], s);
                d = fmaf(v, AD[h * HID + j], d);
            }
            as1[gr * HEADS + h] = s;
            ad1[gr * HEADS + h] = d;
        }
    }
}

// ---- pass A: bucket edges by dst>>8 into fixed-capacity segments of tmp ----
__global__ __launch_bounds__(256) void k_bucketA(const int* __restrict__ src,
                                                 const int* __restrict__ dst, int E,
                                                 int* __restrict__ bwp,
                                                 int* __restrict__ tmp) {
    __shared__ int cnt[NBUCK];
    __shared__ int bbs[NBUCK];
    const int t = threadIdx.x;
    for (int i = t; i < NBUCK; i += 256) cnt[i] = 0;
    __syncthreads();
    const int e0 = blockIdx.x * EPB;
    int v[8], rb[8];
#pragma unroll
    for (int k = 0; k < 8; k++) {
        int e = e0 + k * 256 + t;
        rb[k] = -1;
        if (e < E) {
            int d = dst[e], s = src[e];
            int b = d >> 8;
            int r = atomicAdd(&cnt[b], 1);
            v[k] = (s << 8) | (d & 255);
            rb[k] = (r << 8) | b;
        }
    }
    __syncthreads();
    for (int i = t; i < NBUCK; i += 256) {
        int c = cnt[i];
        bbs[i] = c ? atomicAdd(&bwp[i], c) : 0;
    }
    __syncthreads();
#pragma unroll
    for (int k = 0; k < 8; k++) {
        if (rb[k] >= 0) {
            int b = rb[k] & 255;
            int r = rb[k] >> 8;
            tmp[bbs[b] + r] = v[k];
        }
    }
}

// ---- pass B: per-bucket degree+scan -> rowptr/deg, scatter col ----
__global__ __launch_bounds__(256) void k_bucketB(const int* __restrict__ bwp,
                                                 const int* __restrict__ tmp,
                                                 int* __restrict__ col,
                                                 int* __restrict__ rowptr,
                                                 int* __restrict__ degarr) {
    __shared__ int degs[256];
    __shared__ int wp[256];
    __shared__ int wsum[4];
    const int b = blockIdx.x, t = threadIdx.x;
    const int n0 = b << 8;
    const int beg = b * BCAP;
    const int end = bwp[b];
    degs[t] = 0;
    __syncthreads();
    for (int e = beg + t; e < end; e += 256)
        atomicAdd(&degs[tmp[e] & 255], 1);
    __syncthreads();
    const int d = degs[t];
    int incl = d;
    const int lane = t & 63, w = t >> 6;
#pragma unroll
    for (int s = 1; s < 64; s <<= 1) {
        int u = __shfl_up(incl, s);
        if (lane >= s) incl += u;
    }
    if (lane == 63) wsum[w] = incl;
    __syncthreads();
    if (t == 0) {
        int r = 0;
#pragma unroll
        for (int i = 0; i < 4; i++) { int x = wsum[i]; wsum[i] = r; r += x; }
    }
    __syncthreads();
    const int excl = incl - d + wsum[w] + beg;
    const int nidx = n0 + t;
    if (nidx < NODES) { rowptr[nidx] = excl; degarr[nidx] = d; }
    wp[t] = excl;
    __syncthreads();
    for (int e = beg + t; e < end; e += 256) {
        int v = tmp[e];
        int p = atomicAdd(&wp[v & 255], 1);
        col[p] = v >> 8;
    }
}

// ---- layer-1 aggregation: one wave per dst node; out1 written bf16 ----
__global__ __launch_bounds__(256) void k_agg1(const unsigned short* __restrict__ h1b,
                                              const float* __restrict__ as1,
                                              const float* __restrict__ ad1,
                                              const int* __restrict__ rowptr,
                                              const int* __restrict__ degarr,
                                              const int* __restrict__ col,
                                              const float* __restrict__ b1,
                                              unsigned short* __restrict__ out1) {
    int wid = (blockIdx.x * 256 + threadIdx.x) >> 6;
    if (wid >= NODES) return;
    const int lane = threadIdx.x & 63;
    const int q  = lane >> 4;       // edge slot
    const int ll = lane & 15;       // channel group
    const int fh = ll >> 2;         // head
    const int n = wid;
    const float adn = ad1[n * HEADS + fh];
    const int rs = rowptr[n];
    const int re = rs + degarr[n];

    float den = 0.f;
    float ac[8];
#pragma unroll
    for (int k = 0; k < 8; k++) ac[k] = 0.f;

    int base = rs;
    for (; base + 16 <= re; base += 16) {
        int4a cc = *(const int4a*)(col + base + q * 4);
        float w0 = __expf(lrelu(as1[cc.x * HEADS + fh] + adn));
        float w1 = __expf(lrelu(as1[cc.y * HEADS + fh] + adn));
        float w2 = __expf(lrelu(as1[cc.z * HEADS + fh] + adn));
        float w3 = __expf(lrelu(as1[cc.w * HEADS + fh] + adn));
        den += (w0 + w1) + (w2 + w3);
        uint4 p0 = *(const uint4*)((const char*)h1b + (((unsigned)cc.x << 8) + (unsigned)(ll << 4)));
        uint4 p1 = *(const uint4*)((const char*)h1b + (((unsigned)cc.y << 8) + (unsigned)(ll << 4)));
        uint4 p2 = *(const uint4*)((const char*)h1b + (((unsigned)cc.z << 8) + (unsigned)(ll << 4)));
        uint4 p3 = *(const uint4*)((const char*)h1b + (((unsigned)cc.w << 8) + (unsigned)(ll << 4)));
        ac[0] = fmaf(w0, bflo(p0.x), ac[0]); ac[1] = fmaf(w0, bfhi(p0.x), ac[1]);
        ac[2] = fmaf(w0, bflo(p0.y), ac[2]); ac[3] = fmaf(w0, bfhi(p0.y), ac[3]);
        ac[4] = fmaf(w0, bflo(p0.z), ac[4]); ac[5] = fmaf(w0, bfhi(p0.z), ac[5]);
        ac[6] = fmaf(w0, bflo(p0.w), ac[6]); ac[7] = fmaf(w0, bfhi(p0.w), ac[7]);
        ac[0] = fmaf(w1, bflo(p1.x), ac[0]); ac[1] = fmaf(w1, bfhi(p1.x), ac[1]);
        ac[2] = fmaf(w1, bflo(p1.y), ac[2]); ac[3] = fmaf(w1, bfhi(p1.y), ac[3]);
        ac[4] = fmaf(w1, bflo(p1.z), ac[4]); ac[5] = fmaf(w1, bfhi(p1.z), ac[5]);
        ac[6] = fmaf(w1, bflo(p1.w), ac[6]); ac[7] = fmaf(w1, bfhi(p1.w), ac[7]);
        ac[0] = fmaf(w2, bflo(p2.x), ac[0]); ac[1] = fmaf(w2, bfhi(p2.x), ac[1]);
        ac[2] = fmaf(w2, bflo(p2.y), ac[2]); ac[3] = fmaf(w2, bfhi(p2.y), ac[3]);
        ac[4] = fmaf(w2, bflo(p2.z), ac[4]); ac[5] = fmaf(w2, bfhi(p2.z), ac[5]);
        ac[6] = fmaf(w2, bflo(p2.w), ac[6]); ac[7] = fmaf(w2, bfhi(p2.w), ac[7]);
        ac[0] = fmaf(w3, bflo(p3.x), ac[0]); ac[1] = fmaf(w3, bfhi(p3.x), ac[1]);
        ac[2] = fmaf(w3, bflo(p3.y), ac[2]); ac[3] = fmaf(w3, bfhi(p3.y), ac[3]);
        ac[4] = fmaf(w3, bflo(p3.z), ac[4]); ac[5] = fmaf(w3, bfhi(p3.z), ac[5]);
        ac[6] = fmaf(w3, bflo(p3.w), ac[6]); ac[7] = fmaf(w3, bfhi(p3.w), ac[7]);
    }
    for (; base < re; base += 4) {
        int i = base + q;
        int c = (i < re) ? col[i] : n;
        float w = __expf(lrelu(as1[c * HEADS + fh] + adn));
        if (i >= re) w = 0.f;
        den += w;
        unsigned off = ((unsigned)c << 8) + (unsigned)(ll << 4);
        uint4 pk = *(const uint4*)((const char*)h1b + off);
        ac[0] = fmaf(w, bflo(pk.x), ac[0]); ac[1] = fmaf(w, bfhi(pk.x), ac[1]);
        ac[2] = fmaf(w, bflo(pk.y), ac[2]); ac[3] = fmaf(w, bfhi(pk.y), ac[3]);
        ac[4] = fmaf(w, bflo(pk.z), ac[4]); ac[5] = fmaf(w, bfhi(pk.z), ac[5]);
        ac[6] = fmaf(w, bflo(pk.w), ac[6]); ac[7] = fmaf(w, bfhi(pk.w), ac[7]);
    }
    den += __shfl_xor(den, 16);
    den += __shfl_xor(den, 32);
#pragma unroll
    for (int k = 0; k < 8; k++) {
        ac[k] += __shfl_xor(ac[k], 16);
        ac[k] += __shfl_xor(ac[k], 32);
    }
    const float wself = __expf(lrelu(as1[n * HEADS + fh] + adn));
    den += wself;
    if (q == 0) {
        unsigned offs = ((unsigned)n << 8) + (unsigned)(ll << 4);
        uint4 sp = *(const uint4*)((const char*)h1b + offs);
        float sv[8] = {bflo(sp.x), bfhi(sp.x), bflo(sp.y), bfhi(sp.y),
                       bflo(sp.z), bfhi(sp.z), bflo(sp.w), bfhi(sp.w)};
        float4 bv0 = *(const float4*)(b1 + ll * 8);
        float4 bv1 = *(const float4*)(b1 + ll * 8 + 4);
        float bb[8] = {bv0.x, bv0.y, bv0.z, bv0.w, bv1.x, bv1.y, bv1.z, bv1.w};
        unsigned short ob[8];
#pragma unroll
        for (int k = 0; k < 8; k++)
            ob[k] = f2bf(fmaxf((ac[k] + wself * sv[k]) / den + bb[k], 0.f));
        uint4 pk;
        pk.x = (unsigned)ob[0] | ((unsigned)ob[1] << 16);
        pk.y = (unsigned)ob[2] | ((unsigned)ob[3] << 16);
        pk.z = (unsigned)ob[4] | ((unsigned)ob[5] << 16);
        pk.w = (unsigned)ob[6] | ((unsigned)ob[7] << 16);
        *(uint4*)(out1 + (size_t)n * C1 + ll * 8) = pk;
    }
}

// ---- GEMM2 (MFMA bf16, fused att2): h2b[N,64](bf16) = out1 @ W2 ; as2/ad2 ----
// 3 col-tiles (48 cols, rows 40..47 of Wt2 zeroed; cols 40..47 unused).
__global__ __launch_bounds__(256) void k_gemm2(const unsigned short* __restrict__ out1b,
                                               const unsigned short* __restrict__ w2t,
                                               const float* __restrict__ AS,
                                               const float* __restrict__ AD,
                                               unsigned short* __restrict__ h2b,
                                               float* __restrict__ as2,
                                               float* __restrict__ ad2) {
    __shared__ unsigned short Asm[64][136];
    __shared__ unsigned short Wt2[48][136];
    __shared__ float Cc[64][52];
    const int t = threadIdx.x;
    const int row0 = blockIdx.x * 64;

    // zero pad rows 40..47 of Wt2
    for (int p = t; p < 8 * 136; p += 256) Wt2[40 + p / 136][p % 136] = 0;
    // stage Wt2 rows 0..39 (640 uint4)
    for (int p = t; p < 640; p += 256) {
        int n = p >> 4, k8 = (p & 15) * 8;
        *(uint4*)(&Wt2[n][k8]) = *(const uint4*)(w2t + n * 128 + k8);
    }
    // stage A: out1 bf16 rows
    {
        int r = t >> 2, c0 = (t & 3) * 32;
        int gr = row0 + r;
        if (gr < NODES) {
#pragma unroll
            for (int i = 0; i < 4; i++)
                *(uint4*)(&Asm[r][c0 + i * 8]) =
                    *(const uint4*)(out1b + (size_t)gr * C1 + c0 + i * 8);
        } else {
            uint4 z = make_uint4(0, 0, 0, 0);
#pragma unroll
            for (int i = 0; i < 4; i++) *(uint4*)(&Asm[r][c0 + i * 8]) = z;
        }
    }
    __syncthreads();

    const int w = t >> 6, l = t & 63;
    const int lm = l & 15, quad = l >> 4;
    f32x4 acc[3];
#pragma unroll
    for (int ct = 0; ct < 3; ct++) acc[ct] = (f32x4){0.f, 0.f, 0.f, 0.f};
#pragma unroll
    for (int kt = 0; kt < 4; kt++) {
        bf16x8 a = *(const bf16x8*)(&Asm[w * 16 + lm][kt * 32 + quad * 8]);
#pragma unroll
        for (int ct = 0; ct < 3; ct++) {
            bf16x8 b = *(const bf16x8*)(&Wt2[ct * 16 + lm][kt * 32 + quad * 8]);
            acc[ct] = __builtin_amdgcn_mfma_f32_16x16x32_bf16(a, b, acc[ct], 0, 0, 0);
        }
    }
    __syncthreads();
#pragma unroll
    for (int ct = 0; ct < 3; ct++)
#pragma unroll
        for (int r = 0; r < 4; r++)
            Cc[w * 16 + quad * 4 + r][ct * 16 + lm] = acc[ct][r];
    __syncthreads();
    // epilogue: 4 threads per row, 10 cols each
    {
        int r = t >> 2, c0 = (t & 3) * 10;
        int gr = row0 + r;
        if (gr < NODES) {
#pragma unroll
            for (int i = 0; i < 5; i++) {
                int c = c0 + i * 2;
                unsigned pk = (unsigned)f2bf(Cc[r][c]) |
                              ((unsigned)f2bf(Cc[r][c + 1]) << 16);
                *(unsigned*)(h2b + (size_t)gr * 64 + c) = pk;
            }
            float s = 0.f, d = 0.f;
#pragma unroll
            for (int j = 0; j < 10; j++) {
                float v = Cc[r][c0 + j];
                s = fmaf(v, AS[c0 + j], s);
                d = fmaf(v, AD[c0 + j], d);
            }
            s += __shfl_xor(s, 1); s += __shfl_xor(s, 2);
            d += __shfl_xor(d, 1); d += __shfl_xor(d, 2);
            if ((t & 3) == 0) { as2[gr] = s; ad2[gr] = d; }
        }
    }
}

// ---- layer-2 aggregation: one wave per dst node ----
__global__ __launch_bounds__(256) void k_agg2(const unsigned short* __restrict__ h2b,
                                              const float* __restrict__ as2,
                                              const float* __restrict__ ad2,
                                              const int* __restrict__ rowptr,
                                              const int* __restrict__ degarr,
                                              const int* __restrict__ col,
                                              const float* __restrict__ b2,
                                              float* __restrict__ out) {
    int wid = (blockIdx.x * 256 + threadIdx.x) >> 6;
    if (wid >= NODES) return;
    const int lane = threadIdx.x & 63;
    const int q8 = lane >> 3, l8 = lane & 7;
    const int n = wid;
    const float adn = ad2[n];
    const int rs = rowptr[n];
    const int re = rs + degarr[n];

    float den = 0.f;
    float ac[8];
#pragma unroll
    for (int k = 0; k < 8; k++) ac[k] = 0.f;

    int base = rs;
    for (; base + 16 <= re; base += 16) {
        int2a cc = *(const int2a*)(col + base + q8 * 2);
        float w0 = __expf(lrelu(as2[cc.x] + adn));
        float w1 = __expf(lrelu(as2[cc.y] + adn));
        den += w0 + w1;
        if (l8 < 5) {
            unsigned o0 = ((unsigned)cc.x << 7) + (unsigned)(l8 << 4);
            unsigned o1 = ((unsigned)cc.y << 7) + (unsigned)(l8 << 4);
            uint4 p0 = *(const uint4*)((const char*)h2b + o0);
            uint4 p1 = *(const uint4*)((const char*)h2b + o1);
            ac[0] = fmaf(w0, bflo(p0.x), ac[0]); ac[1] = fmaf(w0, bfhi(p0.x), ac[1]);
            ac[2] = fmaf(w0, bflo(p0.y), ac[2]); ac[3] = fmaf(w0, bfhi(p0.y), ac[3]);
            ac[4] = fmaf(w0, bflo(p0.z), ac[4]); ac[5] = fmaf(w0, bfhi(p0.z), ac[5]);
            ac[6] = fmaf(w0, bflo(p0.w), ac[6]); ac[7] = fmaf(w0, bfhi(p0.w), ac[7]);
            ac[0] = fmaf(w1, bflo(p1.x), ac[0]); ac[1] = fmaf(w1, bfhi(p1.x), ac[1]);
            ac[2] = fmaf(w1, bflo(p1.y), ac[2]); ac[3] = fmaf(w1, bfhi(p1.y), ac[3]);
            ac[4] = fmaf(w1, bflo(p1.z), ac[4]); ac[5] = fmaf(w1, bfhi(p1.z), ac[5]);
            ac[6] = fmaf(w1, bflo(p1.w), ac[6]); ac[7] = fmaf(w1, bfhi(p1.w), ac[7]);
        }
    }
    for (; base < re; base += 8) {
        int i = base + q8;
        int c = (i < re) ? col[i] : n;
        float w = __expf(lrelu(as2[c] + adn));
        if (i >= re) w = 0.f;
        den += w;
        if (l8 < 5) {
            unsigned off = ((unsigned)c << 7) + (unsigned)(l8 << 4);
            uint4 pk = *(const uint4*)((const char*)h2b + off);
            ac[0] = fmaf(w, bflo(pk.x), ac[0]); ac[1] = fmaf(w, bfhi(pk.x), ac[1]);
            ac[2] = fmaf(w, bflo(pk.y), ac[2]); ac[3] = fmaf(w, bfhi(pk.y), ac[3]);
            ac[4] = fmaf(w, bflo(pk.z), ac[4]); ac[5] = fmaf(w, bfhi(pk.z), ac[5]);
            ac[6] = fmaf(w, bflo(pk.w), ac[6]); ac[7] = fmaf(w, bfhi(pk.w), ac[7]);
        }
    }
    den += __shfl_xor(den, 8);
    den += __shfl_xor(den, 16);
    den += __shfl_xor(den, 32);
#pragma unroll
    for (int k = 0; k < 8; k++) {
        ac[k] += __shfl_xor(ac[k], 8);
        ac[k] += __shfl_xor(ac[k], 16);
        ac[k] += __shfl_xor(ac[k], 32);
    }
    const float wself = __expf(lrelu(as2[n] + adn));
    den += wself;
    if (q8 == 0 && l8 < 5) {
        unsigned offs = ((unsigned)n << 7) + (unsigned)(l8 << 4);
        uint4 sp = *(const uint4*)((const char*)h2b + offs);
        float sv[8] = {bflo(sp.x), bfhi(sp.x), bflo(sp.y), bfhi(sp.y),
                       bflo(sp.z), bfhi(sp.z), bflo(sp.w), bfhi(sp.w)};
        float4 bv0 = *(const float4*)(b2 + l8 * 8);
        float4 bv1 = *(const float4*)(b2 + l8 * 8 + 4);
        float bb[8] = {bv0.x, bv0.y, bv0.z, bv0.w, bv1.x, bv1.y, bv1.z, bv1.w};
        float o[8];
#pragma unroll
        for (int k = 0; k < 8; k++)
            o[k] = (ac[k] + wself * sv[k]) / den + bb[k];
        *(float4*)(out + (size_t)n * CLS + l8 * 8) =
            make_float4(o[0], o[1], o[2], o[3]);
        *(float4*)(out + (size_t)n * CLS + l8 * 8 + 4) =
            make_float4(o[4], o[5], o[6], o[7]);
    }
}

extern "C" void kernel_launch(void* const* d_in, const int* in_sizes, int n_in,
                              void* d_out, int out_size, void* d_ws, size_t ws_size,
                              hipStream_t stream) {
    const float* x     = (const float*)d_in[0];
    const int*   ei    = (const int*)d_in[1];
    const float* W1    = (const float*)d_in[2];
    const float* aS1   = (const float*)d_in[3];
    const float* aD1   = (const float*)d_in[4];
    const float* b1    = (const float*)d_in[5];
    const float* W2    = (const float*)d_in[6];
    const float* aS2   = (const float*)d_in[7];
    const float* aD2   = (const float*)d_in[8];
    const float* b2    = (const float*)d_in[9];
    float* out = (float*)d_out;
    const int E = in_sizes[1] / 2;
    const int* src = ei;
    const int* dst = ei + E;

    char* ws = (char*)d_ws;
    size_t off = 0;
    auto alloc = [&](size_t bytes) -> char* {
        char* p = ws + off;
        off += (bytes + 255) & ~(size_t)255;
        return p;
    };
    unsigned short* h1b  = (unsigned short*)alloc((size_t)NODES * C1 * 2);
    unsigned short* out1 = (unsigned short*)alloc((size_t)NODES * C1 * 2);
    unsigned short* h2b  = (unsigned short*)alloc((size_t)NODES * 64 * 2);
    float* as1    = (float*)alloc((size_t)NODES * HEADS * 4);
    float* ad1    = (float*)alloc((size_t)NODES * HEADS * 4);
    float* as2    = (float*)alloc((size_t)NODES * 4);
    float* ad2    = (float*)alloc((size_t)NODES * 4);
    int* rowptr   = (int*)alloc((size_t)NODES * 4);
    int* degarr   = (int*)alloc((size_t)NODES * 4);
    int* col      = (int*)alloc((size_t)NBUCK * BCAP * 4);
    int* tmp      = (int*)alloc((size_t)NBUCK * BCAP * 4);
    unsigned short* w1t = (unsigned short*)alloc((size_t)FIN * C1 * 2);
    unsigned short* w2t = (unsigned short*)alloc((size_t)CLS * 128 * 2);
    int* bwp      = (int*)alloc((size_t)NBUCK * 4);

    k_prep<<<1, 256, 0, stream>>>(W1, W2, w1t, w2t, bwp);
    k_gemm1<<<(NODES + 63) / 64, 256, 0, stream>>>(x, w1t, aS1, aD1, h1b, as1, ad1);
    k_bucketA<<<(E + EPB - 1) / EPB, 256, 0, stream>>>(src, dst, E, bwp, tmp);
    k_bucketB<<<NBUCK, 256, 0, stream>>>(bwp, tmp, col, rowptr, degarr);
    k_agg1<<<(NODES * 64) / 256, 256, 0, stream>>>(h1b, as1, ad1, rowptr, degarr, col, b1, out1);
    k_gemm2<<<(NODES + 63) / 64, 256, 0, stream>>>(out1, w2t, aS2, aD2, h2b, as2, ad2);
    k_agg2<<<(NODES * 64) / 256, 256, 0, stream>>>(h2b, as2, ad2, rowptr, degarr, col, b2, out);
}